// Round 9
// baseline (460.507 us; speedup 1.0000x reference)
//
#include <hip/hip_runtime.h>
#include <hip/hip_bf16.h>

#define S_LEN 1024
#define E_DIM 512
#define INNER_D 1024
#define NHEAD 8
#define DHEAD 128

typedef unsigned short u16;
typedef unsigned int u32;
typedef __attribute__((ext_vector_type(8))) short short8;
typedef __attribute__((ext_vector_type(4))) float f32x4;

union S8 { short8 v; u16 u[8]; uint4 q; };

__device__ __forceinline__ u16 f2bf(float f) {
  u32 u = __float_as_uint(f);
  u32 r = u + 0x7FFFu + ((u >> 16) & 1u);
  return (u16)(r >> 16);
}
__device__ __forceinline__ float bf2f(u16 u) { return __uint_as_float(((u32)u) << 16); }

// direct global -> LDS (16B per lane). LDS dest = wave-uniform base + lane*16B (linear).
__device__ __forceinline__ void gload16(const u16* g, u16* l) {
  __builtin_amdgcn_global_load_lds((const __attribute__((address_space(1))) void*)g,
                                   (__attribute__((address_space(3))) void*)l, 16, 0, 0);
}

// ---------------- merged one-time prep: transposes + gates weights + embedding ----------------
__device__ __forceinline__ void prep_transpose(
    const float* __restrict__ in, u16* __restrict__ out, int K, int N,
    int k0, int n0, int t, u16 (*T)[72])
{
  int kr = t >> 2, nseg = (t & 3) * 16;
  const float* src = in + (size_t)(k0 + kr) * N + n0 + nseg;
#pragma unroll
  for (int j = 0; j < 16; j++) T[kr][nseg + j] = f2bf(src[j]);
  __syncthreads();
  int nr = t >> 2, kseg = (t & 3) * 16;
  u32 u[8];
#pragma unroll
  for (int rr = 0; rr < 8; rr++) {
    u32 lo = T[kseg + 2 * rr][nr];
    u32 hi = T[kseg + 2 * rr + 1][nr];
    u[rr] = lo | (hi << 16);
  }
  u16* dst = out + (size_t)(n0 + nr) * K + k0 + kseg;
  uint4 w0 = {u[0], u[1], u[2], u[3]};
  uint4 w1 = {u[4], u[5], u[6], u[7]};
  *(uint4*)dst = w0;
  *(uint4*)(dst + 8) = w1;
}

__global__ __launch_bounds__(256) void prep_kernel(
    const float* __restrict__ up_W, u16* __restrict__ upWt,
    const float* __restrict__ down_W, u16* __restrict__ dnWt,
    const float* __restrict__ igW, const float* __restrict__ fgW,
    u16* __restrict__ ghi, u16* __restrict__ glo,
    const float* __restrict__ xe, const float* __restrict__ xmk,
    const float* __restrict__ eW, const float* __restrict__ eb,
    float* __restrict__ x)
{
  __shared__ u16 T[64][72];
  __shared__ float in_s[25];
  int id = blockIdx.x;
  int t = threadIdx.x;
  if (id < 1024) {                     // up_W transpose: [L][512][2048] -> [L][2048][512]
    int bx = id & 7, rest = id >> 3;
    int by = rest & 31, L = rest >> 5;
    prep_transpose(up_W + (size_t)L * 512 * 2048, upWt + (size_t)L * 1048576,
                   512, 2048, bx * 64, by * 64, t, T);
  } else if (id < 1536) {              // down_W transpose: [L][1024][512] -> [L][512][1024]
    int id2 = id - 1024;
    int bx = id2 & 15, rest = id2 >> 4;
    int by = rest & 7, L = rest >> 3;
    prep_transpose(down_W + (size_t)L * 1024 * 512, dnWt + (size_t)L * 524288,
                   1024, 512, bx * 64, by * 64, t, T);
  } else if (id < 2304) {              // gates weights: hi/lo split transpose
    int id3 = id - 1536;
    int bx = id3 % 12, rest = id3 / 12;
    int n = rest & 15, L = rest >> 4;
    int k = bx * 256 + t;
    const float* W = ((n < 8) ? igW : fgW) + (size_t)L * 24576;
    float v = W[(size_t)k * 8 + (n & 7)];
    u16 h = f2bf(v);
    u16 l = f2bf(v - bf2f(h));
    size_t o = ((size_t)L * 16 + n) * 3072 + k;
    ghi[o] = h;
    glo[o] = l;
  } else {                             // embedding, one row per block
    int row = id - 2304;
    if (t < 21) in_s[t] = xe[row * 21 + t];
    else if (t < 25) in_s[t] = xmk[row * 4 + t - 21];
    __syncthreads();
#pragma unroll
    for (int rep = 0; rep < 2; rep++) {
      int e = t + rep * 256;
      float acc = eb[e];
#pragma unroll
      for (int i = 0; i < 25; i++) acc += in_s[i] * eW[i * E_DIM + e];
      x[(size_t)row * E_DIM + e] = acc;
    }
  }
}

// ---------------- layernorm -> bf16 ----------------
__global__ __launch_bounds__(256) void ln_kernel(
    const float* __restrict__ x, const float* __restrict__ w, u16* __restrict__ out)
{
  int row = blockIdx.x, tid = threadIdx.x;
  const float* xr = x + (size_t)row * E_DIM;
  float2 v = *(const float2*)(xr + tid * 2);
  float s = v.x + v.y, q = v.x * v.x + v.y * v.y;
#pragma unroll
  for (int off = 32; off; off >>= 1) { s += __shfl_xor(s, off); q += __shfl_xor(q, off); }
  __shared__ float ssum[4], ssq[4];
  int wv = tid >> 6;
  if ((tid & 63) == 0) { ssum[wv] = s; ssq[wv] = q; }
  __syncthreads();
  s = ssum[0] + ssum[1] + ssum[2] + ssum[3];
  q = ssq[0] + ssq[1] + ssq[2] + ssq[3];
  float mu = s * (1.f / E_DIM);
  float var = q * (1.f / E_DIM) - mu * mu;
  float rs = rsqrtf(var + 1e-5f);
  int e = tid * 2;
  ushort2 o;
  o.x = f2bf((v.x - mu) * rs * w[e]);
  o.y = f2bf((v.y - mu) * rs * w[e + 1]);
  *(ushort2*)(out + (size_t)row * E_DIM + e) = o;
}

// ---------------- fused final layernorm + head (one block per output row) ----------------
__global__ __launch_bounds__(256) void lnhead_kernel(
    const float* __restrict__ x, const float* __restrict__ w,
    const float* __restrict__ hW, const float* __restrict__ hb,
    float* __restrict__ out)
{
  int ridx = blockIdx.x;
  int b = ridx / 96, r = ridx % 96;
  int row = b * S_LEN + (S_LEN - 96) + r;
  int tid = threadIdx.x;
  const float* xr = x + (size_t)row * E_DIM;
  float2 v = *(const float2*)(xr + tid * 2);
  float s = v.x + v.y, q = v.x * v.x + v.y * v.y;
#pragma unroll
  for (int off = 32; off; off >>= 1) { s += __shfl_xor(s, off); q += __shfl_xor(q, off); }
  __shared__ float ssum[4], ssq[4];
  __shared__ float lnv[512];
  __shared__ float part[8][32];
  int wv = tid >> 6;
  if ((tid & 63) == 0) { ssum[wv] = s; ssq[wv] = q; }
  __syncthreads();
  s = ssum[0] + ssum[1] + ssum[2] + ssum[3];
  q = ssq[0] + ssq[1] + ssq[2] + ssq[3];
  float mu = s * (1.f / E_DIM);
  float var = q * (1.f / E_DIM) - mu * mu;
  float rs = rsqrtf(var + 1e-5f);
  int e = tid * 2;
  lnv[e]     = (v.x - mu) * rs * w[e];
  lnv[e + 1] = (v.y - mu) * rs * w[e + 1];
  __syncthreads();
  int n = tid & 31, sl = tid >> 5;
  float p = 0.f;
  if (n < 21) {
#pragma unroll 8
    for (int kk = 0; kk < 64; kk++)
      p += lnv[sl * 64 + kk] * hW[(sl * 64 + kk) * 21 + n];
  }
  part[sl][n] = p;
  __syncthreads();
  if (tid < 21) {
    float acc = hb[tid];
#pragma unroll
    for (int j = 0; j < 8; j++) acc += part[j][tid];
    out[ridx * 21 + tid] = acc;
  }
}

// ---------------- bf16 MFMA GEMM 128x128, BK=32, 3-deep counted-vmcnt pipeline --------------
// split C: C0 f32, C1 bf16; grid (N/128, M/128). K must be 512 (NT=16).
__global__ __launch_bounds__(256) void gemm_bf16_split64(
    const u16* __restrict__ A, const u16* __restrict__ Bt,
    float* __restrict__ C0, u16* __restrict__ C1,
    int M, int N, int K, int split_col, int ldc)
{
  __shared__ u16 As0[128 * 32], As1[128 * 32], As2[128 * 32];
  __shared__ u16 Bs0[128 * 32], Bs1[128 * 32], Bs2[128 * 32];
  const int tid = threadIdx.x;
  const int row0 = blockIdx.y * 128, col0 = blockIdx.x * 128;
  const int wave = tid >> 6, lane = tid & 63;
  const int wr = wave >> 1, wc = wave & 1;   // wave tile: 64 rows x 64 cols
  const int lm = lane & 15, lq = lane >> 4;
  const int lr4 = lane >> 2;                 // 0..15 row within 16-row group
  const int cg4 = (lane & 3) ^ (lr4 & 3);    // pre-swizzled source 16B slot (4 slots/row)
  f32x4 acc[4][4] = {};
  const u16* Abase = A + (size_t)(row0 + lr4) * K + cg4 * 8;
  const u16* Bbase = Bt + (size_t)(col0 + lr4) * K + cg4 * 8;
  const int key = lm & 3;

#define STG_UP(AS, BS, K0) do { \
  _Pragma("unroll") for (int i = 0; i < 2; i++) \
    gload16(Abase + (size_t)((wave * 2 + i) * 16) * K + (K0), &AS[(wave * 2 + i) * 512]); \
  _Pragma("unroll") for (int i = 0; i < 2; i++) \
    gload16(Bbase + (size_t)((wave * 2 + i) * 16) * K + (K0), &BS[(wave * 2 + i) * 512]); \
} while (0)

#define CMP_UP(AS, BS) do { \
  short8 af[4], bfv[4]; \
  _Pragma("unroll") for (int i = 0; i < 4; i++) \
    af[i] = *(const short8*)&AS[(wr * 64 + i * 16 + lm) * 32 + ((lq ^ key) * 8)]; \
  _Pragma("unroll") for (int j = 0; j < 4; j++) \
    bfv[j] = *(const short8*)&BS[(wc * 64 + j * 16 + lm) * 32 + ((lq ^ key) * 8)]; \
  _Pragma("unroll") for (int i = 0; i < 4; i++) \
    _Pragma("unroll") for (int j = 0; j < 4; j++) \
      acc[i][j] = __builtin_amdgcn_mfma_f32_16x16x32_bf16(af[i], bfv[j], acc[i][j], 0, 0, 0); \
} while (0)

  STG_UP(As0, Bs0, 0);
  asm volatile("" ::: "memory");
  STG_UP(As1, Bs1, 32);
  asm volatile("" ::: "memory");
  STG_UP(As2, Bs2, 64);
  // 12 DMA ops/wave in flight (4 per tile, 3 tiles)
#pragma unroll
  for (int t = 0; t < 16; t++) {
    if (t <= 13)      asm volatile("s_waitcnt vmcnt(8)" ::: "memory");
    else if (t == 14) asm volatile("s_waitcnt vmcnt(4)" ::: "memory");
    else              asm volatile("s_waitcnt vmcnt(0)" ::: "memory");
    __builtin_amdgcn_sched_barrier(0);
    __builtin_amdgcn_s_barrier();
    if ((t % 3) == 0)      CMP_UP(As0, Bs0);
    else if ((t % 3) == 1) CMP_UP(As1, Bs1);
    else                   CMP_UP(As2, Bs2);
    __builtin_amdgcn_s_barrier();
    if (t + 3 < 16) {
      if ((t % 3) == 0)      STG_UP(As0, Bs0, (t + 3) * 32);
      else if ((t % 3) == 1) STG_UP(As1, Bs1, (t + 3) * 32);
      else                   STG_UP(As2, Bs2, (t + 3) * 32);
    }
  }
#undef STG_UP
#undef CMP_UP

  const bool toC1 = (col0 >= split_col);
#pragma unroll
  for (int i = 0; i < 4; i++) {
#pragma unroll
    for (int j = 0; j < 4; j++) {
      int col = col0 - (toC1 ? split_col : 0) + wc * 64 + j * 16 + lm;
#pragma unroll
      for (int r = 0; r < 4; r++) {
        int row = row0 + wr * 64 + i * 16 + lq * 4 + r;
        if (toC1) C1[(size_t)row * ldc + col] = f2bf(acc[i][j][r]);
        else C0[(size_t)row * ldc + col] = acc[i][j][r];
      }
    }
  }
}

// ---------------- bf16 MFMA GEMM 64x64 (down-proj, +=), BK=64, 3-deep pipeline --------------
// K must be 1024 (NT=16).
__global__ __launch_bounds__(256) void gemm_bf16_32(
    const u16* __restrict__ A, const u16* __restrict__ Bt,
    float* __restrict__ C, int M, int N, int K, int ldc)
{
  __shared__ u16 As0[64 * 64], As1[64 * 64], As2[64 * 64];
  __shared__ u16 Bs0[64 * 64], Bs1[64 * 64], Bs2[64 * 64];
  const int tid = threadIdx.x;
  const int row0 = blockIdx.y * 64, col0 = blockIdx.x * 64;
  const int wave = tid >> 6, lane = tid & 63;
  const int wr = wave >> 1, wc = wave & 1;   // wave tile: 32 rows x 32 cols
  const int lm = lane & 15, lq = lane >> 4;
  const int lr = lane >> 3;
  const int cg = (lane & 7) ^ lr;
  f32x4 acc[2][2] = {};
  const u16* Abase = A + (size_t)(row0 + lr) * K + cg * 8;
  const u16* Bbase = Bt + (size_t)(col0 + lr) * K + cg * 8;
  const int key = lm & 7;

#define STAGE_DN(AS, BS, K0) do { \
  _Pragma("unroll") for (int i = 0; i < 2; i++) \
    gload16(Abase + (size_t)((wave * 2 + i) * 8) * K + (K0), &AS[(wave * 2 + i) * 512]); \
  _Pragma("unroll") for (int j = 0; j < 2; j++) \
    gload16(Bbase + (size_t)((wave * 2 + j) * 8) * K + (K0), &BS[(wave * 2 + j) * 512]); \
} while (0)

#define COMPUTE_DN(AS, BS) do { \
  short8 af[2][2], bfv[2][2]; \
  _Pragma("unroll") for (int kc = 0; kc < 2; kc++) { \
    _Pragma("unroll") for (int i = 0; i < 2; i++) \
      af[kc][i] = *(const short8*)&AS[(wr * 32 + i * 16 + lm) * 64 + (((kc * 4 + lq) ^ key) * 8)]; \
    _Pragma("unroll") for (int j = 0; j < 2; j++) \
      bfv[kc][j] = *(const short8*)&BS[(wc * 32 + j * 16 + lm) * 64 + (((kc * 4 + lq) ^ key) * 8)]; \
  } \
  _Pragma("unroll") for (int kc = 0; kc < 2; kc++) \
    _Pragma("unroll") for (int i = 0; i < 2; i++) \
      _Pragma("unroll") for (int j = 0; j < 2; j++) \
        acc[i][j] = __builtin_amdgcn_mfma_f32_16x16x32_bf16(af[kc][i], bfv[kc][j], acc[i][j], 0, 0, 0); \
} while (0)

  STAGE_DN(As0, Bs0, 0);
  asm volatile("" ::: "memory");
  STAGE_DN(As1, Bs1, 64);
  asm volatile("" ::: "memory");
  STAGE_DN(As2, Bs2, 128);
  // 12 DMA ops/wave in flight (4 per tile, 3 tiles)
#pragma unroll
  for (int t = 0; t < 16; t++) {
    if (t <= 13)      asm volatile("s_waitcnt vmcnt(8)" ::: "memory");
    else if (t == 14) asm volatile("s_waitcnt vmcnt(4)" ::: "memory");
    else              asm volatile("s_waitcnt vmcnt(0)" ::: "memory");
    __builtin_amdgcn_sched_barrier(0);
    __builtin_amdgcn_s_barrier();
    if ((t % 3) == 0)      COMPUTE_DN(As0, Bs0);
    else if ((t % 3) == 1) COMPUTE_DN(As1, Bs1);
    else                   COMPUTE_DN(As2, Bs2);
    __builtin_amdgcn_s_barrier();
    if (t + 3 < 16) {
      if ((t % 3) == 0)      STAGE_DN(As0, Bs0, (t + 3) * 64);
      else if ((t % 3) == 1) STAGE_DN(As1, Bs1, (t + 3) * 64);
      else                   STAGE_DN(As2, Bs2, (t + 3) * 64);
    }
  }
#undef STAGE_DN
#undef COMPUTE_DN

#pragma unroll
  for (int i = 0; i < 2; i++) {
#pragma unroll
    for (int j = 0; j < 2; j++) {
      int col = col0 + wc * 32 + j * 16 + lm;
#pragma unroll
      for (int r = 0; r < 4; r++) {
        int row = row0 + wr * 32 + i * 16 + lq * 4 + r;
        C[(size_t)row * ldc + col] += acc[i][j][r];
      }
    }
  }
}

// ---------------- fused causal conv+SiLU+headwise qkv; 8 rows/block; writes V and V^T -------
__global__ __launch_bounds__(256) void convqkv_kernel(
    const float* __restrict__ xm,
    const float* __restrict__ cw, const float* __restrict__ cb,
    const float* __restrict__ qw, const float* __restrict__ kw, const float* __restrict__ vw,
    float* __restrict__ xc, u16* __restrict__ q, u16* __restrict__ k, u16* __restrict__ v,
    u16* __restrict__ vt)
{
  int r0 = blockIdx.x * 8;         // rows r0..r0+7, same batch (S_LEN % 8 == 0)
  int s0 = r0 & (S_LEN - 1);
  int g = threadIdx.x;             // channel group of 4
  int c0 = g * 4;
  const float* base = xm + (size_t)r0 * INNER_D + c0;

  float4 xv[11];
#pragma unroll
  for (int j = 0; j < 11; j++) {
    int ts = s0 - 3 + j;
    float4 t = {0.f, 0.f, 0.f, 0.f};
    if (ts >= 0) t = *(const float4*)(base + (ptrdiff_t)(j - 3) * INNER_D);
    xv[j] = t;
  }
  float cwv[4][4];
#pragma unroll
  for (int c = 0; c < 4; c++)
#pragma unroll
    for (int kk = 0; kk < 4; kk++) cwv[c][kk] = cw[(c0 + c) * 4 + kk];
  float cbv[4] = {cb[c0], cb[c0 + 1], cb[c0 + 2], cb[c0 + 3]};
  const float* qg = qw + g * 16;
  const float* kg = kw + g * 16;
  const float* vg = vw + g * 16;
  float qwv[16], kwv[16], vwv[16];
#pragma unroll
  for (int i = 0; i < 16; i++) { qwv[i] = qg[i]; kwv[i] = kg[i]; vwv[i] = vg[i]; }

  u32 vt_pack[4][4];   // [channel][s-pair] fully static indexing

#pragma unroll
  for (int i = 0; i < 8; i++) {
    float a0 = cbv[0], a1 = cbv[1], a2 = cbv[2], a3 = cbv[3];
#pragma unroll
    for (int kk = 0; kk < 4; kk++) {
      float4 xvv = xv[i + kk];
      a0 += xvv.x * cwv[0][kk];
      a1 += xvv.y * cwv[1][kk];
      a2 += xvv.z * cwv[2][kk];
      a3 += xvv.w * cwv[3][kk];
    }
    a0 = a0 / (1.f + __expf(-a0));
    a1 = a1 / (1.f + __expf(-a1));
    a2 = a2 / (1.f + __expf(-a2));
    a3 = a3 / (1.f + __expf(-a3));
    float4 accv = {a0, a1, a2, a3};
    *(float4*)(xc + (size_t)(r0 + i) * INNER_D + c0) = accv;

    float xcv[4] = {a0, a1, a2, a3};
    float xmv[4] = {xv[i + 3].x, xv[i + 3].y, xv[i + 3].z, xv[i + 3].w};
    ushort4 qs, ks, vs;
    u16* qp = (u16*)&qs; u16* kp = (u16*)&ks; u16* vp = (u16*)&vs;
#pragma unroll
    for (int o = 0; o < 4; o++) {
      float aq = 0.f, ak = 0.f, av = 0.f;
#pragma unroll
      for (int d = 0; d < 4; d++) {
        aq += xcv[d] * qwv[o * 4 + d];
        ak += xcv[d] * kwv[o * 4 + d];
        av += xmv[d] * vwv[o * 4 + d];
      }
      qp[o] = f2bf(aq); kp[o] = f2bf(ak);
      u16 vv = f2bf(av);
      vp[o] = vv;
      if ((i & 1) == 0) vt_pack[o][i >> 1] = (u32)vv;
      else              vt_pack[o][i >> 1] |= ((u32)vv) << 16;
    }
    size_t off = (size_t)(r0 + i) * INNER_D + c0;
    *(ushort4*)(q + off) = qs;
    *(ushort4*)(k + off) = ks;
    *(ushort4*)(v + off) = vs;
  }
  // V^T: vt[b][d][s], 16B (8 s-values) per channel
  u16* vtb = vt + ((size_t)((r0 >> 10) * INNER_D + c0)) * S_LEN + s0;
#pragma unroll
  for (int c = 0; c < 4; c++) {
    uint4 wv4 = {vt_pack[c][0], vt_pack[c][1], vt_pack[c][2], vt_pack[c][3]};
    *(uint4*)(vtb + (size_t)c * S_LEN) = wv4;
  }
}

// ---------------- gates as skinny MFMA GEMM: C[2048,16] = qkv[2048,3072] @ W^T ----------------
__global__ __launch_bounds__(256) void gates_mfma_kernel(
    const u16* __restrict__ q, const u16* __restrict__ k, const u16* __restrict__ v,
    const u16* __restrict__ whi, const u16* __restrict__ wlo,
    const float* __restrict__ igb, const float* __restrict__ fgb,
    float* __restrict__ ig, float* __restrict__ fg)
{
  const int blk = blockIdx.x;      // 0..127
  const int tid = threadIdx.x;
  const int wave = tid >> 6, lane = tid & 63;
  const int lm = lane & 15, lq = lane >> 4;
  const int grow = blk * 16 + lm;
  const u16* parts[3] = {q, k, v};
  f32x4 acc = {};
#pragma unroll 4
  for (int kc = 0; kc < 24; kc++) {
    int k0 = wave * 768 + kc * 32;
    int part = k0 >> 10;
    int idx = (k0 & 1023) + lq * 8;
    S8 a, bh_, bl_;
    a.q = *(const uint4*)(parts[part] + (size_t)grow * INNER_D + idx);
    bh_.q = *(const uint4*)(whi + (size_t)lm * 3072 + k0 + lq * 8);
    bl_.q = *(const uint4*)(wlo + (size_t)lm * 3072 + k0 + lq * 8);
    __builtin_amdgcn_s_setprio(1);
    acc = __builtin_amdgcn_mfma_f32_16x16x32_bf16(a.v, bh_.v, acc, 0, 0, 0);
    acc = __builtin_amdgcn_mfma_f32_16x16x32_bf16(a.v, bl_.v, acc, 0, 0, 0);
    __builtin_amdgcn_s_setprio(0);
  }
  __shared__ float red[4][16][17];
#pragma unroll
  for (int r = 0; r < 4; r++) red[wave][lq * 4 + r][lm] = acc[r];
  __syncthreads();
  if (wave == 0) {
#pragma unroll
    for (int r = 0; r < 4; r++) {
      int row = lq * 4 + r;
      float sum = red[0][row][lm] + red[1][row][lm] + red[2][row][lm] + red[3][row][lm];
      int growr = blk * 16 + row;
      int b = growr >> 10, s = growr & (S_LEN - 1);
      if (lm < 8) ig[((size_t)(b * NHEAD + lm) << 10) + s] = sum + igb[lm];
      else        fg[((size_t)(b * NHEAD + (lm - 8)) << 10) + s] = sum + fgb[lm - 8];
    }
  }
}

// ---------------- per-(b,h) scans, shuffle-based ----------------
__global__ __launch_bounds__(1024) void scan_kernel(
    const float* __restrict__ ig, const float* __restrict__ fg,
    float* __restrict__ a, float* __restrict__ rm, float* __restrict__ enm)
{
  int bh = blockIdx.x;
  int t = threadIdx.x;
  int lane = t & 63, wv = t >> 6;
  __shared__ float sw[16];
  size_t o = ((size_t)bh << 10) + t;
  float f = fg[o];
  float lf = (f >= 0.f) ? -log1pf(__expf(-f)) : f - log1pf(__expf(f));
  float v = lf;
#pragma unroll
  for (int off = 1; off < 64; off <<= 1) {
    float u = __shfl_up(v, off);
    if (lane >= off) v += u;
  }
  if (lane == 63) sw[wv] = v;
  __syncthreads();
  float pre = 0.f;
  for (int w = 0; w < wv; w++) pre += sw[w];
  float cs = v + pre;
  float av = ig[o] - cs;
  a[o] = av;
  float m = av;
#pragma unroll
  for (int off = 1; off < 64; off <<= 1) {
    float u = __shfl_up(m, off);
    if (lane >= off) m = fmaxf(m, u);
  }
  __syncthreads();
  if (lane == 63) sw[wv] = m;
  __syncthreads();
  float pm = -3.4e38f;
  for (int w = 0; w < wv; w++) pm = fmaxf(pm, sw[w]);
  float rmx = fmaxf(m, pm);
  rm[o] = rmx;
  enm[o] = __expf(-(cs + rmx));
}

// ---------------- balanced fine split-K MFMA attention (<=4 tiles/job, 40 jobs/bh) ----------
__device__ __constant__ int c_qt[40] = {15,15,15,15, 14,14,14,14, 13,13,13,13, 12,12,12,12,
                                        11,11,11, 10,10,10, 9,9,9, 8,8,8,
                                        7,7, 6,6, 5,5, 4,4, 3, 2, 1, 0};
__device__ __constant__ int c_k0[40] = {0,4,8,12, 0,4,8,12, 0,4,8,11, 0,4,7,10,
                                        0,4,8, 0,4,8, 0,4,7, 0,3,6,
                                        0,4, 0,4, 0,3, 0,3, 0, 0, 0, 0};
__device__ __constant__ int c_k1[40] = {4,8,12,16, 4,8,12,15, 4,8,11,14, 4,7,10,13,
                                        4,8,12, 4,8,11, 4,7,10, 3,6,9,
                                        4,8, 4,7, 3,6, 3,5, 4, 3, 2, 1};
__device__ __constant__ int c_md[40] = {1,2,3,4, 1,2,3,4, 1,2,3,4, 1,2,3,4,
                                        1,2,3, 1,2,3, 1,2,3, 1,2,3,
                                        1,2, 1,2, 1,2, 1,2, 0, 0, 0, 0};

#define HP_SLOT 1572864   // 16 bh * 12 qr * 64 rows * 128
#define SC_SLOT 12288     // 16 bh * 12 qr * 64 rows

__global__ __launch_bounds__(256) void attn_mfma_kernel(
    const u16* __restrict__ qhg, const u16* __restrict__ khg, const u16* __restrict__ vtg,
    const float* __restrict__ a_arr, const float* __restrict__ rm_arr, const float* __restrict__ enm_arr,
    const float* __restrict__ xc, const u16* __restrict__ zh,
    const float* __restrict__ skip, const float* __restrict__ onw,
    u16* __restrict__ hs, float* __restrict__ hpart, float* __restrict__ scpart)
{
  const int bh = blockIdx.x;
  const int job = blockIdx.y;
  const int qt = c_qt[job], k0t = c_k0[job], k1t = c_k1[job], mode = c_md[job];
  const int b = bh >> 3, h = bh & 7;
  const int s0 = qt * 64;
  const int tid = threadIdx.x;
  const int wave = tid >> 6, lane = tid & 63;
  const int lm = lane & 15, lq = lane >> 4;
  const size_t rowbase = (size_t)b * S_LEN;
  const int c0 = h * DHEAD;

  __shared__ u16 Ks0[64 * 128], Ks1[64 * 128];  // [t][128], 16B slots XOR-swizzled by (t&7)
  __shared__ u16 Vt0[128 * 64], Vt1[128 * 64];  // [d][64],  16B slots XOR-swizzled by (d&7)
  __shared__ u16 Ws[64 * 72];

  short8 aq[4];
  {
    const u16* qp = qhg + (rowbase + s0 + wave * 16 + lm) * INNER_D + c0 + lq * 8;
#pragma unroll
    for (int kc = 0; kc < 4; kc++) {
      S8 tmp; tmp.q = *(const uint4*)(qp + kc * 32);
      aq[kc] = tmp.v;
    }
  }
  const float scale = 0.08838834764831845f;  // 1/sqrt(128)
  float rmv[4], er[4];
#pragma unroll
  for (int r = 0; r < 4; r++) {
    rmv[r] = rm_arr[(size_t)bh * S_LEN + s0 + wave * 16 + lq * 4 + r];
    er[r] = scale * __expf(-rmv[r]);   // hoisted: exp(ea-rm) = exp(ea)*exp(-rm)
  }

  f32x4 accH[8] = {};
  float sc_acc[4] = {0.f, 0.f, 0.f, 0.f};
  const int lr16 = lane >> 4;      // 0..3 (K rows: 256B each, 16 lanes/row)
  const int ls16 = lane & 15;      // 16B slot within 256B K row
  const int lr8 = lane >> 3;       // 0..7  (V rows: 128B each, 8 lanes/row)
  const int cgv = (lane & 7) ^ lr8;  // pre-swizzled V source slot
  const u16* vtbase = vtg + ((size_t)b * INNER_D + c0) * S_LEN;

  float ae0[4], ae1[4];

#define PREF(KS, VS, AE, T0) do { \
  _Pragma("unroll") for (int j = 0; j < 4; j++) { \
    int rK = (wave * 4 + j) * 4 + lr16; \
    int cgk = ls16 ^ (rK & 7); \
    gload16(khg + (rowbase + (T0) + rK) * INNER_D + c0 + cgk * 8, &KS[(wave * 4 + j) * 512]); \
  } \
  _Pragma("unroll") for (int j = 0; j < 4; j++) { \
    int rV = (wave * 4 + j) * 8 + lr8; \
    gload16(vtbase + (size_t)rV * S_LEN + (T0) + cgv * 8, &VS[(wave * 4 + j) * 512]); \
  } \
  _Pragma("unroll") for (int cb = 0; cb < 4; cb++) \
    AE[cb] = a_arr[(size_t)bh * S_LEN + (T0) + cb * 16 + lm]; \
} while (0)

#define QK_STEP(KS, PACC) do { \
  __builtin_amdgcn_s_setprio(1); \
  _Pragma("unroll") for (int kc = 0; kc < 4; kc++) \
    _Pragma("unroll") for (int cb = 0; cb < 4; cb++) { \
      short8 bk = *(const short8*)&KS[(cb * 16 + lm) * 128 + (((kc * 4 + lq) ^ (lm & 7)) * 8)]; \
      PACC[cb] = __builtin_amdgcn_mfma_f32_16x16x32_bf16(aq[kc], bk, PACC[cb], 0, 0, 0); \
    } \
  __builtin_amdgcn_s_setprio(0); \
} while (0)

#define W_PV(AE, VT, T0, PACC) do { \
  float wpart[4] = {0.f, 0.f, 0.f, 0.f}; \
  _Pragma("unroll") for (int cb = 0; cb < 4; cb++) { \
    int colg = (T0) + cb * 16 + lm; \
    float ec = __expf(AE[cb]); \
    _Pragma("unroll") for (int r = 0; r < 4; r++) { \
      int rowg = s0 + wave * 16 + lq * 4 + r; \
      float wv = PACC[cb][r] * ec * er[r]; \
      if (colg > rowg) wv = 0.f; \
      wpart[r] += wv; \
      Ws[(wave * 16 + lq * 4 + r) * 72 + cb * 16 + lm] = f2bf(wv); \
    } \
  } \
  _Pragma("unroll") for (int r = 0; r < 4; r++) { \
    float sr = wpart[r]; \
    sr += __shfl_xor(sr, 1); sr += __shfl_xor(sr, 2); \
    sr += __shfl_xor(sr, 4); sr += __shfl_xor(sr, 8); \
    sc_acc[r] += sr; \
  } \
  __builtin_amdgcn_s_setprio(1); \
  _Pragma("unroll") for (int kc = 0; kc < 2; kc++) { \
    short8 aw = *(const short8*)&Ws[(wave * 16 + lm) * 72 + kc * 32 + lq * 8]; \
    _Pragma("unroll") for (int nb = 0; nb < 8; nb++) { \
      short8 bv = *(const short8*)&VT[(nb * 16 + lm) * 64 + (((kc * 4 + lq) ^ (lm & 7)) * 8)]; \
      accH[nb] = __builtin_amdgcn_mfma_f32_16x16x32_bf16(aw, bv, accH[nb], 0, 0, 0); \
    } \
  } \
  __builtin_amdgcn_s_setprio(0); \
} while (0)

  int kt = k0t;
  PREF(Ks0, Vt0, ae0, kt * 64);
  asm volatile("" ::: "memory");
  if (kt + 1 < k1t) PREF(Ks1, Vt1, ae1, (kt + 1) * 64);

  while (true) {
    {
      if (kt + 1 < k1t) asm volatile("s_waitcnt vmcnt(12)" ::: "memory");
      else              asm volatile("s_waitcnt vmcnt(0)" ::: "memory");
      __builtin_amdgcn_sched_barrier(0);
      __builtin_amdgcn_s_barrier();
      f32x4 pacc[4] = {};
      QK_STEP(Ks0, pacc);
      W_PV(ae0, Vt0, kt * 64, pacc);
      __builtin_amdgcn_s_barrier();
      if (kt + 2 < k1t) PREF(Ks0, Vt0, ae0, (kt + 2) * 64);
      kt++;
      if (kt >= k1t) break;
    }
    {
      if (kt + 1 < k1t) asm volatile("s_waitcnt vmcnt(12)" ::: "memory");
      else              asm volatile("s_waitcnt vmcnt(0)" ::: "memory");
      __builtin_amdgcn_sched_barrier(0);
      __builtin_amdgcn_s_barrier();
      f32x4 pacc[4] = {};
      QK_STEP(Ks1, pacc);
      W_PV(ae1, Vt1, kt * 64, pacc);
      __builtin_amdgcn_s_barrier();
      if (kt + 2 < k1t) PREF(Ks1, Vt1, ae1, (kt + 2) * 64);
      kt++;
      if (kt >= k1t) break;
    }
  }
#undef PREF
#undef QK_STEP
#undef W_PV

  if (mode != 0) {
    int slot = mode - 1;
    int qr = qt - 4;
    float* Hp = hpart + (size_t)slot * HP_SLOT + ((size_t)(bh * 12 + qr)) * 8192;
    float* sp = scpart + slot * SC_SLOT + (bh * 12 + qr) * 64;
#pragma unroll
    for (int r = 0; r < 4; r++) {
      int row = wave * 16 + lq * 4 + r;
      if (lm == 0) sp[row] = sc_acc[r];
#pragma unroll
      for (int nb = 0; nb < 8; nb++)
        Hp[row * 128 + nb * 16 + lm] = accH[nb][r];
    }
    return;
  }

  float inv[4], muv[4], rsv[4];
#pragma unroll
  for (int r = 0; r < 4; r++) {
    int rowg = s0 + wave * 16 + lq * 4 + r;
    float nrm = fmaxf(fabsf(sc_acc[r]), enm_arr[(size_t)bh * S_LEN + rowg]);
    inv[r] = 1.f / (nrm + 1e-6f);
  }
#pragma unroll
  for (int r = 0; r < 4; r++) {
    float s = 0.f, qq = 0.f;
#pragma unroll
    for (int nb = 0; nb < 8; nb++) {
      float hv = accH[nb][r] * inv[r];
      accH[nb][r] = hv;
      s += hv; qq += hv * hv;
    }
    s += __shfl_xor(s, 1); s += __shfl_xor(s, 2); s += __shfl_xor(s, 4); s += __shfl_xor(s, 8);
    qq += __shfl_xor(qq, 1); qq += __shfl_xor(qq, 2); qq += __shfl_xor(qq, 4); qq += __shfl_xor(qq, 8);
    float mu = s * (1.f / DHEAD);
    float var = qq * (1.f / DHEAD) - mu * mu;
    muv[r] = mu;
    rsv[r] = rsqrtf(var + 1e-5f);
  }
  float ow[8], sk[8];
#pragma unroll
  for (int nb = 0; nb < 8; nb++) {
    ow[nb] = onw[c0 + nb * 16 + lm];
    sk[nb] = skip[c0 + nb * 16 + lm];
  }
#pragma unroll
  for (int r = 0; r < 4; r++) {
    int rowg = s0 + wave * 16 + lq * 4 + r;
    size_t base = (rowbase + rowg) * INNER_D + c0;
#pragma unroll
    for (int nb = 0; nb < 8; nb++) {
      int d = nb * 16 + lm;
      float xcv = xc[base + d];
      float zv = bf2f(zh[base + d]);
      float hn = (accH[nb][r] - muv[r]) * rsv[r] * ow[nb] + sk[nb] * xcv;
      float o = hn * (zv / (1.f + __expf(-zv)));
      hs[base + d] = f2bf(o);
    }
  }
}

// combine 2..4 partial slots for rows s >= 256; one wave per row (12288 rows).
__global__ __launch_bounds__(256) void attn_combine_kernel(
    const float* __restrict__ hpart, const float* __restrict__ scpart,
    const float* __restrict__ enm,
    const float* __restrict__ xc, const u16* __restrict__ zh,
    const float* __restrict__ skip, const float* __restrict__ onw,
    u16* __restrict__ hs)
{
  int wave = threadIdx.x >> 6, lane = threadIdx.x & 63;
  int gid = blockIdx.x * 4 + wave;   // 0..12287
  int bh = gid / 768;
  int rr = gid % 768;
  int qr = rr >> 6, row = rr & 63;
  int b = bh >> 3, hh = bh & 7;
  int s = (qr + 4) * 64 + row;
  int nsl = 2 + (qr >> 2);           // qt4-7:2, qt8-11:3, qt12-15:4
  size_t off = (((size_t)(bh * 12 + qr)) * 64 + row) * 128 + lane * 2;
  int sidx = (bh * 12 + qr) * 64 + row;
  float hx = 0.f, hy = 0.f, sc = 0.f;
  for (int sl = 0; sl < nsl; sl++) {
    float2 hp = *(const float2*)(hpart + (size_t)sl * HP_SLOT + off);
    hx += hp.x; hy += hp.y;
    sc += scpart[sl * SC_SLOT + sidx];
  }
  float nrm = fmaxf(fabsf(sc), enm[(size_t)bh * S_LEN + s]);
  float inv = 1.f / (nrm + 1e-6f);
  hx *= inv; hy *= inv;
  float sm = hx + hy, sq = hx * hx + hy * hy;
#pragma unroll
  for (int off2 = 32; off2; off2 >>= 1) { sm += __shfl_xor(sm, off2); sq += __shfl_xor(sq, off2); }
  float mu = sm * (1.f / DHEAD);
  float var = sq * (1.f / DHEAD) - mu * mu;
  float rs = rsqrtf(var + 1e-5f);
  int c0 = hh * DHEAD + lane * 2;
  size_t base = ((size_t)(b * S_LEN + s)) * INNER_D + c0;
  float2 xc2 = *(const float2*)(xc + base);
  ushort2 z2u = *(const ushort2*)(zh + base);
  float z2x = bf2f(z2u.x), z2y = bf2f(z2u.y);
  float skx = skip[c0], sky = skip[c0 + 1];
  float owx = onw[c0],  owy = onw[c0 + 1];
  ushort2 o;
  o.x = f2bf(((hx - mu) * rs * owx + skx * xc2.x) * (z2x / (1.f + __expf(-z2x))));
  o.y = f2bf(((hy - mu) * rs * owy + sky * xc2.y) * (z2y / (1.f + __expf(-z2y))));
  *(ushort2*)(hs + base) = o;
}

extern "C" void kernel_launch(void* const* d_in, const int* in_sizes, int n_in,
                              void* d_out, int out_size, void* d_ws, size_t ws_size,
                              hipStream_t stream)
{
  const float* x_enc   = (const float*)d_in[0];
  const float* x_mark  = (const float*)d_in[1];
  const float* emb_W   = (const float*)d_in[4];
  const float* emb_b   = (const float*)d_in[5];
  const float* ln_w    = (const float*)d_in[6];
  const float* up_W    = (const float*)d_in[7];
  const float* conv_W  = (const float*)d_in[8];
  const float* conv_b  = (const float*)d_in[9];
  const float* q_W     = (const float*)d_in[10];
  const float* k_W     = (const float*)d_in[11];
  const float* v_W     = (const float*)d_in[12];
  const float* ig_W    = (const float*)d_in[13];
  const float* ig_b    = (const float*)d_in[14];
  const float* fg_W    = (const float*)d_in[15];
  const float* fg_b    = (const float*)d_in[16];
  const float* skip_w  = (const float*)d_in[17];
  const float* onorm_w = (const float*)d_in[18];
  const float* down_W  = (const float*)d_in[19];
  const float* post_ln = (const float*)d_in[20];
  const float* head_W  = (const float*)d_in[21];
  const float* head_b  = (const float*)d_in[22];

  float* p = (float*)d_ws;
  float* x    = p; p += 1048576;   // 2048*512 f32
  float* xm   = p; p += 2097152;   // 2048*1024 f32; reused as hsbh bf16 after convqkv
  float* xc   = p; p += 2097152;
  float* igb_ = p; p += 16384;
  float* fgb_ = p; p += 16384;
  float* ab   = p; p += 16384;
  float* rmb  = p; p += 16384;
  float* enmb = p; p += 16384;
  u16* qhb = (u16*)p; p += 1048576;  // 2048*1024 u16
  u16* khb = (u16*)p; p += 1048576;
  u16* vhb = (u16*)p; p += 1048576;
  u16* zh  = (u16*)p; p += 1048576;  // 2048*1024 u16 (full size — fixes prior overlap into xnh)
  u16* xnh = (u16*)p; p += 524288;   // 2048*512 u16
  u16* upWtA = (u16*)p; p += 2097152; // 4 x 2048x512 u16
  u16* dnWtA = (u16*)p; p += 1048576; // 4 x 512x1024 u16
  u16* gtwH = (u16*)p; p += 98304;    // 4 x 16 x 3072 u16
  u16* gtwL = (u16*)p; p += 98304;
  float* hpart = p; p += 6291456;     // 4 slots x 16 bh x 12 qr x 64 x 128 f32
  float* scpart = p; p += 49152;      // 4 slots x 16 x 12 x 64
  u16* vtg = (u16*)p; p += 1048576;   // 2 x 1024 x 1024 u16 (V^T per layer)
  u16* hsbh = (u16*)xm;

  // one merged prep launch: up/down weight transposes + gates weights + embedding
  prep_kernel<<<4352, 256, 0, stream>>>(
      up_W, upWtA, down_W, dnWtA, ig_W, fg_W, gtwH, gtwL,
      x_enc, x_mark, emb_W, emb_b, x);

  for (int L = 0; L < 4; L++) {
    ln_kernel<<<2048, 256, 0, stream>>>(x, ln_w + L * 512, xnh);
    gemm_bf16_split64<<<dim3(16, 16), 256, 0, stream>>>(
        xnh, upWtA + (size_t)L * 1048576, xm, zh, 2048, 2048, 512, 1024, 1024);
    convqkv_kernel<<<256, 256, 0, stream>>>(
        xm, conv_W + L * 4096, conv_b + L * 1024,
        q_W + L * 4096, k_W + L * 4096, v_W + L * 4096,
        xc, qhb, khb, vhb, vtg);
    gates_mfma_kernel<<<128, 256, 0, stream>>>(
        qhb, khb, vhb, gtwH + (size_t)L * 49152, gtwL + (size_t)L * 49152,
        ig_b + L * 8, fg_b + L * 8, igb_, fgb_);
    scan_kernel<<<16, 1024, 0, stream>>>(igb_, fgb_, ab, rmb, enmb);
    attn_mfma_kernel<<<dim3(16, 40), 256, 0, stream>>>(
        qhb, khb, vtg, ab, rmb, enmb, xc, zh,
        skip_w + L * 1024, onorm_w + L * 1024, hsbh, hpart, scpart);
    attn_combine_kernel<<<3072, 256, 0, stream>>>(
        hpart, scpart, enmb, xc, zh, skip_w + L * 1024, onorm_w + L * 1024, hsbh);
    gemm_bf16_32<<<dim3(8, 32), 256, 0, stream>>>(
        hsbh, dnWtA + (size_t)L * 524288, x, 2048, 512, 1024, 512);
  }

  lnhead_kernel<<<192, 256, 0, stream>>>(x, post_ln, head_W, head_b, (float*)d_out);
}

// Round 10
// 449.660 us; speedup vs baseline: 1.0241x; 1.0241x over previous
//
#include <hip/hip_runtime.h>
#include <hip/hip_bf16.h>

#define S_LEN 1024
#define E_DIM 512
#define INNER_D 1024
#define NHEAD 8
#define DHEAD 128

typedef unsigned short u16;
typedef unsigned int u32;
typedef __attribute__((ext_vector_type(8))) short short8;
typedef __attribute__((ext_vector_type(4))) float f32x4;

union S8 { short8 v; u16 u[8]; uint4 q; };

__device__ __forceinline__ u16 f2bf(float f) {
  u32 u = __float_as_uint(f);
  u32 r = u + 0x7FFFu + ((u >> 16) & 1u);
  return (u16)(r >> 16);
}
__device__ __forceinline__ float bf2f(u16 u) { return __uint_as_float(((u32)u) << 16); }

// direct global -> LDS (16B per lane). LDS dest = wave-uniform base + lane*16B (linear).
__device__ __forceinline__ void gload16(const u16* g, u16* l) {
  __builtin_amdgcn_global_load_lds((const __attribute__((address_space(1))) void*)g,
                                   (__attribute__((address_space(3))) void*)l, 16, 0, 0);
}

// ---------------- merged one-time prep: transposes + gates weights + embedding ----------------
__device__ __forceinline__ void prep_transpose(
    const float* __restrict__ in, u16* __restrict__ out, int K, int N,
    int k0, int n0, int t, u16 (*T)[72])
{
  int kr = t >> 2, nseg = (t & 3) * 16;
  const float* src = in + (size_t)(k0 + kr) * N + n0 + nseg;
#pragma unroll
  for (int j = 0; j < 16; j++) T[kr][nseg + j] = f2bf(src[j]);
  __syncthreads();
  int nr = t >> 2, kseg = (t & 3) * 16;
  u32 u[8];
#pragma unroll
  for (int rr = 0; rr < 8; rr++) {
    u32 lo = T[kseg + 2 * rr][nr];
    u32 hi = T[kseg + 2 * rr + 1][nr];
    u[rr] = lo | (hi << 16);
  }
  u16* dst = out + (size_t)(n0 + nr) * K + k0 + kseg;
  uint4 w0 = {u[0], u[1], u[2], u[3]};
  uint4 w1 = {u[4], u[5], u[6], u[7]};
  *(uint4*)dst = w0;
  *(uint4*)(dst + 8) = w1;
}

__global__ __launch_bounds__(256) void prep_kernel(
    const float* __restrict__ up_W, u16* __restrict__ upWt,
    const float* __restrict__ down_W, u16* __restrict__ dnWt,
    const float* __restrict__ igW, const float* __restrict__ fgW,
    u16* __restrict__ ghi, u16* __restrict__ glo,
    const float* __restrict__ xe, const float* __restrict__ xmk,
    const float* __restrict__ eW, const float* __restrict__ eb,
    float* __restrict__ x)
{
  __shared__ u16 T[64][72];
  __shared__ float in_s[25];
  int id = blockIdx.x;
  int t = threadIdx.x;
  if (id < 1024) {                     // up_W transpose: [L][512][2048] -> [L][2048][512]
    int bx = id & 7, rest = id >> 3;
    int by = rest & 31, L = rest >> 5;
    prep_transpose(up_W + (size_t)L * 512 * 2048, upWt + (size_t)L * 1048576,
                   512, 2048, bx * 64, by * 64, t, T);
  } else if (id < 1536) {              // down_W transpose: [L][1024][512] -> [L][512][1024]
    int id2 = id - 1024;
    int bx = id2 & 15, rest = id2 >> 4;
    int by = rest & 7, L = rest >> 3;
    prep_transpose(down_W + (size_t)L * 1024 * 512, dnWt + (size_t)L * 524288,
                   1024, 512, bx * 64, by * 64, t, T);
  } else if (id < 2304) {              // gates weights: hi/lo split transpose
    int id3 = id - 1536;
    int bx = id3 % 12, rest = id3 / 12;
    int n = rest & 15, L = rest >> 4;
    int k = bx * 256 + t;
    const float* W = ((n < 8) ? igW : fgW) + (size_t)L * 24576;
    float v = W[(size_t)k * 8 + (n & 7)];
    u16 h = f2bf(v);
    u16 l = f2bf(v - bf2f(h));
    size_t o = ((size_t)L * 16 + n) * 3072 + k;
    ghi[o] = h;
    glo[o] = l;
  } else {                             // embedding, one row per block
    int row = id - 2304;
    if (t < 21) in_s[t] = xe[row * 21 + t];
    else if (t < 25) in_s[t] = xmk[row * 4 + t - 21];
    __syncthreads();
#pragma unroll
    for (int rep = 0; rep < 2; rep++) {
      int e = t + rep * 256;
      float acc = eb[e];
#pragma unroll
      for (int i = 0; i < 25; i++) acc += in_s[i] * eW[i * E_DIM + e];
      x[(size_t)row * E_DIM + e] = acc;
    }
  }
}

// ---------------- layernorm -> bf16 ----------------
__global__ __launch_bounds__(256) void ln_kernel(
    const float* __restrict__ x, const float* __restrict__ w, u16* __restrict__ out)
{
  int row = blockIdx.x, tid = threadIdx.x;
  const float* xr = x + (size_t)row * E_DIM;
  float2 v = *(const float2*)(xr + tid * 2);
  float s = v.x + v.y, q = v.x * v.x + v.y * v.y;
#pragma unroll
  for (int off = 32; off; off >>= 1) { s += __shfl_xor(s, off); q += __shfl_xor(q, off); }
  __shared__ float ssum[4], ssq[4];
  int wv = tid >> 6;
  if ((tid & 63) == 0) { ssum[wv] = s; ssq[wv] = q; }
  __syncthreads();
  s = ssum[0] + ssum[1] + ssum[2] + ssum[3];
  q = ssq[0] + ssq[1] + ssq[2] + ssq[3];
  float mu = s * (1.f / E_DIM);
  float var = q * (1.f / E_DIM) - mu * mu;
  float rs = rsqrtf(var + 1e-5f);
  int e = tid * 2;
  ushort2 o;
  o.x = f2bf((v.x - mu) * rs * w[e]);
  o.y = f2bf((v.y - mu) * rs * w[e + 1]);
  *(ushort2*)(out + (size_t)row * E_DIM + e) = o;
}

// ---------------- fused final layernorm + head (one block per output row) ----------------
__global__ __launch_bounds__(256) void lnhead_kernel(
    const float* __restrict__ x, const float* __restrict__ w,
    const float* __restrict__ hW, const float* __restrict__ hb,
    float* __restrict__ out)
{
  int ridx = blockIdx.x;
  int b = ridx / 96, r = ridx % 96;
  int row = b * S_LEN + (S_LEN - 96) + r;
  int tid = threadIdx.x;
  const float* xr = x + (size_t)row * E_DIM;
  float2 v = *(const float2*)(xr + tid * 2);
  float s = v.x + v.y, q = v.x * v.x + v.y * v.y;
#pragma unroll
  for (int off = 32; off; off >>= 1) { s += __shfl_xor(s, off); q += __shfl_xor(q, off); }
  __shared__ float ssum[4], ssq[4];
  __shared__ float lnv[512];
  __shared__ float part[8][32];
  int wv = tid >> 6;
  if ((tid & 63) == 0) { ssum[wv] = s; ssq[wv] = q; }
  __syncthreads();
  s = ssum[0] + ssum[1] + ssum[2] + ssum[3];
  q = ssq[0] + ssq[1] + ssq[2] + ssq[3];
  float mu = s * (1.f / E_DIM);
  float var = q * (1.f / E_DIM) - mu * mu;
  float rs = rsqrtf(var + 1e-5f);
  int e = tid * 2;
  lnv[e]     = (v.x - mu) * rs * w[e];
  lnv[e + 1] = (v.y - mu) * rs * w[e + 1];
  __syncthreads();
  int n = tid & 31, sl = tid >> 5;
  float p = 0.f;
  if (n < 21) {
#pragma unroll 8
    for (int kk = 0; kk < 64; kk++)
      p += lnv[sl * 64 + kk] * hW[(sl * 64 + kk) * 21 + n];
  }
  part[sl][n] = p;
  __syncthreads();
  if (tid < 21) {
    float acc = hb[tid];
#pragma unroll
    for (int j = 0; j < 8; j++) acc += part[j][tid];
    out[ridx * 21 + tid] = acc;
  }
}

// ---------------- bf16 MFMA GEMM 128x128, BK=32, 3-deep counted-vmcnt pipeline --------------
// split C: C0 f32, C1 bf16; grid (N/128, M/128). K must be 512 (NT=16).
__global__ __launch_bounds__(256) void gemm_bf16_split64(
    const u16* __restrict__ A, const u16* __restrict__ Bt,
    float* __restrict__ C0, u16* __restrict__ C1,
    int M, int N, int K, int split_col, int ldc)
{
  __shared__ u16 As0[128 * 32], As1[128 * 32], As2[128 * 32];
  __shared__ u16 Bs0[128 * 32], Bs1[128 * 32], Bs2[128 * 32];
  const int tid = threadIdx.x;
  const int row0 = blockIdx.y * 128, col0 = blockIdx.x * 128;
  const int wave = tid >> 6, lane = tid & 63;
  const int wr = wave >> 1, wc = wave & 1;   // wave tile: 64 rows x 64 cols
  const int lm = lane & 15, lq = lane >> 4;
  const int lr4 = lane >> 2;                 // 0..15 row within 16-row group
  const int cg4 = (lane & 3) ^ (lr4 & 3);    // pre-swizzled source 16B slot (4 slots/row)
  f32x4 acc[4][4] = {};
  const u16* Abase = A + (size_t)(row0 + lr4) * K + cg4 * 8;
  const u16* Bbase = Bt + (size_t)(col0 + lr4) * K + cg4 * 8;
  const int key = lm & 3;

#define STG_UP(AS, BS, K0) do { \
  _Pragma("unroll") for (int i = 0; i < 2; i++) \
    gload16(Abase + (size_t)((wave * 2 + i) * 16) * K + (K0), &AS[(wave * 2 + i) * 512]); \
  _Pragma("unroll") for (int i = 0; i < 2; i++) \
    gload16(Bbase + (size_t)((wave * 2 + i) * 16) * K + (K0), &BS[(wave * 2 + i) * 512]); \
} while (0)

#define CMP_UP(AS, BS) do { \
  short8 af[4], bfv[4]; \
  _Pragma("unroll") for (int i = 0; i < 4; i++) \
    af[i] = *(const short8*)&AS[(wr * 64 + i * 16 + lm) * 32 + ((lq ^ key) * 8)]; \
  _Pragma("unroll") for (int j = 0; j < 4; j++) \
    bfv[j] = *(const short8*)&BS[(wc * 64 + j * 16 + lm) * 32 + ((lq ^ key) * 8)]; \
  _Pragma("unroll") for (int i = 0; i < 4; i++) \
    _Pragma("unroll") for (int j = 0; j < 4; j++) \
      acc[i][j] = __builtin_amdgcn_mfma_f32_16x16x32_bf16(af[i], bfv[j], acc[i][j], 0, 0, 0); \
} while (0)

  STG_UP(As0, Bs0, 0);
  asm volatile("" ::: "memory");
  STG_UP(As1, Bs1, 32);
  asm volatile("" ::: "memory");
  STG_UP(As2, Bs2, 64);
  // 12 DMA ops/wave in flight (4 per tile, 3 tiles)
#pragma unroll
  for (int t = 0; t < 16; t++) {
    if (t <= 13)      asm volatile("s_waitcnt vmcnt(8)" ::: "memory");
    else if (t == 14) asm volatile("s_waitcnt vmcnt(4)" ::: "memory");
    else              asm volatile("s_waitcnt vmcnt(0)" ::: "memory");
    __builtin_amdgcn_sched_barrier(0);
    __builtin_amdgcn_s_barrier();
    if ((t % 3) == 0)      CMP_UP(As0, Bs0);
    else if ((t % 3) == 1) CMP_UP(As1, Bs1);
    else                   CMP_UP(As2, Bs2);
    __builtin_amdgcn_s_barrier();
    if (t + 3 < 16) {
      if ((t % 3) == 0)      STG_UP(As0, Bs0, (t + 3) * 32);
      else if ((t % 3) == 1) STG_UP(As1, Bs1, (t + 3) * 32);
      else                   STG_UP(As2, Bs2, (t + 3) * 32);
    }
  }
#undef STG_UP
#undef CMP_UP

  const bool toC1 = (col0 >= split_col);
#pragma unroll
  for (int i = 0; i < 4; i++) {
#pragma unroll
    for (int j = 0; j < 4; j++) {
      int col = col0 - (toC1 ? split_col : 0) + wc * 64 + j * 16 + lm;
#pragma unroll
      for (int r = 0; r < 4; r++) {
        int row = row0 + wr * 64 + i * 16 + lq * 4 + r;
        if (toC1) C1[(size_t)row * ldc + col] = f2bf(acc[i][j][r]);
        else C0[(size_t)row * ldc + col] = acc[i][j][r];
      }
    }
  }
}

// ---------------- bf16 MFMA GEMM 64x64 (down-proj, +=), BK=64, 3-deep pipeline --------------
// K must be 1024 (NT=16).
__global__ __launch_bounds__(256) void gemm_bf16_32(
    const u16* __restrict__ A, const u16* __restrict__ Bt,
    float* __restrict__ C, int M, int N, int K, int ldc)
{
  __shared__ u16 As0[64 * 64], As1[64 * 64], As2[64 * 64];
  __shared__ u16 Bs0[64 * 64], Bs1[64 * 64], Bs2[64 * 64];
  const int tid = threadIdx.x;
  const int row0 = blockIdx.y * 64, col0 = blockIdx.x * 64;
  const int wave = tid >> 6, lane = tid & 63;
  const int wr = wave >> 1, wc = wave & 1;   // wave tile: 32 rows x 32 cols
  const int lm = lane & 15, lq = lane >> 4;
  const int lr = lane >> 3;
  const int cg = (lane & 7) ^ lr;
  f32x4 acc[2][2] = {};
  const u16* Abase = A + (size_t)(row0 + lr) * K + cg * 8;
  const u16* Bbase = Bt + (size_t)(col0 + lr) * K + cg * 8;
  const int key = lm & 7;

#define STAGE_DN(AS, BS, K0) do { \
  _Pragma("unroll") for (int i = 0; i < 2; i++) \
    gload16(Abase + (size_t)((wave * 2 + i) * 8) * K + (K0), &AS[(wave * 2 + i) * 512]); \
  _Pragma("unroll") for (int j = 0; j < 2; j++) \
    gload16(Bbase + (size_t)((wave * 2 + j) * 8) * K + (K0), &BS[(wave * 2 + j) * 512]); \
} while (0)

#define COMPUTE_DN(AS, BS) do { \
  short8 af[2][2], bfv[2][2]; \
  _Pragma("unroll") for (int kc = 0; kc < 2; kc++) { \
    _Pragma("unroll") for (int i = 0; i < 2; i++) \
      af[kc][i] = *(const short8*)&AS[(wr * 32 + i * 16 + lm) * 64 + (((kc * 4 + lq) ^ key) * 8)]; \
    _Pragma("unroll") for (int j = 0; j < 2; j++) \
      bfv[kc][j] = *(const short8*)&BS[(wc * 32 + j * 16 + lm) * 64 + (((kc * 4 + lq) ^ key) * 8)]; \
  } \
  _Pragma("unroll") for (int kc = 0; kc < 2; kc++) \
    _Pragma("unroll") for (int i = 0; i < 2; i++) \
      _Pragma("unroll") for (int j = 0; j < 2; j++) \
        acc[i][j] = __builtin_amdgcn_mfma_f32_16x16x32_bf16(af[kc][i], bfv[kc][j], acc[i][j], 0, 0, 0); \
} while (0)

  STAGE_DN(As0, Bs0, 0);
  asm volatile("" ::: "memory");
  STAGE_DN(As1, Bs1, 64);
  asm volatile("" ::: "memory");
  STAGE_DN(As2, Bs2, 128);
  // 12 DMA ops/wave in flight (4 per tile, 3 tiles)
#pragma unroll
  for (int t = 0; t < 16; t++) {
    if (t <= 13)      asm volatile("s_waitcnt vmcnt(8)" ::: "memory");
    else if (t == 14) asm volatile("s_waitcnt vmcnt(4)" ::: "memory");
    else              asm volatile("s_waitcnt vmcnt(0)" ::: "memory");
    __builtin_amdgcn_sched_barrier(0);
    __builtin_amdgcn_s_barrier();
    if ((t % 3) == 0)      COMPUTE_DN(As0, Bs0);
    else if ((t % 3) == 1) COMPUTE_DN(As1, Bs1);
    else                   COMPUTE_DN(As2, Bs2);
    __builtin_amdgcn_s_barrier();
    if (t + 3 < 16) {
      if ((t % 3) == 0)      STAGE_DN(As0, Bs0, (t + 3) * 64);
      else if ((t % 3) == 1) STAGE_DN(As1, Bs1, (t + 3) * 64);
      else                   STAGE_DN(As2, Bs2, (t + 3) * 64);
    }
  }
#undef STAGE_DN
#undef COMPUTE_DN

#pragma unroll
  for (int i = 0; i < 2; i++) {
#pragma unroll
    for (int j = 0; j < 2; j++) {
      int col = col0 + wc * 32 + j * 16 + lm;
#pragma unroll
      for (int r = 0; r < 4; r++) {
        int row = row0 + wr * 32 + i * 16 + lq * 4 + r;
        C[(size_t)row * ldc + col] += acc[i][j][r];
      }
    }
  }
}

// ---------------- fused causal conv+SiLU+headwise qkv; 8 rows/block; writes V and V^T -------
__global__ __launch_bounds__(256) void convqkv_kernel(
    const float* __restrict__ xm,
    const float* __restrict__ cw, const float* __restrict__ cb,
    const float* __restrict__ qw, const float* __restrict__ kw, const float* __restrict__ vw,
    float* __restrict__ xc, u16* __restrict__ q, u16* __restrict__ k, u16* __restrict__ v,
    u16* __restrict__ vt)
{
  int r0 = blockIdx.x * 8;         // rows r0..r0+7, same batch (S_LEN % 8 == 0)
  int s0 = r0 & (S_LEN - 1);
  int g = threadIdx.x;             // channel group of 4
  int c0 = g * 4;
  const float* base = xm + (size_t)r0 * INNER_D + c0;

  float4 xv[11];
#pragma unroll
  for (int j = 0; j < 11; j++) {
    int ts = s0 - 3 + j;
    float4 t = {0.f, 0.f, 0.f, 0.f};
    if (ts >= 0) t = *(const float4*)(base + (ptrdiff_t)(j - 3) * INNER_D);
    xv[j] = t;
  }
  float cwv[4][4];
#pragma unroll
  for (int c = 0; c < 4; c++)
#pragma unroll
    for (int kk = 0; kk < 4; kk++) cwv[c][kk] = cw[(c0 + c) * 4 + kk];
  float cbv[4] = {cb[c0], cb[c0 + 1], cb[c0 + 2], cb[c0 + 3]};
  const float* qg = qw + g * 16;
  const float* kg = kw + g * 16;
  const float* vg = vw + g * 16;
  float qwv[16], kwv[16], vwv[16];
#pragma unroll
  for (int i = 0; i < 16; i++) { qwv[i] = qg[i]; kwv[i] = kg[i]; vwv[i] = vg[i]; }

  u32 vt_pack[4][4];   // [channel][s-pair] fully static indexing

#pragma unroll
  for (int i = 0; i < 8; i++) {
    float a0 = cbv[0], a1 = cbv[1], a2 = cbv[2], a3 = cbv[3];
#pragma unroll
    for (int kk = 0; kk < 4; kk++) {
      float4 xvv = xv[i + kk];
      a0 += xvv.x * cwv[0][kk];
      a1 += xvv.y * cwv[1][kk];
      a2 += xvv.z * cwv[2][kk];
      a3 += xvv.w * cwv[3][kk];
    }
    a0 = a0 / (1.f + __expf(-a0));
    a1 = a1 / (1.f + __expf(-a1));
    a2 = a2 / (1.f + __expf(-a2));
    a3 = a3 / (1.f + __expf(-a3));
    float4 accv = {a0, a1, a2, a3};
    *(float4*)(xc + (size_t)(r0 + i) * INNER_D + c0) = accv;

    float xcv[4] = {a0, a1, a2, a3};
    float xmv[4] = {xv[i + 3].x, xv[i + 3].y, xv[i + 3].z, xv[i + 3].w};
    ushort4 qs, ks, vs;
    u16* qp = (u16*)&qs; u16* kp = (u16*)&ks; u16* vp = (u16*)&vs;
#pragma unroll
    for (int o = 0; o < 4; o++) {
      float aq = 0.f, ak = 0.f, av = 0.f;
#pragma unroll
      for (int d = 0; d < 4; d++) {
        aq += xcv[d] * qwv[o * 4 + d];
        ak += xcv[d] * kwv[o * 4 + d];
        av += xmv[d] * vwv[o * 4 + d];
      }
      qp[o] = f2bf(aq); kp[o] = f2bf(ak);
      u16 vv = f2bf(av);
      vp[o] = vv;
      if ((i & 1) == 0) vt_pack[o][i >> 1] = (u32)vv;
      else              vt_pack[o][i >> 1] |= ((u32)vv) << 16;
    }
    size_t off = (size_t)(r0 + i) * INNER_D + c0;
    *(ushort4*)(q + off) = qs;
    *(ushort4*)(k + off) = ks;
    *(ushort4*)(v + off) = vs;
  }
  // V^T: vt[b][d][s], 16B (8 s-values) per channel
  u16* vtb = vt + ((size_t)((r0 >> 10) * INNER_D + c0)) * S_LEN + s0;
#pragma unroll
  for (int c = 0; c < 4; c++) {
    uint4 wv4 = {vt_pack[c][0], vt_pack[c][1], vt_pack[c][2], vt_pack[c][3]};
    *(uint4*)(vtb + (size_t)c * S_LEN) = wv4;
  }
}

// ---------------- gates as skinny MFMA GEMM: C[2048,16] = qkv[2048,3072] @ W^T ----------------
__global__ __launch_bounds__(256) void gates_mfma_kernel(
    const u16* __restrict__ q, const u16* __restrict__ k, const u16* __restrict__ v,
    const u16* __restrict__ whi, const u16* __restrict__ wlo,
    const float* __restrict__ igb, const float* __restrict__ fgb,
    float* __restrict__ ig, float* __restrict__ fg)
{
  const int blk = blockIdx.x;      // 0..127
  const int tid = threadIdx.x;
  const int wave = tid >> 6, lane = tid & 63;
  const int lm = lane & 15, lq = lane >> 4;
  const int grow = blk * 16 + lm;
  const u16* parts[3] = {q, k, v};
  f32x4 acc = {};
#pragma unroll 4
  for (int kc = 0; kc < 24; kc++) {
    int k0 = wave * 768 + kc * 32;
    int part = k0 >> 10;
    int idx = (k0 & 1023) + lq * 8;
    S8 a, bh_, bl_;
    a.q = *(const uint4*)(parts[part] + (size_t)grow * INNER_D + idx);
    bh_.q = *(const uint4*)(whi + (size_t)lm * 3072 + k0 + lq * 8);
    bl_.q = *(const uint4*)(wlo + (size_t)lm * 3072 + k0 + lq * 8);
    __builtin_amdgcn_s_setprio(1);
    acc = __builtin_amdgcn_mfma_f32_16x16x32_bf16(a.v, bh_.v, acc, 0, 0, 0);
    acc = __builtin_amdgcn_mfma_f32_16x16x32_bf16(a.v, bl_.v, acc, 0, 0, 0);
    __builtin_amdgcn_s_setprio(0);
  }
  __shared__ float red[4][16][17];
#pragma unroll
  for (int r = 0; r < 4; r++) red[wave][lq * 4 + r][lm] = acc[r];
  __syncthreads();
  if (wave == 0) {
#pragma unroll
    for (int r = 0; r < 4; r++) {
      int row = lq * 4 + r;
      float sum = red[0][row][lm] + red[1][row][lm] + red[2][row][lm] + red[3][row][lm];
      int growr = blk * 16 + row;
      int b = growr >> 10, s = growr & (S_LEN - 1);
      if (lm < 8) ig[((size_t)(b * NHEAD + lm) << 10) + s] = sum + igb[lm];
      else        fg[((size_t)(b * NHEAD + (lm - 8)) << 10) + s] = sum + fgb[lm - 8];
    }
  }
}

// ---------------- per-(b,h) scans, shuffle-based ----------------
__global__ __launch_bounds__(1024) void scan_kernel(
    const float* __restrict__ ig, const float* __restrict__ fg,
    float* __restrict__ a, float* __restrict__ rm, float* __restrict__ enm)
{
  int bh = blockIdx.x;
  int t = threadIdx.x;
  int lane = t & 63, wv = t >> 6;
  __shared__ float sw[16];
  size_t o = ((size_t)bh << 10) + t;
  float f = fg[o];
  float lf = (f >= 0.f) ? -log1pf(__expf(-f)) : f - log1pf(__expf(f));
  float v = lf;
#pragma unroll
  for (int off = 1; off < 64; off <<= 1) {
    float u = __shfl_up(v, off);
    if (lane >= off) v += u;
  }
  if (lane == 63) sw[wv] = v;
  __syncthreads();
  float pre = 0.f;
  for (int w = 0; w < wv; w++) pre += sw[w];
  float cs = v + pre;
  float av = ig[o] - cs;
  a[o] = av;
  float m = av;
#pragma unroll
  for (int off = 1; off < 64; off <<= 1) {
    float u = __shfl_up(m, off);
    if (lane >= off) m = fmaxf(m, u);
  }
  __syncthreads();
  if (lane == 63) sw[wv] = m;
  __syncthreads();
  float pm = -3.4e38f;
  for (int w = 0; w < wv; w++) pm = fmaxf(pm, sw[w]);
  float rmx = fmaxf(m, pm);
  rm[o] = rmx;
  enm[o] = __expf(-(cs + rmx));
}

// ---------------- 128-q-row (8-wave) split-K MFMA attention, 15 jobs/bh ----------
// qp = q-tile-pair index (128 rows); k range in 64-t tiles.
__device__ __constant__ int c_qp[15] = {7, 7, 7, 6, 6, 6, 5, 5, 4, 4, 3, 3, 2, 1, 0};
__device__ __constant__ int c_k0[15] = {0, 6,11, 0, 5,10, 0, 6, 0, 5, 0, 4, 0, 0, 0};
__device__ __constant__ int c_k1[15] = {6,11,16, 5,10,14, 6,12, 5,10, 4, 8, 6, 4, 2};
__device__ __constant__ int c_md[15] = {1, 2, 3, 1, 2, 3, 1, 2, 1, 2, 1, 2, 0, 0, 0};

#define HP_SLOT 1310720   // 16 bh * 5 qr * 128 rows * 128
#define SC_SLOT 10240     // 16 bh * 5 qr * 128 rows

__global__ __launch_bounds__(512) void attn_mfma_kernel(
    const u16* __restrict__ qhg, const u16* __restrict__ khg, const u16* __restrict__ vtg,
    const float* __restrict__ a_arr, const float* __restrict__ rm_arr, const float* __restrict__ enm_arr,
    const float* __restrict__ xc, const u16* __restrict__ zh,
    const float* __restrict__ skip, const float* __restrict__ onw,
    u16* __restrict__ hs, float* __restrict__ hpart, float* __restrict__ scpart)
{
  const int bh = blockIdx.x;
  const int job = blockIdx.y;
  const int qp = c_qp[job], k0t = c_k0[job], k1t = c_k1[job], mode = c_md[job];
  const int b = bh >> 3, h = bh & 7;
  const int s0 = qp * 128;
  const int tid = threadIdx.x;
  const int wave = tid >> 6, lane = tid & 63;
  const int lm = lane & 15, lq = lane >> 4;
  const size_t rowbase = (size_t)b * S_LEN;
  const int c0 = h * DHEAD;

  __shared__ u16 Ks0[64 * 128], Ks1[64 * 128];  // [t][128], 16B slots XOR-swizzled by (t&7)
  __shared__ u16 Vt0[128 * 64], Vt1[128 * 64];  // [d][64],  16B slots XOR-swizzled by (d&7)
  __shared__ u16 Ws[128 * 72];

  short8 aq[4];
  {
    const u16* qpp = qhg + (rowbase + s0 + wave * 16 + lm) * INNER_D + c0 + lq * 8;
#pragma unroll
    for (int kc = 0; kc < 4; kc++) {
      S8 tmp; tmp.q = *(const uint4*)(qpp + kc * 32);
      aq[kc] = tmp.v;
    }
  }
  const float scale = 0.08838834764831845f;  // 1/sqrt(128)
  float rmv[4], er[4];
#pragma unroll
  for (int r = 0; r < 4; r++) {
    rmv[r] = rm_arr[(size_t)bh * S_LEN + s0 + wave * 16 + lq * 4 + r];
    er[r] = scale * __expf(-rmv[r]);   // hoisted: exp(ea-rm) = exp(ea)*exp(-rm)
  }

  f32x4 accH[8] = {};
  float sc_acc[4] = {0.f, 0.f, 0.f, 0.f};
  const int lr16 = lane >> 4;      // 0..3 (K rows: 256B each, 16 lanes/row)
  const int ls16 = lane & 15;      // 16B slot within 256B K row
  const int lr8 = lane >> 3;       // 0..7  (V rows: 128B each, 8 lanes/row)
  const int cgv = (lane & 7) ^ lr8;  // pre-swizzled V source slot
  const u16* vtbase = vtg + ((size_t)b * INNER_D + c0) * S_LEN;

  float ae0[4], ae1[4];

// 8 waves: each stages 2 K block-rows + 2 V block-rows (16 gloads total each)
#define PREF(KS, VS, AE, T0) do { \
  _Pragma("unroll") for (int j = 0; j < 2; j++) { \
    int rK = (wave * 2 + j) * 4 + lr16; \
    int cgk = ls16 ^ (rK & 7); \
    gload16(khg + (rowbase + (T0) + rK) * INNER_D + c0 + cgk * 8, &KS[(wave * 2 + j) * 512]); \
  } \
  _Pragma("unroll") for (int j = 0; j < 2; j++) { \
    int rV = (wave * 2 + j) * 8 + lr8; \
    gload16(vtbase + (size_t)rV * S_LEN + (T0) + cgv * 8, &VS[(wave * 2 + j) * 512]); \
  } \
  _Pragma("unroll") for (int cb = 0; cb < 4; cb++) \
    AE[cb] = a_arr[(size_t)bh * S_LEN + (T0) + cb * 16 + lm]; \
} while (0)

#define QK_STEP(KS, PACC) do { \
  __builtin_amdgcn_s_setprio(1); \
  _Pragma("unroll") for (int kc = 0; kc < 4; kc++) \
    _Pragma("unroll") for (int cb = 0; cb < 4; cb++) { \
      short8 bk = *(const short8*)&KS[(cb * 16 + lm) * 128 + (((kc * 4 + lq) ^ (lm & 7)) * 8)]; \
      PACC[cb] = __builtin_amdgcn_mfma_f32_16x16x32_bf16(aq[kc], bk, PACC[cb], 0, 0, 0); \
    } \
  __builtin_amdgcn_s_setprio(0); \
} while (0)

#define W_PV(AE, VT, T0, PACC) do { \
  float wpart[4] = {0.f, 0.f, 0.f, 0.f}; \
  _Pragma("unroll") for (int cb = 0; cb < 4; cb++) { \
    int colg = (T0) + cb * 16 + lm; \
    float ec = __expf(AE[cb]); \
    _Pragma("unroll") for (int r = 0; r < 4; r++) { \
      int rowg = s0 + wave * 16 + lq * 4 + r; \
      float wv = PACC[cb][r] * ec * er[r]; \
      if (colg > rowg) wv = 0.f; \
      wpart[r] += wv; \
      Ws[(wave * 16 + lq * 4 + r) * 72 + cb * 16 + lm] = f2bf(wv); \
    } \
  } \
  _Pragma("unroll") for (int r = 0; r < 4; r++) { \
    float sr = wpart[r]; \
    sr += __shfl_xor(sr, 1); sr += __shfl_xor(sr, 2); \
    sr += __shfl_xor(sr, 4); sr += __shfl_xor(sr, 8); \
    sc_acc[r] += sr; \
  } \
  __builtin_amdgcn_s_setprio(1); \
  _Pragma("unroll") for (int kc = 0; kc < 2; kc++) { \
    short8 aw = *(const short8*)&Ws[(wave * 16 + lm) * 72 + kc * 32 + lq * 8]; \
    _Pragma("unroll") for (int nb = 0; nb < 8; nb++) { \
      short8 bv = *(const short8*)&VT[(nb * 16 + lm) * 64 + (((kc * 4 + lq) ^ (lm & 7)) * 8)]; \
      accH[nb] = __builtin_amdgcn_mfma_f32_16x16x32_bf16(aw, bv, accH[nb], 0, 0, 0); \
    } \
  } \
  __builtin_amdgcn_s_setprio(0); \
} while (0)

  int kt = k0t;
  PREF(Ks0, Vt0, ae0, kt * 64);
  asm volatile("" ::: "memory");
  if (kt + 1 < k1t) PREF(Ks1, Vt1, ae1, (kt + 1) * 64);

  while (true) {
    {
      if (kt + 1 < k1t) asm volatile("s_waitcnt vmcnt(8)" ::: "memory");
      else              asm volatile("s_waitcnt vmcnt(0)" ::: "memory");
      __builtin_amdgcn_sched_barrier(0);
      __builtin_amdgcn_s_barrier();
      f32x4 pacc[4] = {};
      QK_STEP(Ks0, pacc);
      W_PV(ae0, Vt0, kt * 64, pacc);
      __builtin_amdgcn_s_barrier();
      if (kt + 2 < k1t) PREF(Ks0, Vt0, ae0, (kt + 2) * 64);
      kt++;
      if (kt >= k1t) break;
    }
    {
      if (kt + 1 < k1t) asm volatile("s_waitcnt vmcnt(8)" ::: "memory");
      else              asm volatile("s_waitcnt vmcnt(0)" ::: "memory");
      __builtin_amdgcn_sched_barrier(0);
      __builtin_amdgcn_s_barrier();
      f32x4 pacc[4] = {};
      QK_STEP(Ks1, pacc);
      W_PV(ae1, Vt1, kt * 64, pacc);
      __builtin_amdgcn_s_barrier();
      if (kt + 2 < k1t) PREF(Ks1, Vt1, ae1, (kt + 2) * 64);
      kt++;
      if (kt >= k1t) break;
    }
  }
#undef PREF
#undef QK_STEP
#undef W_PV

  if (mode != 0) {
    int slot = mode - 1;
    int qr = qp - 3;
    float* Hp = hpart + (size_t)slot * HP_SLOT + ((size_t)(bh * 5 + qr)) * 16384;
    float* sp = scpart + slot * SC_SLOT + (bh * 5 + qr) * 128;
#pragma unroll
    for (int r = 0; r < 4; r++) {
      int row = wave * 16 + lq * 4 + r;
      if (lm == 0) sp[row] = sc_acc[r];
#pragma unroll
      for (int nb = 0; nb < 8; nb++)
        Hp[row * 128 + nb * 16 + lm] = accH[nb][r];
    }
    return;
  }

  float inv[4], muv[4], rsv[4];
#pragma unroll
  for (int r = 0; r < 4; r++) {
    int rowg = s0 + wave * 16 + lq * 4 + r;
    float nrm = fmaxf(fabsf(sc_acc[r]), enm_arr[(size_t)bh * S_LEN + rowg]);
    inv[r] = 1.f / (nrm + 1e-6f);
  }
#pragma unroll
  for (int r = 0; r < 4; r++) {
    float s = 0.f, qq = 0.f;
#pragma unroll
    for (int nb = 0; nb < 8; nb++) {
      float hv = accH[nb][r] * inv[r];
      accH[nb][r] = hv;
      s += hv; qq += hv * hv;
    }
    s += __shfl_xor(s, 1); s += __shfl_xor(s, 2); s += __shfl_xor(s, 4); s += __shfl_xor(s, 8);
    qq += __shfl_xor(qq, 1); qq += __shfl_xor(qq, 2); qq += __shfl_xor(qq, 4); qq += __shfl_xor(qq, 8);
    float mu = s * (1.f / DHEAD);
    float var = qq * (1.f / DHEAD) - mu * mu;
    muv[r] = mu;
    rsv[r] = rsqrtf(var + 1e-5f);
  }
  float ow[8], sk[8];
#pragma unroll
  for (int nb = 0; nb < 8; nb++) {
    ow[nb] = onw[c0 + nb * 16 + lm];
    sk[nb] = skip[c0 + nb * 16 + lm];
  }
#pragma unroll
  for (int r = 0; r < 4; r++) {
    int rowg = s0 + wave * 16 + lq * 4 + r;
    size_t base = (rowbase + rowg) * INNER_D + c0;
#pragma unroll
    for (int nb = 0; nb < 8; nb++) {
      int d = nb * 16 + lm;
      float xcv = xc[base + d];
      float zv = bf2f(zh[base + d]);
      float hn = (accH[nb][r] - muv[r]) * rsv[r] * ow[nb] + sk[nb] * xcv;
      float o = hn * (zv / (1.f + __expf(-zv)));
      hs[base + d] = f2bf(o);
    }
  }
}

// combine 2..3 partial slots for rows s >= 384; one wave per row (10240 rows).
__global__ __launch_bounds__(256) void attn_combine_kernel(
    const float* __restrict__ hpart, const float* __restrict__ scpart,
    const float* __restrict__ enm,
    const float* __restrict__ xc, const u16* __restrict__ zh,
    const float* __restrict__ skip, const float* __restrict__ onw,
    u16* __restrict__ hs)
{
  int wave = threadIdx.x >> 6, lane = threadIdx.x & 63;
  int gid = blockIdx.x * 4 + wave;   // 0..10239
  int bh = gid / 640;
  int rr = gid % 640;
  int qr = rr >> 7, row = rr & 127;
  int b = bh >> 3, hh = bh & 7;
  int s = (qr + 3) * 128 + row;
  int nsl = (qr >= 3) ? 3 : 2;       // qp3-5: 2 slots, qp6-7: 3 slots
  size_t off = (((size_t)(bh * 5 + qr)) * 128 + row) * 128 + lane * 2;
  int sidx = (bh * 5 + qr) * 128 + row;
  float hx = 0.f, hy = 0.f, sc = 0.f;
  for (int sl = 0; sl < nsl; sl++) {
    float2 hp = *(const float2*)(hpart + (size_t)sl * HP_SLOT + off);
    hx += hp.x; hy += hp.y;
    sc += scpart[sl * SC_SLOT + sidx];
  }
  float nrm = fmaxf(fabsf(sc), enm[(size_t)bh * S_LEN + s]);
  float inv = 1.f / (nrm + 1e-6f);
  hx *= inv; hy *= inv;
  float sm = hx + hy, sq = hx * hx + hy * hy;
#pragma unroll
  for (int off2 = 32; off2; off2 >>= 1) { sm += __shfl_xor(sm, off2); sq += __shfl_xor(sq, off2); }
  float mu = sm * (1.f / DHEAD);
  float var = sq * (1.f / DHEAD) - mu * mu;
  float rs = rsqrtf(var + 1e-5f);
  int c0 = hh * DHEAD + lane * 2;
  size_t base = ((size_t)(b * S_LEN + s)) * INNER_D + c0;
  float2 xc2 = *(const float2*)(xc + base);
  ushort2 z2u = *(const ushort2*)(zh + base);
  float z2x = bf2f(z2u.x), z2y = bf2f(z2u.y);
  float skx = skip[c0], sky = skip[c0 + 1];
  float owx = onw[c0],  owy = onw[c0 + 1];
  ushort2 o;
  o.x = f2bf(((hx - mu) * rs * owx + skx * xc2.x) * (z2x / (1.f + __expf(-z2x))));
  o.y = f2bf(((hy - mu) * rs * owy + sky * xc2.y) * (z2y / (1.f + __expf(-z2y))));
  *(ushort2*)(hs + base) = o;
}

extern "C" void kernel_launch(void* const* d_in, const int* in_sizes, int n_in,
                              void* d_out, int out_size, void* d_ws, size_t ws_size,
                              hipStream_t stream)
{
  const float* x_enc   = (const float*)d_in[0];
  const float* x_mark  = (const float*)d_in[1];
  const float* emb_W   = (const float*)d_in[4];
  const float* emb_b   = (const float*)d_in[5];
  const float* ln_w    = (const float*)d_in[6];
  const float* up_W    = (const float*)d_in[7];
  const float* conv_W  = (const float*)d_in[8];
  const float* conv_b  = (const float*)d_in[9];
  const float* q_W     = (const float*)d_in[10];
  const float* k_W     = (const float*)d_in[11];
  const float* v_W     = (const float*)d_in[12];
  const float* ig_W    = (const float*)d_in[13];
  const float* ig_b    = (const float*)d_in[14];
  const float* fg_W    = (const float*)d_in[15];
  const float* fg_b    = (const float*)d_in[16];
  const float* skip_w  = (const float*)d_in[17];
  const float* onorm_w = (const float*)d_in[18];
  const float* down_W  = (const float*)d_in[19];
  const float* post_ln = (const float*)d_in[20];
  const float* head_W  = (const float*)d_in[21];
  const float* head_b  = (const float*)d_in[22];

  float* p = (float*)d_ws;
  float* x    = p; p += 1048576;   // 2048*512 f32
  float* xm   = p; p += 2097152;   // 2048*1024 f32; reused as hsbh bf16 after convqkv
  float* xc   = p; p += 2097152;
  float* igb_ = p; p += 16384;
  float* fgb_ = p; p += 16384;
  float* ab   = p; p += 16384;
  float* rmb  = p; p += 16384;
  float* enmb = p; p += 16384;
  u16* qhb = (u16*)p; p += 1048576;  // 2048*1024 u16
  u16* khb = (u16*)p; p += 1048576;
  u16* vhb = (u16*)p; p += 1048576;
  u16* zh  = (u16*)p; p += 1048576;  // 2048*1024 u16 (full size)
  u16* xnh = (u16*)p; p += 524288;   // 2048*512 u16
  u16* upWtA = (u16*)p; p += 2097152; // 4 x 2048x512 u16
  u16* dnWtA = (u16*)p; p += 1048576; // 4 x 512x1024 u16
  u16* gtwH = (u16*)p; p += 98304;    // 4 x 16 x 3072 u16
  u16* gtwL = (u16*)p; p += 98304;
  float* hpart = p; p += 3932160;     // 3 slots x 16 bh x 5 qr x 128 x 128 f32
  float* scpart = p; p += 32768;      // 3 slots x 10240 (padded)
  u16* vtg = (u16*)p; p += 1048576;   // 2 x 1024 x 1024 u16 (V^T per layer)
  u16* hsbh = (u16*)xm;

  // one merged prep launch: up/down weight transposes + gates weights + embedding
  prep_kernel<<<4352, 256, 0, stream>>>(
      up_W, upWtA, down_W, dnWtA, ig_W, fg_W, gtwH, gtwL,
      x_enc, x_mark, emb_W, emb_b, x);

  for (int L = 0; L < 4; L++) {
    ln_kernel<<<2048, 256, 0, stream>>>(x, ln_w + L * 512, xnh);
    gemm_bf16_split64<<<dim3(16, 16), 256, 0, stream>>>(
        xnh, upWtA + (size_t)L * 1048576, xm, zh, 2048, 2048, 512, 1024, 1024);
    convqkv_kernel<<<256, 256, 0, stream>>>(
        xm, conv_W + L * 4096, conv_b + L * 1024,
        q_W + L * 4096, k_W + L * 4096, v_W + L * 4096,
        xc, qhb, khb, vhb, vtg);
    gates_mfma_kernel<<<128, 256, 0, stream>>>(
        qhb, khb, vhb, gtwH + (size_t)L * 49152, gtwL + (size_t)L * 49152,
        ig_b + L * 8, fg_b + L * 8, igb_, fgb_);
    scan_kernel<<<16, 1024, 0, stream>>>(igb_, fgb_, ab, rmb, enmb);
    attn_mfma_kernel<<<dim3(16, 15), 512, 0, stream>>>(
        qhb, khb, vtg, ab, rmb, enmb, xc, zh,
        skip_w + L * 1024, onorm_w + L * 1024, hsbh, hpart, scpart);
    attn_combine_kernel<<<2560, 256, 0, stream>>>(
        hpart, scpart, enmb, xc, zh, skip_w + L * 1024, onorm_w + L * 1024, hsbh);
    gemm_bf16_32<<<dim3(8, 32), 256, 0, stream>>>(
        hsbh, dnWtA + (size_t)L * 524288, x, 2048, 512, 1024, 512);
  }

  lnhead_kernel<<<192, 256, 0, stream>>>(x, post_ln, head_W, head_b, (float*)d_out);
}

// Round 11
// 428.805 us; speedup vs baseline: 1.0739x; 1.0486x over previous
//
#include <hip/hip_runtime.h>
#include <hip/hip_bf16.h>

#define S_LEN 1024
#define E_DIM 512
#define INNER_D 1024
#define NHEAD 8
#define DHEAD 128

typedef unsigned short u16;
typedef unsigned int u32;
typedef __attribute__((ext_vector_type(8))) short short8;
typedef __attribute__((ext_vector_type(4))) float f32x4;

union S8 { short8 v; u16 u[8]; uint4 q; };

__device__ __forceinline__ u16 f2bf(float f) {
  u32 u = __float_as_uint(f);
  u32 r = u + 0x7FFFu + ((u >> 16) & 1u);
  return (u16)(r >> 16);
}
__device__ __forceinline__ float bf2f(u16 u) { return __uint_as_float(((u32)u) << 16); }

// direct global -> LDS (16B per lane). LDS dest = wave-uniform base + lane*16B (linear).
__device__ __forceinline__ void gload16(const u16* g, u16* l) {
  __builtin_amdgcn_global_load_lds((const __attribute__((address_space(1))) void*)g,
                                   (__attribute__((address_space(3))) void*)l, 16, 0, 0);
}

// ---------------- merged one-time prep: transposes + gates weights + embedding ----------------
__device__ __forceinline__ void prep_transpose(
    const float* __restrict__ in, u16* __restrict__ out, int K, int N,
    int k0, int n0, int t, u16 (*T)[72])
{
  int kr = t >> 2, nseg = (t & 3) * 16;
  const float* src = in + (size_t)(k0 + kr) * N + n0 + nseg;
#pragma unroll
  for (int j = 0; j < 16; j++) T[kr][nseg + j] = f2bf(src[j]);
  __syncthreads();
  int nr = t >> 2, kseg = (t & 3) * 16;
  u32 u[8];
#pragma unroll
  for (int rr = 0; rr < 8; rr++) {
    u32 lo = T[kseg + 2 * rr][nr];
    u32 hi = T[kseg + 2 * rr + 1][nr];
    u[rr] = lo | (hi << 16);
  }
  u16* dst = out + (size_t)(n0 + nr) * K + k0 + kseg;
  uint4 w0 = {u[0], u[1], u[2], u[3]};
  uint4 w1 = {u[4], u[5], u[6], u[7]};
  *(uint4*)dst = w0;
  *(uint4*)(dst + 8) = w1;
}

__global__ __launch_bounds__(256) void prep_kernel(
    const float* __restrict__ up_W, u16* __restrict__ upWt,
    const float* __restrict__ down_W, u16* __restrict__ dnWt,
    const float* __restrict__ igW, const float* __restrict__ fgW,
    u16* __restrict__ ghi, u16* __restrict__ glo,
    const float* __restrict__ xe, const float* __restrict__ xmk,
    const float* __restrict__ eW, const float* __restrict__ eb,
    float* __restrict__ x)
{
  __shared__ u16 T[64][72];
  __shared__ float in_s[25];
  int id = blockIdx.x;
  int t = threadIdx.x;
  if (id < 1024) {                     // up_W transpose: [L][512][2048] -> [L][2048][512]
    int bx = id & 7, rest = id >> 3;
    int by = rest & 31, L = rest >> 5;
    prep_transpose(up_W + (size_t)L * 512 * 2048, upWt + (size_t)L * 1048576,
                   512, 2048, bx * 64, by * 64, t, T);
  } else if (id < 1536) {              // down_W transpose: [L][1024][512] -> [L][512][1024]
    int id2 = id - 1024;
    int bx = id2 & 15, rest = id2 >> 4;
    int by = rest & 7, L = rest >> 3;
    prep_transpose(down_W + (size_t)L * 1024 * 512, dnWt + (size_t)L * 524288,
                   1024, 512, bx * 64, by * 64, t, T);
  } else if (id < 2304) {              // gates weights: hi/lo split transpose
    int id3 = id - 1536;
    int bx = id3 % 12, rest = id3 / 12;
    int n = rest & 15, L = rest >> 4;
    int k = bx * 256 + t;
    const float* W = ((n < 8) ? igW : fgW) + (size_t)L * 24576;
    float v = W[(size_t)k * 8 + (n & 7)];
    u16 h = f2bf(v);
    u16 l = f2bf(v - bf2f(h));
    size_t o = ((size_t)L * 16 + n) * 3072 + k;
    ghi[o] = h;
    glo[o] = l;
  } else {                             // embedding, one row per block
    int row = id - 2304;
    if (t < 21) in_s[t] = xe[row * 21 + t];
    else if (t < 25) in_s[t] = xmk[row * 4 + t - 21];
    __syncthreads();
#pragma unroll
    for (int rep = 0; rep < 2; rep++) {
      int e = t + rep * 256;
      float acc = eb[e];
#pragma unroll
      for (int i = 0; i < 25; i++) acc += in_s[i] * eW[i * E_DIM + e];
      x[(size_t)row * E_DIM + e] = acc;
    }
  }
}

// ---------------- layernorm -> bf16 ----------------
__global__ __launch_bounds__(256) void ln_kernel(
    const float* __restrict__ x, const float* __restrict__ w, u16* __restrict__ out)
{
  int row = blockIdx.x, tid = threadIdx.x;
  const float* xr = x + (size_t)row * E_DIM;
  float2 v = *(const float2*)(xr + tid * 2);
  float s = v.x + v.y, q = v.x * v.x + v.y * v.y;
#pragma unroll
  for (int off = 32; off; off >>= 1) { s += __shfl_xor(s, off); q += __shfl_xor(q, off); }
  __shared__ float ssum[4], ssq[4];
  int wv = tid >> 6;
  if ((tid & 63) == 0) { ssum[wv] = s; ssq[wv] = q; }
  __syncthreads();
  s = ssum[0] + ssum[1] + ssum[2] + ssum[3];
  q = ssq[0] + ssq[1] + ssq[2] + ssq[3];
  float mu = s * (1.f / E_DIM);
  float var = q * (1.f / E_DIM) - mu * mu;
  float rs = rsqrtf(var + 1e-5f);
  int e = tid * 2;
  ushort2 o;
  o.x = f2bf((v.x - mu) * rs * w[e]);
  o.y = f2bf((v.y - mu) * rs * w[e + 1]);
  *(ushort2*)(out + (size_t)row * E_DIM + e) = o;
}

// ---------------- fused final layernorm + head (one block per output row) ----------------
__global__ __launch_bounds__(256) void lnhead_kernel(
    const float* __restrict__ x, const float* __restrict__ w,
    const float* __restrict__ hW, const float* __restrict__ hb,
    float* __restrict__ out)
{
  int ridx = blockIdx.x;
  int b = ridx / 96, r = ridx % 96;
  int row = b * S_LEN + (S_LEN - 96) + r;
  int tid = threadIdx.x;
  const float* xr = x + (size_t)row * E_DIM;
  float2 v = *(const float2*)(xr + tid * 2);
  float s = v.x + v.y, q = v.x * v.x + v.y * v.y;
#pragma unroll
  for (int off = 32; off; off >>= 1) { s += __shfl_xor(s, off); q += __shfl_xor(q, off); }
  __shared__ float ssum[4], ssq[4];
  __shared__ float lnv[512];
  __shared__ float part[8][32];
  int wv = tid >> 6;
  if ((tid & 63) == 0) { ssum[wv] = s; ssq[wv] = q; }
  __syncthreads();
  s = ssum[0] + ssum[1] + ssum[2] + ssum[3];
  q = ssq[0] + ssq[1] + ssq[2] + ssq[3];
  float mu = s * (1.f / E_DIM);
  float var = q * (1.f / E_DIM) - mu * mu;
  float rs = rsqrtf(var + 1e-5f);
  int e = tid * 2;
  lnv[e]     = (v.x - mu) * rs * w[e];
  lnv[e + 1] = (v.y - mu) * rs * w[e + 1];
  __syncthreads();
  int n = tid & 31, sl = tid >> 5;
  float p = 0.f;
  if (n < 21) {
#pragma unroll 8
    for (int kk = 0; kk < 64; kk++)
      p += lnv[sl * 64 + kk] * hW[(sl * 64 + kk) * 21 + n];
  }
  part[sl][n] = p;
  __syncthreads();
  if (tid < 21) {
    float acc = hb[tid];
#pragma unroll
    for (int j = 0; j < 8; j++) acc += part[j][tid];
    out[ridx * 21 + tid] = acc;
  }
}

// ---------------- bf16 MFMA GEMM 128x128, BK=32, 3-deep counted-vmcnt pipeline --------------
// split C: C0 f32, C1 bf16; grid (N/128, M/128). K must be 512 (NT=16).
__global__ __launch_bounds__(256) void gemm_bf16_split64(
    const u16* __restrict__ A, const u16* __restrict__ Bt,
    float* __restrict__ C0, u16* __restrict__ C1,
    int M, int N, int K, int split_col, int ldc)
{
  __shared__ u16 As0[128 * 32], As1[128 * 32], As2[128 * 32];
  __shared__ u16 Bs0[128 * 32], Bs1[128 * 32], Bs2[128 * 32];
  const int tid = threadIdx.x;
  const int row0 = blockIdx.y * 128, col0 = blockIdx.x * 128;
  const int wave = tid >> 6, lane = tid & 63;
  const int wr = wave >> 1, wc = wave & 1;   // wave tile: 64 rows x 64 cols
  const int lm = lane & 15, lq = lane >> 4;
  const int lr4 = lane >> 2;                 // 0..15 row within 16-row group
  const int cg4 = (lane & 3) ^ (lr4 & 3);    // pre-swizzled source 16B slot (4 slots/row)
  f32x4 acc[4][4] = {};
  const u16* Abase = A + (size_t)(row0 + lr4) * K + cg4 * 8;
  const u16* Bbase = Bt + (size_t)(col0 + lr4) * K + cg4 * 8;
  const int key = lm & 3;

#define STG_UP(AS, BS, K0) do { \
  _Pragma("unroll") for (int i = 0; i < 2; i++) \
    gload16(Abase + (size_t)((wave * 2 + i) * 16) * K + (K0), &AS[(wave * 2 + i) * 512]); \
  _Pragma("unroll") for (int i = 0; i < 2; i++) \
    gload16(Bbase + (size_t)((wave * 2 + i) * 16) * K + (K0), &BS[(wave * 2 + i) * 512]); \
} while (0)

#define CMP_UP(AS, BS) do { \
  short8 af[4], bfv[4]; \
  _Pragma("unroll") for (int i = 0; i < 4; i++) \
    af[i] = *(const short8*)&AS[(wr * 64 + i * 16 + lm) * 32 + ((lq ^ key) * 8)]; \
  _Pragma("unroll") for (int j = 0; j < 4; j++) \
    bfv[j] = *(const short8*)&BS[(wc * 64 + j * 16 + lm) * 32 + ((lq ^ key) * 8)]; \
  _Pragma("unroll") for (int i = 0; i < 4; i++) \
    _Pragma("unroll") for (int j = 0; j < 4; j++) \
      acc[i][j] = __builtin_amdgcn_mfma_f32_16x16x32_bf16(af[i], bfv[j], acc[i][j], 0, 0, 0); \
} while (0)

  STG_UP(As0, Bs0, 0);
  asm volatile("" ::: "memory");
  STG_UP(As1, Bs1, 32);
  asm volatile("" ::: "memory");
  STG_UP(As2, Bs2, 64);
  // 12 DMA ops/wave in flight (4 per tile, 3 tiles)
#pragma unroll
  for (int t = 0; t < 16; t++) {
    if (t <= 13)      asm volatile("s_waitcnt vmcnt(8)" ::: "memory");
    else if (t == 14) asm volatile("s_waitcnt vmcnt(4)" ::: "memory");
    else              asm volatile("s_waitcnt vmcnt(0)" ::: "memory");
    __builtin_amdgcn_sched_barrier(0);
    __builtin_amdgcn_s_barrier();
    if ((t % 3) == 0)      CMP_UP(As0, Bs0);
    else if ((t % 3) == 1) CMP_UP(As1, Bs1);
    else                   CMP_UP(As2, Bs2);
    __builtin_amdgcn_s_barrier();
    if (t + 3 < 16) {
      if ((t % 3) == 0)      STG_UP(As0, Bs0, (t + 3) * 32);
      else if ((t % 3) == 1) STG_UP(As1, Bs1, (t + 3) * 32);
      else                   STG_UP(As2, Bs2, (t + 3) * 32);
    }
  }
#undef STG_UP
#undef CMP_UP

  const bool toC1 = (col0 >= split_col);
#pragma unroll
  for (int i = 0; i < 4; i++) {
#pragma unroll
    for (int j = 0; j < 4; j++) {
      int col = col0 - (toC1 ? split_col : 0) + wc * 64 + j * 16 + lm;
#pragma unroll
      for (int r = 0; r < 4; r++) {
        int row = row0 + wr * 64 + i * 16 + lq * 4 + r;
        if (toC1) C1[(size_t)row * ldc + col] = f2bf(acc[i][j][r]);
        else C0[(size_t)row * ldc + col] = acc[i][j][r];
      }
    }
  }
}

// ---------------- bf16 MFMA GEMM 64x64 (down-proj, +=), BK=64, 3-deep pipeline --------------
// K must be 1024 (NT=16).
__global__ __launch_bounds__(256) void gemm_bf16_32(
    const u16* __restrict__ A, const u16* __restrict__ Bt,
    float* __restrict__ C, int M, int N, int K, int ldc)
{
  __shared__ u16 As0[64 * 64], As1[64 * 64], As2[64 * 64];
  __shared__ u16 Bs0[64 * 64], Bs1[64 * 64], Bs2[64 * 64];
  const int tid = threadIdx.x;
  const int row0 = blockIdx.y * 64, col0 = blockIdx.x * 64;
  const int wave = tid >> 6, lane = tid & 63;
  const int wr = wave >> 1, wc = wave & 1;   // wave tile: 32 rows x 32 cols
  const int lm = lane & 15, lq = lane >> 4;
  const int lr = lane >> 3;
  const int cg = (lane & 7) ^ lr;
  f32x4 acc[2][2] = {};
  const u16* Abase = A + (size_t)(row0 + lr) * K + cg * 8;
  const u16* Bbase = Bt + (size_t)(col0 + lr) * K + cg * 8;
  const int key = lm & 7;

#define STAGE_DN(AS, BS, K0) do { \
  _Pragma("unroll") for (int i = 0; i < 2; i++) \
    gload16(Abase + (size_t)((wave * 2 + i) * 8) * K + (K0), &AS[(wave * 2 + i) * 512]); \
  _Pragma("unroll") for (int j = 0; j < 2; j++) \
    gload16(Bbase + (size_t)((wave * 2 + j) * 8) * K + (K0), &BS[(wave * 2 + j) * 512]); \
} while (0)

#define COMPUTE_DN(AS, BS) do { \
  short8 af[2][2], bfv[2][2]; \
  _Pragma("unroll") for (int kc = 0; kc < 2; kc++) { \
    _Pragma("unroll") for (int i = 0; i < 2; i++) \
      af[kc][i] = *(const short8*)&AS[(wr * 32 + i * 16 + lm) * 64 + (((kc * 4 + lq) ^ key) * 8)]; \
    _Pragma("unroll") for (int j = 0; j < 2; j++) \
      bfv[kc][j] = *(const short8*)&BS[(wc * 32 + j * 16 + lm) * 64 + (((kc * 4 + lq) ^ key) * 8)]; \
  } \
  _Pragma("unroll") for (int kc = 0; kc < 2; kc++) \
    _Pragma("unroll") for (int i = 0; i < 2; i++) \
      _Pragma("unroll") for (int j = 0; j < 2; j++) \
        acc[i][j] = __builtin_amdgcn_mfma_f32_16x16x32_bf16(af[kc][i], bfv[kc][j], acc[i][j], 0, 0, 0); \
} while (0)

  STAGE_DN(As0, Bs0, 0);
  asm volatile("" ::: "memory");
  STAGE_DN(As1, Bs1, 64);
  asm volatile("" ::: "memory");
  STAGE_DN(As2, Bs2, 128);
  // 12 DMA ops/wave in flight (4 per tile, 3 tiles)
#pragma unroll
  for (int t = 0; t < 16; t++) {
    if (t <= 13)      asm volatile("s_waitcnt vmcnt(8)" ::: "memory");
    else if (t == 14) asm volatile("s_waitcnt vmcnt(4)" ::: "memory");
    else              asm volatile("s_waitcnt vmcnt(0)" ::: "memory");
    __builtin_amdgcn_sched_barrier(0);
    __builtin_amdgcn_s_barrier();
    if ((t % 3) == 0)      COMPUTE_DN(As0, Bs0);
    else if ((t % 3) == 1) COMPUTE_DN(As1, Bs1);
    else                   COMPUTE_DN(As2, Bs2);
    __builtin_amdgcn_s_barrier();
    if (t + 3 < 16) {
      if ((t % 3) == 0)      STAGE_DN(As0, Bs0, (t + 3) * 64);
      else if ((t % 3) == 1) STAGE_DN(As1, Bs1, (t + 3) * 64);
      else                   STAGE_DN(As2, Bs2, (t + 3) * 64);
    }
  }
#undef STAGE_DN
#undef COMPUTE_DN

#pragma unroll
  for (int i = 0; i < 2; i++) {
#pragma unroll
    for (int j = 0; j < 2; j++) {
      int col = col0 + wc * 32 + j * 16 + lm;
#pragma unroll
      for (int r = 0; r < 4; r++) {
        int row = row0 + wr * 32 + i * 16 + lq * 4 + r;
        C[(size_t)row * ldc + col] += acc[i][j][r];
      }
    }
  }
}

// ---------------- fused causal conv+SiLU+headwise qkv; 8 rows/block; writes V and V^T -------
__global__ __launch_bounds__(256) void convqkv_kernel(
    const float* __restrict__ xm,
    const float* __restrict__ cw, const float* __restrict__ cb,
    const float* __restrict__ qw, const float* __restrict__ kw, const float* __restrict__ vw,
    float* __restrict__ xc, u16* __restrict__ q, u16* __restrict__ k, u16* __restrict__ v,
    u16* __restrict__ vt)
{
  int r0 = blockIdx.x * 8;         // rows r0..r0+7, same batch (S_LEN % 8 == 0)
  int s0 = r0 & (S_LEN - 1);
  int g = threadIdx.x;             // channel group of 4
  int c0 = g * 4;
  const float* base = xm + (size_t)r0 * INNER_D + c0;

  float4 xv[11];
#pragma unroll
  for (int j = 0; j < 11; j++) {
    int ts = s0 - 3 + j;
    float4 t = {0.f, 0.f, 0.f, 0.f};
    if (ts >= 0) t = *(const float4*)(base + (ptrdiff_t)(j - 3) * INNER_D);
    xv[j] = t;
  }
  float cwv[4][4];
#pragma unroll
  for (int c = 0; c < 4; c++)
#pragma unroll
    for (int kk = 0; kk < 4; kk++) cwv[c][kk] = cw[(c0 + c) * 4 + kk];
  float cbv[4] = {cb[c0], cb[c0 + 1], cb[c0 + 2], cb[c0 + 3]};
  const float* qg = qw + g * 16;
  const float* kg = kw + g * 16;
  const float* vg = vw + g * 16;
  float qwv[16], kwv[16], vwv[16];
#pragma unroll
  for (int i = 0; i < 16; i++) { qwv[i] = qg[i]; kwv[i] = kg[i]; vwv[i] = vg[i]; }

  u32 vt_pack[4][4];   // [channel][s-pair] fully static indexing

#pragma unroll
  for (int i = 0; i < 8; i++) {
    float a0 = cbv[0], a1 = cbv[1], a2 = cbv[2], a3 = cbv[3];
#pragma unroll
    for (int kk = 0; kk < 4; kk++) {
      float4 xvv = xv[i + kk];
      a0 += xvv.x * cwv[0][kk];
      a1 += xvv.y * cwv[1][kk];
      a2 += xvv.z * cwv[2][kk];
      a3 += xvv.w * cwv[3][kk];
    }
    a0 = a0 / (1.f + __expf(-a0));
    a1 = a1 / (1.f + __expf(-a1));
    a2 = a2 / (1.f + __expf(-a2));
    a3 = a3 / (1.f + __expf(-a3));
    float4 accv = {a0, a1, a2, a3};
    *(float4*)(xc + (size_t)(r0 + i) * INNER_D + c0) = accv;

    float xcv[4] = {a0, a1, a2, a3};
    float xmv[4] = {xv[i + 3].x, xv[i + 3].y, xv[i + 3].z, xv[i + 3].w};
    ushort4 qs, ks, vs;
    u16* qp = (u16*)&qs; u16* kp = (u16*)&ks; u16* vp = (u16*)&vs;
#pragma unroll
    for (int o = 0; o < 4; o++) {
      float aq = 0.f, ak = 0.f, av = 0.f;
#pragma unroll
      for (int d = 0; d < 4; d++) {
        aq += xcv[d] * qwv[o * 4 + d];
        ak += xcv[d] * kwv[o * 4 + d];
        av += xmv[d] * vwv[o * 4 + d];
      }
      qp[o] = f2bf(aq); kp[o] = f2bf(ak);
      u16 vv = f2bf(av);
      vp[o] = vv;
      if ((i & 1) == 0) vt_pack[o][i >> 1] = (u32)vv;
      else              vt_pack[o][i >> 1] |= ((u32)vv) << 16;
    }
    size_t off = (size_t)(r0 + i) * INNER_D + c0;
    *(ushort4*)(q + off) = qs;
    *(ushort4*)(k + off) = ks;
    *(ushort4*)(v + off) = vs;
  }
  // V^T: vt[b][d][s], 16B (8 s-values) per channel
  u16* vtb = vt + ((size_t)((r0 >> 10) * INNER_D + c0)) * S_LEN + s0;
#pragma unroll
  for (int c = 0; c < 4; c++) {
    uint4 wv4 = {vt_pack[c][0], vt_pack[c][1], vt_pack[c][2], vt_pack[c][3]};
    *(uint4*)(vtb + (size_t)c * S_LEN) = wv4;
  }
}

// ---------------- gates as skinny MFMA GEMM, K-split x2: 256 blocks ----------------
// block 2i+h: rows [16i,16i+16), K half h (1536 each); outputs to half-offset buffers.
__global__ __launch_bounds__(256) void gates_mfma_kernel(
    const u16* __restrict__ q, const u16* __restrict__ k, const u16* __restrict__ v,
    const u16* __restrict__ whi, const u16* __restrict__ wlo,
    const float* __restrict__ igb, const float* __restrict__ fgb,
    float* __restrict__ ig, float* __restrict__ fg)
{
  const int blk2 = blockIdx.x;     // 0..255
  const int blk = blk2 >> 1, half = blk2 & 1;
  const int tid = threadIdx.x;
  const int wave = tid >> 6, lane = tid & 63;
  const int lm = lane & 15, lq = lane >> 4;
  const int grow = blk * 16 + lm;
  const u16* parts[3] = {q, k, v};
  f32x4 acc = {};
#pragma unroll 4
  for (int kc = 0; kc < 12; kc++) {
    int k0 = half * 1536 + wave * 384 + kc * 32;
    int part = k0 >> 10;
    int idx = (k0 & 1023) + lq * 8;
    S8 a, bh_, bl_;
    a.q = *(const uint4*)(parts[part] + (size_t)grow * INNER_D + idx);
    bh_.q = *(const uint4*)(whi + (size_t)lm * 3072 + k0 + lq * 8);
    bl_.q = *(const uint4*)(wlo + (size_t)lm * 3072 + k0 + lq * 8);
    __builtin_amdgcn_s_setprio(1);
    acc = __builtin_amdgcn_mfma_f32_16x16x32_bf16(a.v, bh_.v, acc, 0, 0, 0);
    acc = __builtin_amdgcn_mfma_f32_16x16x32_bf16(a.v, bl_.v, acc, 0, 0, 0);
    __builtin_amdgcn_s_setprio(0);
  }
  __shared__ float red[4][16][17];
#pragma unroll
  for (int r = 0; r < 4; r++) red[wave][lq * 4 + r][lm] = acc[r];
  __syncthreads();
  if (wave == 0) {
#pragma unroll
    for (int r = 0; r < 4; r++) {
      int row = lq * 4 + r;
      float sum = red[0][row][lm] + red[1][row][lm] + red[2][row][lm] + red[3][row][lm];
      int growr = blk * 16 + row;
      int b = growr >> 10, s = growr & (S_LEN - 1);
      if (lm < 8) {
        float bias = (half == 0) ? igb[lm] : 0.f;
        ig[half * 16384 + ((size_t)(b * NHEAD + lm) << 10) + s] = sum + bias;
      } else {
        float bias = (half == 0) ? fgb[lm - 8] : 0.f;
        fg[half * 16384 + ((size_t)(b * NHEAD + (lm - 8)) << 10) + s] = sum + bias;
      }
    }
  }
}

// ---------------- per-(b,h) scans, shuffle-based; sums gates K-halves; a := exp(a) ----------
__global__ __launch_bounds__(1024) void scan_kernel(
    const float* __restrict__ ig, const float* __restrict__ fg,
    float* __restrict__ a, float* __restrict__ rm, float* __restrict__ enm)
{
  int bh = blockIdx.x;
  int t = threadIdx.x;
  int lane = t & 63, wv = t >> 6;
  __shared__ float sw[16];
  size_t o = ((size_t)bh << 10) + t;
  float f = fg[o] + fg[16384 + o];
  float lf = (f >= 0.f) ? -log1pf(__expf(-f)) : f - log1pf(__expf(f));
  float v = lf;
#pragma unroll
  for (int off = 1; off < 64; off <<= 1) {
    float u = __shfl_up(v, off);
    if (lane >= off) v += u;
  }
  if (lane == 63) sw[wv] = v;
  __syncthreads();
  float pre = 0.f;
  for (int w = 0; w < wv; w++) pre += sw[w];
  float cs = v + pre;
  float av = (ig[o] + ig[16384 + o]) - cs;
  a[o] = __expf(av);                 // store exp(a): attention uses only exp(a)
  float m = av;
#pragma unroll
  for (int off = 1; off < 64; off <<= 1) {
    float u = __shfl_up(m, off);
    if (lane >= off) m = fmaxf(m, u);
  }
  __syncthreads();
  if (lane == 63) sw[wv] = m;
  __syncthreads();
  float pm = -3.4e38f;
  for (int w = 0; w < wv; w++) pm = fmaxf(pm, sw[w]);
  float rmx = fmaxf(m, pm);
  rm[o] = rmx;
  enm[o] = __expf(-(cs + rmx));
}

// ---------------- 128-q-row (8-wave) split-K MFMA attention, 15 jobs/bh ----------
// qp = q-tile-pair index (128 rows); k range in 64-t tiles.
__device__ __constant__ int c_qp[15] = {7, 7, 7, 6, 6, 6, 5, 5, 4, 4, 3, 3, 2, 1, 0};
__device__ __constant__ int c_k0[15] = {0, 6,11, 0, 5,10, 0, 6, 0, 5, 0, 4, 0, 0, 0};
__device__ __constant__ int c_k1[15] = {6,11,16, 5,10,14, 6,12, 5,10, 4, 8, 6, 4, 2};
__device__ __constant__ int c_md[15] = {1, 2, 3, 1, 2, 3, 1, 2, 1, 2, 1, 2, 0, 0, 0};

#define HP_SLOT 1310720   // 16 bh * 5 qr * 128 rows * 128
#define SC_SLOT 10240     // 16 bh * 5 qr * 128 rows

__global__ __launch_bounds__(512) void attn_mfma_kernel(
    const u16* __restrict__ qhg, const u16* __restrict__ khg, const u16* __restrict__ vtg,
    const float* __restrict__ a_arr, const float* __restrict__ rm_arr, const float* __restrict__ enm_arr,
    const float* __restrict__ xc, const u16* __restrict__ zh,
    const float* __restrict__ skip, const float* __restrict__ onw,
    u16* __restrict__ hs, float* __restrict__ hpart, float* __restrict__ scpart)
{
  const int bh = blockIdx.x;
  const int job = blockIdx.y;
  const int qp = c_qp[job], k0t = c_k0[job], k1t = c_k1[job], mode = c_md[job];
  const int b = bh >> 3, h = bh & 7;
  const int s0 = qp * 128;
  const int tid = threadIdx.x;
  const int wave = tid >> 6, lane = tid & 63;
  const int lm = lane & 15, lq = lane >> 4;
  const size_t rowbase = (size_t)b * S_LEN;
  const int c0 = h * DHEAD;

  __shared__ u16 Ks0[64 * 128], Ks1[64 * 128];  // [t][128], 16B slots XOR-swizzled by (t&7)
  __shared__ u16 Vt0[128 * 64], Vt1[128 * 64];  // [d][64],  16B slots XOR-swizzled by (d&7)
  __shared__ u16 Ws[128 * 72];

  short8 aq[4];
  {
    const u16* qpp = qhg + (rowbase + s0 + wave * 16 + lm) * INNER_D + c0 + lq * 8;
#pragma unroll
    for (int kc = 0; kc < 4; kc++) {
      S8 tmp; tmp.q = *(const uint4*)(qpp + kc * 32);
      aq[kc] = tmp.v;
    }
  }
  const float scale = 0.08838834764831845f;  // 1/sqrt(128)
  float rmv[4], er[4];
#pragma unroll
  for (int r = 0; r < 4; r++) {
    rmv[r] = rm_arr[(size_t)bh * S_LEN + s0 + wave * 16 + lq * 4 + r];
    er[r] = scale * __expf(-rmv[r]);   // hoisted: exp(a-rm) = exp(a)*exp(-rm)
  }

  f32x4 accH[8] = {};
  float sc_acc[4] = {0.f, 0.f, 0.f, 0.f};
  const int lr16 = lane >> 4;      // 0..3 (K rows: 256B each, 16 lanes/row)
  const int ls16 = lane & 15;      // 16B slot within 256B K row
  const int lr8 = lane >> 3;       // 0..7  (V rows: 128B each, 8 lanes/row)
  const int cgv = (lane & 7) ^ lr8;  // pre-swizzled V source slot
  const u16* vtbase = vtg + ((size_t)b * INNER_D + c0) * S_LEN;

  float ae0[4], ae1[4];

// 8 waves: each stages 2 K block-rows + 2 V block-rows; AE = exp(a) preloaded
#define PREF(KS, VS, AE, T0) do { \
  _Pragma("unroll") for (int j = 0; j < 2; j++) { \
    int rK = (wave * 2 + j) * 4 + lr16; \
    int cgk = ls16 ^ (rK & 7); \
    gload16(khg + (rowbase + (T0) + rK) * INNER_D + c0 + cgk * 8, &KS[(wave * 2 + j) * 512]); \
  } \
  _Pragma("unroll") for (int j = 0; j < 2; j++) { \
    int rV = (wave * 2 + j) * 8 + lr8; \
    gload16(vtbase + (size_t)rV * S_LEN + (T0) + cgv * 8, &VS[(wave * 2 + j) * 512]); \
  } \
  _Pragma("unroll") for (int cb = 0; cb < 4; cb++) \
    AE[cb] = a_arr[(size_t)bh * S_LEN + (T0) + cb * 16 + lm]; \
} while (0)

#define QK_STEP(KS, PACC) do { \
  __builtin_amdgcn_s_setprio(1); \
  _Pragma("unroll") for (int kc = 0; kc < 4; kc++) \
    _Pragma("unroll") for (int cb = 0; cb < 4; cb++) { \
      short8 bk = *(const short8*)&KS[(cb * 16 + lm) * 128 + (((kc * 4 + lq) ^ (lm & 7)) * 8)]; \
      PACC[cb] = __builtin_amdgcn_mfma_f32_16x16x32_bf16(aq[kc], bk, PACC[cb], 0, 0, 0); \
    } \
  __builtin_amdgcn_s_setprio(0); \
} while (0)

#define W_PV(AE, VT, T0, PACC) do { \
  float wpart[4] = {0.f, 0.f, 0.f, 0.f}; \
  _Pragma("unroll") for (int cb = 0; cb < 4; cb++) { \
    int colg = (T0) + cb * 16 + lm; \
    float ec = AE[cb]; \
    _Pragma("unroll") for (int r = 0; r < 4; r++) { \
      int rowg = s0 + wave * 16 + lq * 4 + r; \
      float wv = PACC[cb][r] * ec * er[r]; \
      if (colg > rowg) wv = 0.f; \
      wpart[r] += wv; \
      Ws[(wave * 16 + lq * 4 + r) * 72 + cb * 16 + lm] = f2bf(wv); \
    } \
  } \
  _Pragma("unroll") for (int r = 0; r < 4; r++) { \
    float sr = wpart[r]; \
    sr += __shfl_xor(sr, 1); sr += __shfl_xor(sr, 2); \
    sr += __shfl_xor(sr, 4); sr += __shfl_xor(sr, 8); \
    sc_acc[r] += sr; \
  } \
  __builtin_amdgcn_s_setprio(1); \
  _Pragma("unroll") for (int kc = 0; kc < 2; kc++) { \
    short8 aw = *(const short8*)&Ws[(wave * 16 + lm) * 72 + kc * 32 + lq * 8]; \
    _Pragma("unroll") for (int nb = 0; nb < 8; nb++) { \
      short8 bv = *(const short8*)&VT[(nb * 16 + lm) * 64 + (((kc * 4 + lq) ^ (lm & 7)) * 8)]; \
      accH[nb] = __builtin_amdgcn_mfma_f32_16x16x32_bf16(aw, bv, accH[nb], 0, 0, 0); \
    } \
  } \
  __builtin_amdgcn_s_setprio(0); \
} while (0)

  int kt = k0t;
  PREF(Ks0, Vt0, ae0, kt * 64);
  asm volatile("" ::: "memory");
  if (kt + 1 < k1t) PREF(Ks1, Vt1, ae1, (kt + 1) * 64);

  while (true) {
    {
      if (kt + 1 < k1t) asm volatile("s_waitcnt vmcnt(8)" ::: "memory");
      else              asm volatile("s_waitcnt vmcnt(0)" ::: "memory");
      __builtin_amdgcn_sched_barrier(0);
      __builtin_amdgcn_s_barrier();
      f32x4 pacc[4] = {};
      QK_STEP(Ks0, pacc);
      W_PV(ae0, Vt0, kt * 64, pacc);
      __builtin_amdgcn_s_barrier();
      if (kt + 2 < k1t) PREF(Ks0, Vt0, ae0, (kt + 2) * 64);
      kt++;
      if (kt >= k1t) break;
    }
    {
      if (kt + 1 < k1t) asm volatile("s_waitcnt vmcnt(8)" ::: "memory");
      else              asm volatile("s_waitcnt vmcnt(0)" ::: "memory");
      __builtin_amdgcn_sched_barrier(0);
      __builtin_amdgcn_s_barrier();
      f32x4 pacc[4] = {};
      QK_STEP(Ks1, pacc);
      W_PV(ae1, Vt1, kt * 64, pacc);
      __builtin_amdgcn_s_barrier();
      if (kt + 2 < k1t) PREF(Ks1, Vt1, ae1, (kt + 2) * 64);
      kt++;
      if (kt >= k1t) break;
    }
  }
#undef PREF
#undef QK_STEP
#undef W_PV

  if (mode != 0) {
    int slot = mode - 1;
    int qr = qp - 3;
    float* Hp = hpart + (size_t)slot * HP_SLOT + ((size_t)(bh * 5 + qr)) * 16384;
    float* sp = scpart + slot * SC_SLOT + (bh * 5 + qr) * 128;
#pragma unroll
    for (int r = 0; r < 4; r++) {
      int row = wave * 16 + lq * 4 + r;
      if (lm == 0) sp[row] = sc_acc[r];
#pragma unroll
      for (int nb = 0; nb < 8; nb++)
        Hp[row * 128 + nb * 16 + lm] = accH[nb][r];
    }
    return;
  }

  float inv[4], muv[4], rsv[4];
#pragma unroll
  for (int r = 0; r < 4; r++) {
    int rowg = s0 + wave * 16 + lq * 4 + r;
    float nrm = fmaxf(fabsf(sc_acc[r]), enm_arr[(size_t)bh * S_LEN + rowg]);
    inv[r] = 1.f / (nrm + 1e-6f);
  }
#pragma unroll
  for (int r = 0; r < 4; r++) {
    float s = 0.f, qq = 0.f;
#pragma unroll
    for (int nb = 0; nb < 8; nb++) {
      float hv = accH[nb][r] * inv[r];
      accH[nb][r] = hv;
      s += hv; qq += hv * hv;
    }
    s += __shfl_xor(s, 1); s += __shfl_xor(s, 2); s += __shfl_xor(s, 4); s += __shfl_xor(s, 8);
    qq += __shfl_xor(qq, 1); qq += __shfl_xor(qq, 2); qq += __shfl_xor(qq, 4); qq += __shfl_xor(qq, 8);
    float mu = s * (1.f / DHEAD);
    float var = qq * (1.f / DHEAD) - mu * mu;
    muv[r] = mu;
    rsv[r] = rsqrtf(var + 1e-5f);
  }
  float ow[8], sk[8];
#pragma unroll
  for (int nb = 0; nb < 8; nb++) {
    ow[nb] = onw[c0 + nb * 16 + lm];
    sk[nb] = skip[c0 + nb * 16 + lm];
  }
#pragma unroll
  for (int r = 0; r < 4; r++) {
    int rowg = s0 + wave * 16 + lq * 4 + r;
    size_t base = (rowbase + rowg) * INNER_D + c0;
#pragma unroll
    for (int nb = 0; nb < 8; nb++) {
      int d = nb * 16 + lm;
      float xcv = xc[base + d];
      float zv = bf2f(zh[base + d]);
      float hn = (accH[nb][r] - muv[r]) * rsv[r] * ow[nb] + sk[nb] * xcv;
      float o = hn * (zv / (1.f + __expf(-zv)));
      hs[base + d] = f2bf(o);
    }
  }
}

// combine 2..3 partial slots for rows s >= 384; one wave per row (10240 rows).
__global__ __launch_bounds__(256) void attn_combine_kernel(
    const float* __restrict__ hpart, const float* __restrict__ scpart,
    const float* __restrict__ enm,
    const float* __restrict__ xc, const u16* __restrict__ zh,
    const float* __restrict__ skip, const float* __restrict__ onw,
    u16* __restrict__ hs)
{
  int wave = threadIdx.x >> 6, lane = threadIdx.x & 63;
  int gid = blockIdx.x * 4 + wave;   // 0..10239
  int bh = gid / 640;
  int rr = gid % 640;
  int qr = rr >> 7, row = rr & 127;
  int b = bh >> 3, hh = bh & 7;
  int s = (qr + 3) * 128 + row;
  int nsl = (qr >= 3) ? 3 : 2;       // qp3-5: 2 slots, qp6-7: 3 slots
  size_t off = (((size_t)(bh * 5 + qr)) * 128 + row) * 128 + lane * 2;
  int sidx = (bh * 5 + qr) * 128 + row;
  float hx = 0.f, hy = 0.f, sc = 0.f;
  for (int sl = 0; sl < nsl; sl++) {
    float2 hp = *(const float2*)(hpart + (size_t)sl * HP_SLOT + off);
    hx += hp.x; hy += hp.y;
    sc += scpart[sl * SC_SLOT + sidx];
  }
  float nrm = fmaxf(fabsf(sc), enm[(size_t)bh * S_LEN + s]);
  float inv = 1.f / (nrm + 1e-6f);
  hx *= inv; hy *= inv;
  float sm = hx + hy, sq = hx * hx + hy * hy;
#pragma unroll
  for (int off2 = 32; off2; off2 >>= 1) { sm += __shfl_xor(sm, off2); sq += __shfl_xor(sq, off2); }
  float mu = sm * (1.f / DHEAD);
  float var = sq * (1.f / DHEAD) - mu * mu;
  float rs = rsqrtf(var + 1e-5f);
  int c0 = hh * DHEAD + lane * 2;
  size_t base = ((size_t)(b * S_LEN + s)) * INNER_D + c0;
  float2 xc2 = *(const float2*)(xc + base);
  ushort2 z2u = *(const ushort2*)(zh + base);
  float z2x = bf2f(z2u.x), z2y = bf2f(z2u.y);
  float skx = skip[c0], sky = skip[c0 + 1];
  float owx = onw[c0],  owy = onw[c0 + 1];
  ushort2 o;
  o.x = f2bf(((hx - mu) * rs * owx + skx * xc2.x) * (z2x / (1.f + __expf(-z2x))));
  o.y = f2bf(((hy - mu) * rs * owy + sky * xc2.y) * (z2y / (1.f + __expf(-z2y))));
  *(ushort2*)(hs + base) = o;
}

extern "C" void kernel_launch(void* const* d_in, const int* in_sizes, int n_in,
                              void* d_out, int out_size, void* d_ws, size_t ws_size,
                              hipStream_t stream)
{
  const float* x_enc   = (const float*)d_in[0];
  const float* x_mark  = (const float*)d_in[1];
  const float* emb_W   = (const float*)d_in[4];
  const float* emb_b   = (const float*)d_in[5];
  const float* ln_w    = (const float*)d_in[6];
  const float* up_W    = (const float*)d_in[7];
  const float* conv_W  = (const float*)d_in[8];
  const float* conv_b  = (const float*)d_in[9];
  const float* q_W     = (const float*)d_in[10];
  const float* k_W     = (const float*)d_in[11];
  const float* v_W     = (const float*)d_in[12];
  const float* ig_W    = (const float*)d_in[13];
  const float* ig_b    = (const float*)d_in[14];
  const float* fg_W    = (const float*)d_in[15];
  const float* fg_b    = (const float*)d_in[16];
  const float* skip_w  = (const float*)d_in[17];
  const float* onorm_w = (const float*)d_in[18];
  const float* down_W  = (const float*)d_in[19];
  const float* post_ln = (const float*)d_in[20];
  const float* head_W  = (const float*)d_in[21];
  const float* head_b  = (const float*)d_in[22];

  float* p = (float*)d_ws;
  float* x    = p; p += 1048576;   // 2048*512 f32
  float* xm   = p; p += 2097152;   // 2048*1024 f32; reused as hsbh bf16 after convqkv
  float* xc   = p; p += 2097152;
  float* igb_ = p; p += 32768;     // 2 K-halves x 16384
  float* fgb_ = p; p += 32768;
  float* ab   = p; p += 16384;     // holds exp(a)
  float* rmb  = p; p += 16384;
  float* enmb = p; p += 16384;
  u16* qhb = (u16*)p; p += 1048576;  // 2048*1024 u16
  u16* khb = (u16*)p; p += 1048576;
  u16* vhb = (u16*)p; p += 1048576;
  u16* zh  = (u16*)p; p += 1048576;  // 2048*1024 u16 (full size)
  u16* xnh = (u16*)p; p += 524288;   // 2048*512 u16
  u16* upWtA = (u16*)p; p += 2097152; // 4 x 2048x512 u16
  u16* dnWtA = (u16*)p; p += 1048576; // 4 x 512x1024 u16
  u16* gtwH = (u16*)p; p += 98304;    // 4 x 16 x 3072 u16
  u16* gtwL = (u16*)p; p += 98304;
  float* hpart = p; p += 3932160;     // 3 slots x 16 bh x 5 qr x 128 x 128 f32
  float* scpart = p; p += 32768;      // 3 slots x 10240 (padded)
  u16* vtg = (u16*)p; p += 1048576;   // 2 x 1024 x 1024 u16 (V^T per layer)
  u16* hsbh = (u16*)xm;

  // one merged prep launch: up/down weight transposes + gates weights + embedding
  prep_kernel<<<4352, 256, 0, stream>>>(
      up_W, upWtA, down_W, dnWtA, ig_W, fg_W, gtwH, gtwL,
      x_enc, x_mark, emb_W, emb_b, x);

  for (int L = 0; L < 4; L++) {
    ln_kernel<<<2048, 256, 0, stream>>>(x, ln_w + L * 512, xnh);
    gemm_bf16_split64<<<dim3(16, 16), 256, 0, stream>>>(
        xnh, upWtA + (size_t)L * 1048576, xm, zh, 2048, 2048, 512, 1024, 1024);
    convqkv_kernel<<<256, 256, 0, stream>>>(
        xm, conv_W + L * 4096, conv_b + L * 1024,
        q_W + L * 4096, k_W + L * 4096, v_W + L * 4096,
        xc, qhb, khb, vhb, vtg);
    gates_mfma_kernel<<<256, 256, 0, stream>>>(
        qhb, khb, vhb, gtwH + (size_t)L * 49152, gtwL + (size_t)L * 49152,
        ig_b + L * 8, fg_b + L * 8, igb_, fgb_);
    scan_kernel<<<16, 1024, 0, stream>>>(igb_, fgb_, ab, rmb, enmb);
    attn_mfma_kernel<<<dim3(16, 15), 512, 0, stream>>>(
        qhb, khb, vtg, ab, rmb, enmb, xc, zh,
        skip_w + L * 1024, onorm_w + L * 1024, hsbh, hpart, scpart);
    attn_combine_kernel<<<2560, 256, 0, stream>>>(
        hpart, scpart, enmb, xc, zh, skip_w + L * 1024, onorm_w + L * 1024, hsbh);
    gemm_bf16_32<<<dim3(8, 32), 256, 0, stream>>>(
        hsbh, dnWtA + (size_t)L * 524288, x, 2048, 512, 1024, 512);
  }

  lnhead_kernel<<<192, 256, 0, stream>>>(x, post_ln, head_W, head_b, (float*)d_out);
}

// Round 12
// 415.457 us; speedup vs baseline: 1.1084x; 1.0321x over previous
//
#include <hip/hip_runtime.h>
#include <hip/hip_bf16.h>

#define S_LEN 1024
#define E_DIM 512
#define INNER_D 1024
#define NHEAD 8
#define DHEAD 128

typedef unsigned short u16;
typedef unsigned int u32;
typedef __attribute__((ext_vector_type(8))) short short8;
typedef __attribute__((ext_vector_type(4))) float f32x4;

union S8 { short8 v; u16 u[8]; uint4 q; };

__device__ __forceinline__ u16 f2bf(float f) {
  u32 u = __float_as_uint(f);
  u32 r = u + 0x7FFFu + ((u >> 16) & 1u);
  return (u16)(r >> 16);
}
__device__ __forceinline__ float bf2f(u16 u) { return __uint_as_float(((u32)u) << 16); }

// direct global -> LDS (16B per lane). LDS dest = wave-uniform base + lane*16B (linear).
__device__ __forceinline__ void gload16(const u16* g, u16* l) {
  __builtin_amdgcn_global_load_lds((const __attribute__((address_space(1))) void*)g,
                                   (__attribute__((address_space(3))) void*)l, 16, 0, 0);
}

// ---------------- merged one-time prep: transposes + gates weights + embedding ----------------
__device__ __forceinline__ void prep_transpose(
    const float* __restrict__ in, u16* __restrict__ out, int K, int N,
    int k0, int n0, int t, u16 (*T)[72])
{
  int kr = t >> 2, nseg = (t & 3) * 16;
  const float* src = in + (size_t)(k0 + kr) * N + n0 + nseg;
#pragma unroll
  for (int j = 0; j < 16; j++) T[kr][nseg + j] = f2bf(src[j]);
  __syncthreads();
  int nr = t >> 2, kseg = (t & 3) * 16;
  u32 u[8];
#pragma unroll
  for (int rr = 0; rr < 8; rr++) {
    u32 lo = T[kseg + 2 * rr][nr];
    u32 hi = T[kseg + 2 * rr + 1][nr];
    u[rr] = lo | (hi << 16);
  }
  u16* dst = out + (size_t)(n0 + nr) * K + k0 + kseg;
  uint4 w0 = {u[0], u[1], u[2], u[3]};
  uint4 w1 = {u[4], u[5], u[6], u[7]};
  *(uint4*)dst = w0;
  *(uint4*)(dst + 8) = w1;
}

__global__ __launch_bounds__(256) void prep_kernel(
    const float* __restrict__ up_W, u16* __restrict__ upWt,
    const float* __restrict__ down_W, u16* __restrict__ dnWt,
    const float* __restrict__ igW, const float* __restrict__ fgW,
    u16* __restrict__ ghi, u16* __restrict__ glo,
    const float* __restrict__ xe, const float* __restrict__ xmk,
    const float* __restrict__ eW, const float* __restrict__ eb,
    float* __restrict__ x)
{
  __shared__ u16 T[64][72];
  __shared__ float in_s[25];
  int id = blockIdx.x;
  int t = threadIdx.x;
  if (id < 1024) {                     // up_W transpose: [L][512][2048] -> [L][2048][512]
    int bx = id & 7, rest = id >> 3;
    int by = rest & 31, L = rest >> 5;
    prep_transpose(up_W + (size_t)L * 512 * 2048, upWt + (size_t)L * 1048576,
                   512, 2048, bx * 64, by * 64, t, T);
  } else if (id < 1536) {              // down_W transpose: [L][1024][512] -> [L][512][1024]
    int id2 = id - 1024;
    int bx = id2 & 15, rest = id2 >> 4;
    int by = rest & 7, L = rest >> 3;
    prep_transpose(down_W + (size_t)L * 1024 * 512, dnWt + (size_t)L * 524288,
                   1024, 512, bx * 64, by * 64, t, T);
  } else if (id < 2304) {              // gates weights: hi/lo split transpose
    int id3 = id - 1536;
    int bx = id3 % 12, rest = id3 / 12;
    int n = rest & 15, L = rest >> 4;
    int k = bx * 256 + t;
    const float* W = ((n < 8) ? igW : fgW) + (size_t)L * 24576;
    float v = W[(size_t)k * 8 + (n & 7)];
    u16 h = f2bf(v);
    u16 l = f2bf(v - bf2f(h));
    size_t o = ((size_t)L * 16 + n) * 3072 + k;
    ghi[o] = h;
    glo[o] = l;
  } else {                             // embedding, one row per block
    int row = id - 2304;
    if (t < 21) in_s[t] = xe[row * 21 + t];
    else if (t < 25) in_s[t] = xmk[row * 4 + t - 21];
    __syncthreads();
#pragma unroll
    for (int rep = 0; rep < 2; rep++) {
      int e = t + rep * 256;
      float acc = eb[e];
#pragma unroll
      for (int i = 0; i < 25; i++) acc += in_s[i] * eW[i * E_DIM + e];
      x[(size_t)row * E_DIM + e] = acc;
    }
  }
}

// ---------------- layernorm -> bf16 ----------------
__global__ __launch_bounds__(256) void ln_kernel(
    const float* __restrict__ x, const float* __restrict__ w, u16* __restrict__ out)
{
  int row = blockIdx.x, tid = threadIdx.x;
  const float* xr = x + (size_t)row * E_DIM;
  float2 v = *(const float2*)(xr + tid * 2);
  float s = v.x + v.y, q = v.x * v.x + v.y * v.y;
#pragma unroll
  for (int off = 32; off; off >>= 1) { s += __shfl_xor(s, off); q += __shfl_xor(q, off); }
  __shared__ float ssum[4], ssq[4];
  int wv = tid >> 6;
  if ((tid & 63) == 0) { ssum[wv] = s; ssq[wv] = q; }
  __syncthreads();
  s = ssum[0] + ssum[1] + ssum[2] + ssum[3];
  q = ssq[0] + ssq[1] + ssq[2] + ssq[3];
  float mu = s * (1.f / E_DIM);
  float var = q * (1.f / E_DIM) - mu * mu;
  float rs = rsqrtf(var + 1e-5f);
  int e = tid * 2;
  ushort2 o;
  o.x = f2bf((v.x - mu) * rs * w[e]);
  o.y = f2bf((v.y - mu) * rs * w[e + 1]);
  *(ushort2*)(out + (size_t)row * E_DIM + e) = o;
}

// ---------------- fused final layernorm + head (one block per output row) ----------------
__global__ __launch_bounds__(256) void lnhead_kernel(
    const float* __restrict__ x, const float* __restrict__ w,
    const float* __restrict__ hW, const float* __restrict__ hb,
    float* __restrict__ out)
{
  int ridx = blockIdx.x;
  int b = ridx / 96, r = ridx % 96;
  int row = b * S_LEN + (S_LEN - 96) + r;
  int tid = threadIdx.x;
  const float* xr = x + (size_t)row * E_DIM;
  float2 v = *(const float2*)(xr + tid * 2);
  float s = v.x + v.y, q = v.x * v.x + v.y * v.y;
#pragma unroll
  for (int off = 32; off; off >>= 1) { s += __shfl_xor(s, off); q += __shfl_xor(q, off); }
  __shared__ float ssum[4], ssq[4];
  __shared__ float lnv[512];
  __shared__ float part[8][32];
  int wv = tid >> 6;
  if ((tid & 63) == 0) { ssum[wv] = s; ssq[wv] = q; }
  __syncthreads();
  s = ssum[0] + ssum[1] + ssum[2] + ssum[3];
  q = ssq[0] + ssq[1] + ssq[2] + ssq[3];
  float mu = s * (1.f / E_DIM);
  float var = q * (1.f / E_DIM) - mu * mu;
  float rs = rsqrtf(var + 1e-5f);
  int e = tid * 2;
  lnv[e]     = (v.x - mu) * rs * w[e];
  lnv[e + 1] = (v.y - mu) * rs * w[e + 1];
  __syncthreads();
  int n = tid & 31, sl = tid >> 5;
  float p = 0.f;
  if (n < 21) {
#pragma unroll 8
    for (int kk = 0; kk < 64; kk++)
      p += lnv[sl * 64 + kk] * hW[(sl * 64 + kk) * 21 + n];
  }
  part[sl][n] = p;
  __syncthreads();
  if (tid < 21) {
    float acc = hb[tid];
#pragma unroll
    for (int j = 0; j < 8; j++) acc += part[j][tid];
    out[ridx * 21 + tid] = acc;
  }
}

// ---------------- bf16 MFMA GEMM 128x128, BK=64, 3-deep counted-vmcnt pipeline --------------
// split C: C0 f32, C1 bf16; grid (N/128, M/128). K must be 512 (NT=8).
__global__ __launch_bounds__(256) void gemm_bf16_split64(
    const u16* __restrict__ A, const u16* __restrict__ Bt,
    float* __restrict__ C0, u16* __restrict__ C1,
    int M, int N, int K, int split_col, int ldc)
{
  __shared__ u16 As0[128 * 64], As1[128 * 64], As2[128 * 64];
  __shared__ u16 Bs0[128 * 64], Bs1[128 * 64], Bs2[128 * 64];
  const int tid = threadIdx.x;
  const int row0 = blockIdx.y * 128, col0 = blockIdx.x * 128;
  const int wave = tid >> 6, lane = tid & 63;
  const int wr = wave >> 1, wc = wave & 1;   // wave tile: 64 rows x 64 cols
  const int lm = lane & 15, lq = lane >> 4;
  const int lr8 = lane >> 3;                 // 0..7 row within 8-row group
  const int cg8 = (lane & 7) ^ lr8;          // pre-swizzled source 16B slot (8 slots/row)
  f32x4 acc[4][4] = {};
  const u16* Abase = A + (size_t)(row0 + lr8) * K + cg8 * 8;
  const u16* Bbase = Bt + (size_t)(col0 + lr8) * K + cg8 * 8;
  const int key = lm & 7;

#define STG_UP(AS, BS, K0) do { \
  _Pragma("unroll") for (int i = 0; i < 4; i++) \
    gload16(Abase + (size_t)((wave * 4 + i) * 8) * K + (K0), &AS[(wave * 4 + i) * 512]); \
  _Pragma("unroll") for (int i = 0; i < 4; i++) \
    gload16(Bbase + (size_t)((wave * 4 + i) * 8) * K + (K0), &BS[(wave * 4 + i) * 512]); \
} while (0)

#define CMP_UP(AS, BS) do { \
  _Pragma("unroll") for (int kc = 0; kc < 2; kc++) { \
    short8 af[4], bfv[4]; \
    _Pragma("unroll") for (int i = 0; i < 4; i++) \
      af[i] = *(const short8*)&AS[(wr * 64 + i * 16 + lm) * 64 + (((kc * 4 + lq) ^ key) * 8)]; \
    _Pragma("unroll") for (int j = 0; j < 4; j++) \
      bfv[j] = *(const short8*)&BS[(wc * 64 + j * 16 + lm) * 64 + (((kc * 4 + lq) ^ key) * 8)]; \
    _Pragma("unroll") for (int i = 0; i < 4; i++) \
      _Pragma("unroll") for (int j = 0; j < 4; j++) \
        acc[i][j] = __builtin_amdgcn_mfma_f32_16x16x32_bf16(af[i], bfv[j], acc[i][j], 0, 0, 0); \
  } \
} while (0)

  STG_UP(As0, Bs0, 0);
  asm volatile("" ::: "memory");
  STG_UP(As1, Bs1, 64);
  asm volatile("" ::: "memory");
  STG_UP(As2, Bs2, 128);
  // 24 DMA ops/wave in flight (8 per tile, 3 tiles)
#pragma unroll
  for (int t = 0; t < 8; t++) {
    if (t <= 5)       asm volatile("s_waitcnt vmcnt(16)" ::: "memory");
    else if (t == 6)  asm volatile("s_waitcnt vmcnt(8)" ::: "memory");
    else              asm volatile("s_waitcnt vmcnt(0)" ::: "memory");
    __builtin_amdgcn_sched_barrier(0);
    __builtin_amdgcn_s_barrier();
    if ((t % 3) == 0)      CMP_UP(As0, Bs0);
    else if ((t % 3) == 1) CMP_UP(As1, Bs1);
    else                   CMP_UP(As2, Bs2);
    __builtin_amdgcn_s_barrier();
    if (t + 3 < 8) {
      if ((t % 3) == 0)      STG_UP(As0, Bs0, (t + 3) * 64);
      else if ((t % 3) == 1) STG_UP(As1, Bs1, (t + 3) * 64);
      else                   STG_UP(As2, Bs2, (t + 3) * 64);
    }
  }
#undef STG_UP
#undef CMP_UP

  const bool toC1 = (col0 >= split_col);
#pragma unroll
  for (int i = 0; i < 4; i++) {
#pragma unroll
    for (int j = 0; j < 4; j++) {
      int col = col0 - (toC1 ? split_col : 0) + wc * 64 + j * 16 + lm;
#pragma unroll
      for (int r = 0; r < 4; r++) {
        int row = row0 + wr * 64 + i * 16 + lq * 4 + r;
        if (toC1) C1[(size_t)row * ldc + col] = f2bf(acc[i][j][r]);
        else C0[(size_t)row * ldc + col] = acc[i][j][r];
      }
    }
  }
}

// ---------------- bf16 MFMA GEMM 64x64 (down-proj, +=), BK=128, 3-deep pipeline -------------
// K must be 1024 (NT=8).
__global__ __launch_bounds__(256) void gemm_bf16_32(
    const u16* __restrict__ A, const u16* __restrict__ Bt,
    float* __restrict__ C, int M, int N, int K, int ldc)
{
  __shared__ u16 As0[64 * 128], As1[64 * 128], As2[64 * 128];
  __shared__ u16 Bs0[64 * 128], Bs1[64 * 128], Bs2[64 * 128];
  const int tid = threadIdx.x;
  const int row0 = blockIdx.y * 64, col0 = blockIdx.x * 64;
  const int wave = tid >> 6, lane = tid & 63;
  const int wr = wave >> 1, wc = wave & 1;   // wave tile: 32 rows x 32 cols
  const int lm = lane & 15, lq = lane >> 4;
  const int lr16 = lane >> 4;                // 0..3 row within 4-row group (256B rows)
  const int ls16 = lane & 15;                // 16B slot within row (16 slots)
  f32x4 acc[2][2] = {};

#define STAGE_DN(AS, BS, K0) do { \
  _Pragma("unroll") for (int i = 0; i < 4; i++) { \
    int rA = (wave * 4 + i) * 4 + lr16; \
    int cgk = ls16 ^ (rA & 15); \
    gload16(A + (size_t)(row0 + rA) * K + (K0) + cgk * 8, &AS[(wave * 4 + i) * 512]); \
  } \
  _Pragma("unroll") for (int i = 0; i < 4; i++) { \
    int rB = (wave * 4 + i) * 4 + lr16; \
    int cgk = ls16 ^ (rB & 15); \
    gload16(Bt + (size_t)(col0 + rB) * K + (K0) + cgk * 8, &BS[(wave * 4 + i) * 512]); \
  } \
} while (0)

#define COMPUTE_DN(AS, BS) do { \
  _Pragma("unroll") for (int kc = 0; kc < 4; kc++) { \
    short8 af[2], bfv[2]; \
    _Pragma("unroll") for (int i = 0; i < 2; i++) \
      af[i] = *(const short8*)&AS[(wr * 32 + i * 16 + lm) * 128 + (((kc * 4 + lq) ^ lm) * 8)]; \
    _Pragma("unroll") for (int j = 0; j < 2; j++) \
      bfv[j] = *(const short8*)&BS[(wc * 32 + j * 16 + lm) * 128 + (((kc * 4 + lq) ^ lm) * 8)]; \
    _Pragma("unroll") for (int i = 0; i < 2; i++) \
      _Pragma("unroll") for (int j = 0; j < 2; j++) \
        acc[i][j] = __builtin_amdgcn_mfma_f32_16x16x32_bf16(af[i], bfv[j], acc[i][j], 0, 0, 0); \
  } \
} while (0)

  STAGE_DN(As0, Bs0, 0);
  asm volatile("" ::: "memory");
  STAGE_DN(As1, Bs1, 128);
  asm volatile("" ::: "memory");
  STAGE_DN(As2, Bs2, 256);
  // 24 DMA ops/wave in flight (8 per tile, 3 tiles)
#pragma unroll
  for (int t = 0; t < 8; t++) {
    if (t <= 5)       asm volatile("s_waitcnt vmcnt(16)" ::: "memory");
    else if (t == 6)  asm volatile("s_waitcnt vmcnt(8)" ::: "memory");
    else              asm volatile("s_waitcnt vmcnt(0)" ::: "memory");
    __builtin_amdgcn_sched_barrier(0);
    __builtin_amdgcn_s_barrier();
    if ((t % 3) == 0)      COMPUTE_DN(As0, Bs0);
    else if ((t % 3) == 1) COMPUTE_DN(As1, Bs1);
    else                   COMPUTE_DN(As2, Bs2);
    __builtin_amdgcn_s_barrier();
    if (t + 3 < 8) {
      if ((t % 3) == 0)      STAGE_DN(As0, Bs0, (t + 3) * 128);
      else if ((t % 3) == 1) STAGE_DN(As1, Bs1, (t + 3) * 128);
      else                   STAGE_DN(As2, Bs2, (t + 3) * 128);
    }
  }
#undef STAGE_DN
#undef COMPUTE_DN

#pragma unroll
  for (int i = 0; i < 2; i++) {
#pragma unroll
    for (int j = 0; j < 2; j++) {
      int col = col0 + wc * 32 + j * 16 + lm;
#pragma unroll
      for (int r = 0; r < 4; r++) {
        int row = row0 + wr * 32 + i * 16 + lq * 4 + r;
        C[(size_t)row * ldc + col] += acc[i][j][r];
      }
    }
  }
}

// ---------------- fused causal conv+SiLU+headwise qkv; 8 rows/block; writes V and V^T -------
__global__ __launch_bounds__(256) void convqkv_kernel(
    const float* __restrict__ xm,
    const float* __restrict__ cw, const float* __restrict__ cb,
    const float* __restrict__ qw, const float* __restrict__ kw, const float* __restrict__ vw,
    float* __restrict__ xc, u16* __restrict__ q, u16* __restrict__ k, u16* __restrict__ v,
    u16* __restrict__ vt)
{
  int r0 = blockIdx.x * 8;         // rows r0..r0+7, same batch (S_LEN % 8 == 0)
  int s0 = r0 & (S_LEN - 1);
  int g = threadIdx.x;             // channel group of 4
  int c0 = g * 4;
  const float* base = xm + (size_t)r0 * INNER_D + c0;

  float4 xv[11];
#pragma unroll
  for (int j = 0; j < 11; j++) {
    int ts = s0 - 3 + j;
    float4 t = {0.f, 0.f, 0.f, 0.f};
    if (ts >= 0) t = *(const float4*)(base + (ptrdiff_t)(j - 3) * INNER_D);
    xv[j] = t;
  }
  float cwv[4][4];
#pragma unroll
  for (int c = 0; c < 4; c++)
#pragma unroll
    for (int kk = 0; kk < 4; kk++) cwv[c][kk] = cw[(c0 + c) * 4 + kk];
  float cbv[4] = {cb[c0], cb[c0 + 1], cb[c0 + 2], cb[c0 + 3]};
  const float* qg = qw + g * 16;
  const float* kg = kw + g * 16;
  const float* vg = vw + g * 16;
  float qwv[16], kwv[16], vwv[16];
#pragma unroll
  for (int i = 0; i < 16; i++) { qwv[i] = qg[i]; kwv[i] = kg[i]; vwv[i] = vg[i]; }

  u32 vt_pack[4][4];   // [channel][s-pair] fully static indexing

#pragma unroll
  for (int i = 0; i < 8; i++) {
    float a0 = cbv[0], a1 = cbv[1], a2 = cbv[2], a3 = cbv[3];
#pragma unroll
    for (int kk = 0; kk < 4; kk++) {
      float4 xvv = xv[i + kk];
      a0 += xvv.x * cwv[0][kk];
      a1 += xvv.y * cwv[1][kk];
      a2 += xvv.z * cwv[2][kk];
      a3 += xvv.w * cwv[3][kk];
    }
    a0 = a0 / (1.f + __expf(-a0));
    a1 = a1 / (1.f + __expf(-a1));
    a2 = a2 / (1.f + __expf(-a2));
    a3 = a3 / (1.f + __expf(-a3));
    float4 accv = {a0, a1, a2, a3};
    *(float4*)(xc + (size_t)(r0 + i) * INNER_D + c0) = accv;

    float xcv[4] = {a0, a1, a2, a3};
    float xmv[4] = {xv[i + 3].x, xv[i + 3].y, xv[i + 3].z, xv[i + 3].w};
    ushort4 qs, ks, vs;
    u16* qp = (u16*)&qs; u16* kp = (u16*)&ks; u16* vp = (u16*)&vs;
#pragma unroll
    for (int o = 0; o < 4; o++) {
      float aq = 0.f, ak = 0.f, av = 0.f;
#pragma unroll
      for (int d = 0; d < 4; d++) {
        aq += xcv[d] * qwv[o * 4 + d];
        ak += xcv[d] * kwv[o * 4 + d];
        av += xmv[d] * vwv[o * 4 + d];
      }
      qp[o] = f2bf(aq); kp[o] = f2bf(ak);
      u16 vv = f2bf(av);
      vp[o] = vv;
      if ((i & 1) == 0) vt_pack[o][i >> 1] = (u32)vv;
      else              vt_pack[o][i >> 1] |= ((u32)vv) << 16;
    }
    size_t off = (size_t)(r0 + i) * INNER_D + c0;
    *(ushort4*)(q + off) = qs;
    *(ushort4*)(k + off) = ks;
    *(ushort4*)(v + off) = vs;
  }
  // V^T: vt[b][d][s], 16B (8 s-values) per channel
  u16* vtb = vt + ((size_t)((r0 >> 10) * INNER_D + c0)) * S_LEN + s0;
#pragma unroll
  for (int c = 0; c < 4; c++) {
    uint4 wv4 = {vt_pack[c][0], vt_pack[c][1], vt_pack[c][2], vt_pack[c][3]};
    *(uint4*)(vtb + (size_t)c * S_LEN) = wv4;
  }
}

// ---------------- gates as skinny MFMA GEMM, K-split x2: 256 blocks ----------------
// block 2i+h: rows [16i,16i+16), K half h (1536 each); outputs to half-offset buffers.
__global__ __launch_bounds__(256) void gates_mfma_kernel(
    const u16* __restrict__ q, const u16* __restrict__ k, const u16* __restrict__ v,
    const u16* __restrict__ whi, const u16* __restrict__ wlo,
    const float* __restrict__ igb, const float* __restrict__ fgb,
    float* __restrict__ ig, float* __restrict__ fg)
{
  const int blk2 = blockIdx.x;     // 0..255
  const int blk = blk2 >> 1, half = blk2 & 1;
  const int tid = threadIdx.x;
  const int wave = tid >> 6, lane = tid & 63;
  const int lm = lane & 15, lq = lane >> 4;
  const int grow = blk * 16 + lm;
  const u16* parts[3] = {q, k, v};
  f32x4 acc = {};
#pragma unroll 4
  for (int kc = 0; kc < 12; kc++) {
    int k0 = half * 1536 + wave * 384 + kc * 32;
    int part = k0 >> 10;
    int idx = (k0 & 1023) + lq * 8;
    S8 a, bh_, bl_;
    a.q = *(const uint4*)(parts[part] + (size_t)grow * INNER_D + idx);
    bh_.q = *(const uint4*)(whi + (size_t)lm * 3072 + k0 + lq * 8);
    bl_.q = *(const uint4*)(wlo + (size_t)lm * 3072 + k0 + lq * 8);
    __builtin_amdgcn_s_setprio(1);
    acc = __builtin_amdgcn_mfma_f32_16x16x32_bf16(a.v, bh_.v, acc, 0, 0, 0);
    acc = __builtin_amdgcn_mfma_f32_16x16x32_bf16(a.v, bl_.v, acc, 0, 0, 0);
    __builtin_amdgcn_s_setprio(0);
  }
  __shared__ float red[4][16][17];
#pragma unroll
  for (int r = 0; r < 4; r++) red[wave][lq * 4 + r][lm] = acc[r];
  __syncthreads();
  if (wave == 0) {
#pragma unroll
    for (int r = 0; r < 4; r++) {
      int row = lq * 4 + r;
      float sum = red[0][row][lm] + red[1][row][lm] + red[2][row][lm] + red[3][row][lm];
      int growr = blk * 16 + row;
      int b = growr >> 10, s = growr & (S_LEN - 1);
      if (lm < 8) {
        float bias = (half == 0) ? igb[lm] : 0.f;
        ig[half * 16384 + ((size_t)(b * NHEAD + lm) << 10) + s] = sum + bias;
      } else {
        float bias = (half == 0) ? fgb[lm - 8] : 0.f;
        fg[half * 16384 + ((size_t)(b * NHEAD + (lm - 8)) << 10) + s] = sum + bias;
      }
    }
  }
}

// ---------------- per-(b,h) scans, shuffle-based; sums gates K-halves; a := exp(a) ----------
__global__ __launch_bounds__(1024) void scan_kernel(
    const float* __restrict__ ig, const float* __restrict__ fg,
    float* __restrict__ a, float* __restrict__ rm, float* __restrict__ enm)
{
  int bh = blockIdx.x;
  int t = threadIdx.x;
  int lane = t & 63, wv = t >> 6;
  __shared__ float sw[16];
  size_t o = ((size_t)bh << 10) + t;
  float f = fg[o] + fg[16384 + o];
  float lf = (f >= 0.f) ? -log1pf(__expf(-f)) : f - log1pf(__expf(f));
  float v = lf;
#pragma unroll
  for (int off = 1; off < 64; off <<= 1) {
    float u = __shfl_up(v, off);
    if (lane >= off) v += u;
  }
  if (lane == 63) sw[wv] = v;
  __syncthreads();
  float pre = 0.f;
  for (int w = 0; w < wv; w++) pre += sw[w];
  float cs = v + pre;
  float av = (ig[o] + ig[16384 + o]) - cs;
  a[o] = __expf(av);                 // store exp(a): attention uses only exp(a)
  float m = av;
#pragma unroll
  for (int off = 1; off < 64; off <<= 1) {
    float u = __shfl_up(m, off);
    if (lane >= off) m = fmaxf(m, u);
  }
  __syncthreads();
  if (lane == 63) sw[wv] = m;
  __syncthreads();
  float pm = -3.4e38f;
  for (int w = 0; w < wv; w++) pm = fmaxf(pm, sw[w]);
  float rmx = fmaxf(m, pm);
  rm[o] = rmx;
  enm[o] = __expf(-(cs + rmx));
}

// ---------------- 128-q-row (8-wave) split-K MFMA attention, 15 jobs/bh ----------
// qp = q-tile-pair index (128 rows); k range in 64-t tiles.
__device__ __constant__ int c_qp[15] = {7, 7, 7, 6, 6, 6, 5, 5, 4, 4, 3, 3, 2, 1, 0};
__device__ __constant__ int c_k0[15] = {0, 6,11, 0, 5,10, 0, 6, 0, 5, 0, 4, 0, 0, 0};
__device__ __constant__ int c_k1[15] = {6,11,16, 5,10,14, 6,12, 5,10, 4, 8, 6, 4, 2};
__device__ __constant__ int c_md[15] = {1, 2, 3, 1, 2, 3, 1, 2, 1, 2, 1, 2, 0, 0, 0};

#define HP_SLOT 1310720   // 16 bh * 5 qr * 128 rows * 128
#define SC_SLOT 10240     // 16 bh * 5 qr * 128 rows

__global__ __launch_bounds__(512) void attn_mfma_kernel(
    const u16* __restrict__ qhg, const u16* __restrict__ khg, const u16* __restrict__ vtg,
    const float* __restrict__ a_arr, const float* __restrict__ rm_arr, const float* __restrict__ enm_arr,
    const float* __restrict__ xc, const u16* __restrict__ zh,
    const float* __restrict__ skip, const float* __restrict__ onw,
    u16* __restrict__ hs, float* __restrict__ hpart, float* __restrict__ scpart)
{
  const int bh = blockIdx.x;
  const int job = blockIdx.y;
  const int qp = c_qp[job], k0t = c_k0[job], k1t = c_k1[job], mode = c_md[job];
  const int b = bh >> 3, h = bh & 7;
  const int s0 = qp * 128;
  const int tid = threadIdx.x;
  const int wave = tid >> 6, lane = tid & 63;
  const int lm = lane & 15, lq = lane >> 4;
  const size_t rowbase = (size_t)b * S_LEN;
  const int c0 = h * DHEAD;

  __shared__ u16 Ks0[64 * 128], Ks1[64 * 128];  // [t][128], 16B slots XOR-swizzled by (t&7)
  __shared__ u16 Vt0[128 * 64], Vt1[128 * 64];  // [d][64],  16B slots XOR-swizzled by (d&7)
  __shared__ u16 Ws[128 * 72];

  short8 aq[4];
  {
    const u16* qpp = qhg + (rowbase + s0 + wave * 16 + lm) * INNER_D + c0 + lq * 8;
#pragma unroll
    for (int kc = 0; kc < 4; kc++) {
      S8 tmp; tmp.q = *(const uint4*)(qpp + kc * 32);
      aq[kc] = tmp.v;
    }
  }
  const float scale = 0.08838834764831845f;  // 1/sqrt(128)
  float rmv[4], er[4];
#pragma unroll
  for (int r = 0; r < 4; r++) {
    rmv[r] = rm_arr[(size_t)bh * S_LEN + s0 + wave * 16 + lq * 4 + r];
    er[r] = scale * __expf(-rmv[r]);   // hoisted: exp(a-rm) = exp(a)*exp(-rm)
  }

  // bf16 ones vector for MFMA row-sum (sc = P @ 1)
  S8 onesu;
#pragma unroll
  for (int j = 0; j < 8; j++) onesu.u[j] = 0x3F80;
  const short8 ones8 = onesu.v;

  f32x4 accH[8] = {};
  f32x4 accS = {};
  const int lr16 = lane >> 4;      // 0..3 (K rows: 256B each, 16 lanes/row)
  const int ls16 = lane & 15;      // 16B slot within 256B K row
  const int lr8 = lane >> 3;       // 0..7  (V rows: 128B each, 8 lanes/row)
  const int cgv = (lane & 7) ^ lr8;  // pre-swizzled V source slot
  const u16* vtbase = vtg + ((size_t)b * INNER_D + c0) * S_LEN;

  float ae0[4], ae1[4];

// 8 waves: each stages 2 K block-rows + 2 V block-rows; AE = exp(a) preloaded
#define PREF(KS, VS, AE, T0) do { \
  _Pragma("unroll") for (int j = 0; j < 2; j++) { \
    int rK = (wave * 2 + j) * 4 + lr16; \
    int cgk = ls16 ^ (rK & 7); \
    gload16(khg + (rowbase + (T0) + rK) * INNER_D + c0 + cgk * 8, &KS[(wave * 2 + j) * 512]); \
  } \
  _Pragma("unroll") for (int j = 0; j < 2; j++) { \
    int rV = (wave * 2 + j) * 8 + lr8; \
    gload16(vtbase + (size_t)rV * S_LEN + (T0) + cgv * 8, &VS[(wave * 2 + j) * 512]); \
  } \
  _Pragma("unroll") for (int cb = 0; cb < 4; cb++) \
    AE[cb] = a_arr[(size_t)bh * S_LEN + (T0) + cb * 16 + lm]; \
} while (0)

#define QK_STEP(KS, PACC) do { \
  __builtin_amdgcn_s_setprio(1); \
  _Pragma("unroll") for (int kc = 0; kc < 4; kc++) \
    _Pragma("unroll") for (int cb = 0; cb < 4; cb++) { \
      short8 bk = *(const short8*)&KS[(cb * 16 + lm) * 128 + (((kc * 4 + lq) ^ (lm & 7)) * 8)]; \
      PACC[cb] = __builtin_amdgcn_mfma_f32_16x16x32_bf16(aq[kc], bk, PACC[cb], 0, 0, 0); \
    } \
  __builtin_amdgcn_s_setprio(0); \
} while (0)

// msk: block-uniform — causal cndmask only on tiles with T0 >= s0
#define W_PV(AE, VT, T0, PACC, MSK) do { \
  _Pragma("unroll") for (int cb = 0; cb < 4; cb++) { \
    float ec = AE[cb]; \
    _Pragma("unroll") for (int r = 0; r < 4; r++) { \
      float wv = PACC[cb][r] * ec * er[r]; \
      if (MSK) { \
        int colg = (T0) + cb * 16 + lm; \
        int rowg = s0 + wave * 16 + lq * 4 + r; \
        if (colg > rowg) wv = 0.f; \
      } \
      Ws[(wave * 16 + lq * 4 + r) * 72 + cb * 16 + lm] = f2bf(wv); \
    } \
  } \
  __builtin_amdgcn_s_setprio(1); \
  _Pragma("unroll") for (int kc = 0; kc < 2; kc++) { \
    short8 aw = *(const short8*)&Ws[(wave * 16 + lm) * 72 + kc * 32 + lq * 8]; \
    accS = __builtin_amdgcn_mfma_f32_16x16x32_bf16(aw, ones8, accS, 0, 0, 0); \
    _Pragma("unroll") for (int nb = 0; nb < 8; nb++) { \
      short8 bv = *(const short8*)&VT[(nb * 16 + lm) * 64 + (((kc * 4 + lq) ^ (lm & 7)) * 8)]; \
      accH[nb] = __builtin_amdgcn_mfma_f32_16x16x32_bf16(aw, bv, accH[nb], 0, 0, 0); \
    } \
  } \
  __builtin_amdgcn_s_setprio(0); \
} while (0)

  int kt = k0t;
  PREF(Ks0, Vt0, ae0, kt * 64);
  asm volatile("" ::: "memory");
  if (kt + 1 < k1t) PREF(Ks1, Vt1, ae1, (kt + 1) * 64);

  while (true) {
    {
      if (kt + 1 < k1t) asm volatile("s_waitcnt vmcnt(8)" ::: "memory");
      else              asm volatile("s_waitcnt vmcnt(0)" ::: "memory");
      __builtin_amdgcn_sched_barrier(0);
      __builtin_amdgcn_s_barrier();
      f32x4 pacc[4] = {};
      QK_STEP(Ks0, pacc);
      bool msk = (kt * 64 >= s0);
      W_PV(ae0, Vt0, kt * 64, pacc, msk);
      __builtin_amdgcn_s_barrier();
      if (kt + 2 < k1t) PREF(Ks0, Vt0, ae0, (kt + 2) * 64);
      kt++;
      if (kt >= k1t) break;
    }
    {
      if (kt + 1 < k1t) asm volatile("s_waitcnt vmcnt(8)" ::: "memory");
      else              asm volatile("s_waitcnt vmcnt(0)" ::: "memory");
      __builtin_amdgcn_sched_barrier(0);
      __builtin_amdgcn_s_barrier();
      f32x4 pacc[4] = {};
      QK_STEP(Ks1, pacc);
      bool msk = (kt * 64 >= s0);
      W_PV(ae1, Vt1, kt * 64, pacc, msk);
      __builtin_amdgcn_s_barrier();
      if (kt + 2 < k1t) PREF(Ks1, Vt1, ae1, (kt + 2) * 64);
      kt++;
      if (kt >= k1t) break;
    }
  }
#undef PREF
#undef QK_STEP
#undef W_PV

  if (mode != 0) {
    int slot = mode - 1;
    int qr = qp - 3;
    float* Hp = hpart + (size_t)slot * HP_SLOT + ((size_t)(bh * 5 + qr)) * 16384;
    float* sp = scpart + slot * SC_SLOT + (bh * 5 + qr) * 128;
#pragma unroll
    for (int r = 0; r < 4; r++) {
      int row = wave * 16 + lq * 4 + r;
      if (lm == 0) sp[row] = accS[r];
#pragma unroll
      for (int nb = 0; nb < 8; nb++)
        Hp[row * 128 + nb * 16 + lm] = accH[nb][r];
    }
    return;
  }

  float inv[4], muv[4], rsv[4];
#pragma unroll
  for (int r = 0; r < 4; r++) {
    int rowg = s0 + wave * 16 + lq * 4 + r;
    float nrm = fmaxf(fabsf(accS[r]), enm_arr[(size_t)bh * S_LEN + rowg]);
    inv[r] = 1.f / (nrm + 1e-6f);
  }
#pragma unroll
  for (int r = 0; r < 4; r++) {
    float s = 0.f, qq = 0.f;
#pragma unroll
    for (int nb = 0; nb < 8; nb++) {
      float hv = accH[nb][r] * inv[r];
      accH[nb][r] = hv;
      s += hv; qq += hv * hv;
    }
    s += __shfl_xor(s, 1); s += __shfl_xor(s, 2); s += __shfl_xor(s, 4); s += __shfl_xor(s, 8);
    qq += __shfl_xor(qq, 1); qq += __shfl_xor(qq, 2); qq += __shfl_xor(qq, 4); qq += __shfl_xor(qq, 8);
    float mu = s * (1.f / DHEAD);
    float var = qq * (1.f / DHEAD) - mu * mu;
    muv[r] = mu;
    rsv[r] = rsqrtf(var + 1e-5f);
  }
  float ow[8], sk[8];
#pragma unroll
  for (int nb = 0; nb < 8; nb++) {
    ow[nb] = onw[c0 + nb * 16 + lm];
    sk[nb] = skip[c0 + nb * 16 + lm];
  }
#pragma unroll
  for (int r = 0; r < 4; r++) {
    int rowg = s0 + wave * 16 + lq * 4 + r;
    size_t base = (rowbase + rowg) * INNER_D + c0;
#pragma unroll
    for (int nb = 0; nb < 8; nb++) {
      int d = nb * 16 + lm;
      float xcv = xc[base + d];
      float zv = bf2f(zh[base + d]);
      float hn = (accH[nb][r] - muv[r]) * rsv[r] * ow[nb] + sk[nb] * xcv;
      float o = hn * (zv / (1.f + __expf(-zv)));
      hs[base + d] = f2bf(o);
    }
  }
}

// combine 2..3 partial slots for rows s >= 384; one wave per row (10240 rows).
__global__ __launch_bounds__(256) void attn_combine_kernel(
    const float* __restrict__ hpart, const float* __restrict__ scpart,
    const float* __restrict__ enm,
    const float* __restrict__ xc, const u16* __restrict__ zh,
    const float* __restrict__ skip, const float* __restrict__ onw,
    u16* __restrict__ hs)
{
  int wave = threadIdx.x >> 6, lane = threadIdx.x & 63;
  int gid = blockIdx.x * 4 + wave;   // 0..10239
  int bh = gid / 640;
  int rr = gid % 640;
  int qr = rr >> 7, row = rr & 127;
  int b = bh >> 3, hh = bh & 7;
  int s = (qr + 3) * 128 + row;
  int nsl = (qr >= 3) ? 3 : 2;       // qp3-5: 2 slots, qp6-7: 3 slots
  size_t off = (((size_t)(bh * 5 + qr)) * 128 + row) * 128 + lane * 2;
  int sidx = (bh * 5 + qr) * 128 + row;
  float hx = 0.f, hy = 0.f, sc = 0.f;
  for (int sl = 0; sl < nsl; sl++) {
    float2 hp = *(const float2*)(hpart + (size_t)sl * HP_SLOT + off);
    hx += hp.x; hy += hp.y;
    sc += scpart[sl * SC_SLOT + sidx];
  }
  float nrm = fmaxf(fabsf(sc), enm[(size_t)bh * S_LEN + s]);
  float inv = 1.f / (nrm + 1e-6f);
  hx *= inv; hy *= inv;
  float sm = hx + hy, sq = hx * hx + hy * hy;
#pragma unroll
  for (int off2 = 32; off2; off2 >>= 1) { sm += __shfl_xor(sm, off2); sq += __shfl_xor(sq, off2); }
  float mu = sm * (1.f / DHEAD);
  float var = sq * (1.f / DHEAD) - mu * mu;
  float rs = rsqrtf(var + 1e-5f);
  int c0 = hh * DHEAD + lane * 2;
  size_t base = ((size_t)(b * S_LEN + s)) * INNER_D + c0;
  float2 xc2 = *(const float2*)(xc + base);
  ushort2 z2u = *(const ushort2*)(zh + base);
  float z2x = bf2f(z2u.x), z2y = bf2f(z2u.y);
  float skx = skip[c0], sky = skip[c0 + 1];
  float owx = onw[c0],  owy = onw[c0 + 1];
  ushort2 o;
  o.x = f2bf(((hx - mu) * rs * owx + skx * xc2.x) * (z2x / (1.f + __expf(-z2x))));
  o.y = f2bf(((hy - mu) * rs * owy + sky * xc2.y) * (z2y / (1.f + __expf(-z2y))));
  *(ushort2*)(hs + base) = o;
}

extern "C" void kernel_launch(void* const* d_in, const int* in_sizes, int n_in,
                              void* d_out, int out_size, void* d_ws, size_t ws_size,
                              hipStream_t stream)
{
  const float* x_enc   = (const float*)d_in[0];
  const float* x_mark  = (const float*)d_in[1];
  const float* emb_W   = (const float*)d_in[4];
  const float* emb_b   = (const float*)d_in[5];
  const float* ln_w    = (const float*)d_in[6];
  const float* up_W    = (const float*)d_in[7];
  const float* conv_W  = (const float*)d_in[8];
  const float* conv_b  = (const float*)d_in[9];
  const float* q_W     = (const float*)d_in[10];
  const float* k_W     = (const float*)d_in[11];
  const float* v_W     = (const float*)d_in[12];
  const float* ig_W    = (const float*)d_in[13];
  const float* ig_b    = (const float*)d_in[14];
  const float* fg_W    = (const float*)d_in[15];
  const float* fg_b    = (const float*)d_in[16];
  const float* skip_w  = (const float*)d_in[17];
  const float* onorm_w = (const float*)d_in[18];
  const float* down_W  = (const float*)d_in[19];
  const float* post_ln = (const float*)d_in[20];
  const float* head_W  = (const float*)d_in[21];
  const float* head_b  = (const float*)d_in[22];

  float* p = (float*)d_ws;
  float* x    = p; p += 1048576;   // 2048*512 f32
  float* xm   = p; p += 2097152;   // 2048*1024 f32; reused as hsbh bf16 after convqkv
  float* xc   = p; p += 2097152;
  float* igb_ = p; p += 32768;     // 2 K-halves x 16384
  float* fgb_ = p; p += 32768;
  float* ab   = p; p += 16384;     // holds exp(a)
  float* rmb  = p; p += 16384;
  float* enmb = p; p += 16384;
  u16* qhb = (u16*)p; p += 1048576;  // 2048*1024 u16
  u16* khb = (u16*)p; p += 1048576;
  u16* vhb = (u16*)p; p += 1048576;
  u16* zh  = (u16*)p; p += 1048576;  // 2048*1024 u16 (full size)
  u16* xnh = (u16*)p; p += 524288;   // 2048*512 u16
  u16* upWtA = (u16*)p; p += 2097152; // 4 x 2048x512 u16
  u16* dnWtA = (u16*)p; p += 1048576; // 4 x 512x1024 u16
  u16* gtwH = (u16*)p; p += 98304;    // 4 x 16 x 3072 u16
  u16* gtwL = (u16*)p; p += 98304;
  float* hpart = p; p += 3932160;     // 3 slots x 16 bh x 5 qr x 128 x 128 f32
  float* scpart = p; p += 32768;      // 3 slots x 10240 (padded)
  u16* vtg = (u16*)p; p += 1048576;   // 2 x 1024 x 1024 u16 (V^T per layer)
  u16* hsbh = (u16*)xm;

  // one merged prep launch: up/down weight transposes + gates weights + embedding
  prep_kernel<<<4352, 256, 0, stream>>>(
      up_W, upWtA, down_W, dnWtA, ig_W, fg_W, gtwH, gtwL,
      x_enc, x_mark, emb_W, emb_b, x);

  for (int L = 0; L < 4; L++) {
    ln_kernel<<<2048, 256, 0, stream>>>(x, ln_w + L * 512, xnh);
    gemm_bf16_split64<<<dim3(16, 16), 256, 0, stream>>>(
        xnh, upWtA + (size_t)L * 1048576, xm, zh, 2048, 2048, 512, 1024, 1024);
    convqkv_kernel<<<256, 256, 0, stream>>>(
        xm, conv_W + L * 4096, conv_b + L * 1024,
        q_W + L * 4096, k_W + L * 4096, v_W + L * 4096,
        xc, qhb, khb, vhb, vtg);
    gates_mfma_kernel<<<256, 256, 0, stream>>>(
        qhb, khb, vhb, gtwH + (size_t)L * 49152, gtwL + (size_t)L * 49152,
        ig_b + L * 8, fg_b + L * 8, igb_, fgb_);
    scan_kernel<<<16, 1024, 0, stream>>>(igb_, fgb_, ab, rmb, enmb);
    attn_mfma_kernel<<<dim3(16, 15), 512, 0, stream>>>(
        qhb, khb, vtg, ab, rmb, enmb, xc, zh,
        skip_w + L * 1024, onorm_w + L * 1024, hsbh, hpart, scpart);
    attn_combine_kernel<<<2560, 256, 0, stream>>>(
        hpart, scpart, enmb, xc, zh, skip_w + L * 1024, onorm_w + L * 1024, hsbh);
    gemm_bf16_32<<<dim3(8, 32), 256, 0, stream>>>(
        hsbh, dnWtA + (size_t)L * 524288, x, 2048, 512, 1024, 512);
  }

  lnhead_kernel<<<192, 256, 0, stream>>>(x, post_ln, head_W, head_b, (float*)d_out);
}

// Round 13
// 414.979 us; speedup vs baseline: 1.1097x; 1.0012x over previous
//
#include <hip/hip_runtime.h>
#include <hip/hip_bf16.h>

#define S_LEN 1024
#define E_DIM 512
#define INNER_D 1024
#define NHEAD 8
#define DHEAD 128

typedef unsigned short u16;
typedef unsigned int u32;
typedef __attribute__((ext_vector_type(8))) short short8;
typedef __attribute__((ext_vector_type(4))) float f32x4;

union S8 { short8 v; u16 u[8]; uint4 q; };

__device__ __forceinline__ u16 f2bf(float f) {
  u32 u = __float_as_uint(f);
  u32 r = u + 0x7FFFu + ((u >> 16) & 1u);
  return (u16)(r >> 16);
}
__device__ __forceinline__ float bf2f(u16 u) { return __uint_as_float(((u32)u) << 16); }

// direct global -> LDS (16B per lane). LDS dest = wave-uniform base + lane*16B (linear).
__device__ __forceinline__ void gload16(const u16* g, u16* l) {
  __builtin_amdgcn_global_load_lds((const __attribute__((address_space(1))) void*)g,
                                   (__attribute__((address_space(3))) void*)l, 16, 0, 0);
}

// ---------------- merged one-time prep: transposes + gates weights + embedding ----------------
__device__ __forceinline__ void prep_transpose(
    const float* __restrict__ in, u16* __restrict__ out, int K, int N,
    int k0, int n0, int t, u16 (*T)[72])
{
  int kr = t >> 2, nseg = (t & 3) * 16;
  const float* src = in + (size_t)(k0 + kr) * N + n0 + nseg;
#pragma unroll
  for (int j = 0; j < 16; j++) T[kr][nseg + j] = f2bf(src[j]);
  __syncthreads();
  int nr = t >> 2, kseg = (t & 3) * 16;
  u32 u[8];
#pragma unroll
  for (int rr = 0; rr < 8; rr++) {
    u32 lo = T[kseg + 2 * rr][nr];
    u32 hi = T[kseg + 2 * rr + 1][nr];
    u[rr] = lo | (hi << 16);
  }
  u16* dst = out + (size_t)(n0 + nr) * K + k0 + kseg;
  uint4 w0 = {u[0], u[1], u[2], u[3]};
  uint4 w1 = {u[4], u[5], u[6], u[7]};
  *(uint4*)dst = w0;
  *(uint4*)(dst + 8) = w1;
}

__global__ __launch_bounds__(256) void prep_kernel(
    const float* __restrict__ up_W, u16* __restrict__ upWt,
    const float* __restrict__ down_W, u16* __restrict__ dnWt,
    const float* __restrict__ igW, const float* __restrict__ fgW,
    u16* __restrict__ ghi, u16* __restrict__ glo,
    const float* __restrict__ xe, const float* __restrict__ xmk,
    const float* __restrict__ eW, const float* __restrict__ eb,
    float* __restrict__ x)
{
  __shared__ u16 T[64][72];
  __shared__ float in_s[25];
  int id = blockIdx.x;
  int t = threadIdx.x;
  if (id < 1024) {                     // up_W transpose: [L][512][2048] -> [L][2048][512]
    int bx = id & 7, rest = id >> 3;
    int by = rest & 31, L = rest >> 5;
    prep_transpose(up_W + (size_t)L * 512 * 2048, upWt + (size_t)L * 1048576,
                   512, 2048, bx * 64, by * 64, t, T);
  } else if (id < 1536) {              // down_W transpose: [L][1024][512] -> [L][512][1024]
    int id2 = id - 1024;
    int bx = id2 & 15, rest = id2 >> 4;
    int by = rest & 7, L = rest >> 3;
    prep_transpose(down_W + (size_t)L * 1024 * 512, dnWt + (size_t)L * 524288,
                   1024, 512, bx * 64, by * 64, t, T);
  } else if (id < 2304) {              // gates weights: hi/lo split transpose
    int id3 = id - 1536;
    int bx = id3 % 12, rest = id3 / 12;
    int n = rest & 15, L = rest >> 4;
    int k = bx * 256 + t;
    const float* W = ((n < 8) ? igW : fgW) + (size_t)L * 24576;
    float v = W[(size_t)k * 8 + (n & 7)];
    u16 h = f2bf(v);
    u16 l = f2bf(v - bf2f(h));
    size_t o = ((size_t)L * 16 + n) * 3072 + k;
    ghi[o] = h;
    glo[o] = l;
  } else {                             // embedding, one row per block
    int row = id - 2304;
    if (t < 21) in_s[t] = xe[row * 21 + t];
    else if (t < 25) in_s[t] = xmk[row * 4 + t - 21];
    __syncthreads();
#pragma unroll
    for (int rep = 0; rep < 2; rep++) {
      int e = t + rep * 256;
      float acc = eb[e];
#pragma unroll
      for (int i = 0; i < 25; i++) acc += in_s[i] * eW[i * E_DIM + e];
      x[(size_t)row * E_DIM + e] = acc;
    }
  }
}

// ---------------- layernorm -> bf16; one wave per row, 4 rows/block ----------------
__global__ __launch_bounds__(256) void ln_kernel(
    const float* __restrict__ x, const float* __restrict__ w, u16* __restrict__ out)
{
  int row = blockIdx.x * 4 + (threadIdx.x >> 6);
  int lane = threadIdx.x & 63;
  const float* xr = x + (size_t)row * E_DIM + lane * 8;
  float4 a = *(const float4*)xr;
  float4 b = *(const float4*)(xr + 4);
  float s = a.x + a.y + a.z + a.w + b.x + b.y + b.z + b.w;
  float q = a.x * a.x + a.y * a.y + a.z * a.z + a.w * a.w
          + b.x * b.x + b.y * b.y + b.z * b.z + b.w * b.w;
#pragma unroll
  for (int off = 1; off < 64; off <<= 1) { s += __shfl_xor(s, off); q += __shfl_xor(q, off); }
  float mu = s * (1.f / E_DIM);
  float var = q * (1.f / E_DIM) - mu * mu;
  float rs = rsqrtf(var + 1e-5f);
  const float* wr = w + lane * 8;
  S8 o;
  o.u[0] = f2bf((a.x - mu) * rs * wr[0]);
  o.u[1] = f2bf((a.y - mu) * rs * wr[1]);
  o.u[2] = f2bf((a.z - mu) * rs * wr[2]);
  o.u[3] = f2bf((a.w - mu) * rs * wr[3]);
  o.u[4] = f2bf((b.x - mu) * rs * wr[4]);
  o.u[5] = f2bf((b.y - mu) * rs * wr[5]);
  o.u[6] = f2bf((b.z - mu) * rs * wr[6]);
  o.u[7] = f2bf((b.w - mu) * rs * wr[7]);
  *(uint4*)(out + (size_t)row * E_DIM + lane * 8) = o.q;
}

// ---------------- fused final layernorm + head (one block per output row) ----------------
__global__ __launch_bounds__(256) void lnhead_kernel(
    const float* __restrict__ x, const float* __restrict__ w,
    const float* __restrict__ hW, const float* __restrict__ hb,
    float* __restrict__ out)
{
  int ridx = blockIdx.x;
  int b = ridx / 96, r = ridx % 96;
  int row = b * S_LEN + (S_LEN - 96) + r;
  int tid = threadIdx.x;
  const float* xr = x + (size_t)row * E_DIM;
  float2 v = *(const float2*)(xr + tid * 2);
  float s = v.x + v.y, q = v.x * v.x + v.y * v.y;
#pragma unroll
  for (int off = 32; off; off >>= 1) { s += __shfl_xor(s, off); q += __shfl_xor(q, off); }
  __shared__ float ssum[4], ssq[4];
  __shared__ float lnv[512];
  __shared__ float part[8][32];
  int wv = tid >> 6;
  if ((tid & 63) == 0) { ssum[wv] = s; ssq[wv] = q; }
  __syncthreads();
  s = ssum[0] + ssum[1] + ssum[2] + ssum[3];
  q = ssq[0] + ssq[1] + ssq[2] + ssq[3];
  float mu = s * (1.f / E_DIM);
  float var = q * (1.f / E_DIM) - mu * mu;
  float rs = rsqrtf(var + 1e-5f);
  int e = tid * 2;
  lnv[e]     = (v.x - mu) * rs * w[e];
  lnv[e + 1] = (v.y - mu) * rs * w[e + 1];
  __syncthreads();
  int n = tid & 31, sl = tid >> 5;
  float p = 0.f;
  if (n < 21) {
#pragma unroll 8
    for (int kk = 0; kk < 64; kk++)
      p += lnv[sl * 64 + kk] * hW[(sl * 64 + kk) * 21 + n];
  }
  part[sl][n] = p;
  __syncthreads();
  if (tid < 21) {
    float acc = hb[tid];
#pragma unroll
    for (int j = 0; j < 8; j++) acc += part[j][tid];
    out[ridx * 21 + tid] = acc;
  }
}

// ---------------- bf16 MFMA GEMM 128x128, BK=64, 3-deep counted-vmcnt pipeline --------------
// split C: C0 f32, C1 bf16; grid (N/128, M/128). K must be 512 (NT=8).
__global__ __launch_bounds__(256) void gemm_bf16_split64(
    const u16* __restrict__ A, const u16* __restrict__ Bt,
    float* __restrict__ C0, u16* __restrict__ C1,
    int M, int N, int K, int split_col, int ldc)
{
  __shared__ u16 As0[128 * 64], As1[128 * 64], As2[128 * 64];
  __shared__ u16 Bs0[128 * 64], Bs1[128 * 64], Bs2[128 * 64];
  const int tid = threadIdx.x;
  const int row0 = blockIdx.y * 128, col0 = blockIdx.x * 128;
  const int wave = tid >> 6, lane = tid & 63;
  const int wr = wave >> 1, wc = wave & 1;   // wave tile: 64 rows x 64 cols
  const int lm = lane & 15, lq = lane >> 4;
  const int lr8 = lane >> 3;                 // 0..7 row within 8-row group
  const int cg8 = (lane & 7) ^ lr8;          // pre-swizzled source 16B slot (8 slots/row)
  f32x4 acc[4][4] = {};
  const u16* Abase = A + (size_t)(row0 + lr8) * K + cg8 * 8;
  const u16* Bbase = Bt + (size_t)(col0 + lr8) * K + cg8 * 8;
  const int key = lm & 7;

#define STG_UP(AS, BS, K0) do { \
  _Pragma("unroll") for (int i = 0; i < 4; i++) \
    gload16(Abase + (size_t)((wave * 4 + i) * 8) * K + (K0), &AS[(wave * 4 + i) * 512]); \
  _Pragma("unroll") for (int i = 0; i < 4; i++) \
    gload16(Bbase + (size_t)((wave * 4 + i) * 8) * K + (K0), &BS[(wave * 4 + i) * 512]); \
} while (0)

#define CMP_UP(AS, BS) do { \
  _Pragma("unroll") for (int kc = 0; kc < 2; kc++) { \
    short8 af[4], bfv[4]; \
    _Pragma("unroll") for (int i = 0; i < 4; i++) \
      af[i] = *(const short8*)&AS[(wr * 64 + i * 16 + lm) * 64 + (((kc * 4 + lq) ^ key) * 8)]; \
    _Pragma("unroll") for (int j = 0; j < 4; j++) \
      bfv[j] = *(const short8*)&BS[(wc * 64 + j * 16 + lm) * 64 + (((kc * 4 + lq) ^ key) * 8)]; \
    _Pragma("unroll") for (int i = 0; i < 4; i++) \
      _Pragma("unroll") for (int j = 0; j < 4; j++) \
        acc[i][j] = __builtin_amdgcn_mfma_f32_16x16x32_bf16(af[i], bfv[j], acc[i][j], 0, 0, 0); \
  } \
} while (0)

  STG_UP(As0, Bs0, 0);
  asm volatile("" ::: "memory");
  STG_UP(As1, Bs1, 64);
  asm volatile("" ::: "memory");
  STG_UP(As2, Bs2, 128);
  // 24 DMA ops/wave in flight (8 per tile, 3 tiles)
#pragma unroll
  for (int t = 0; t < 8; t++) {
    if (t <= 5)       asm volatile("s_waitcnt vmcnt(16)" ::: "memory");
    else if (t == 6)  asm volatile("s_waitcnt vmcnt(8)" ::: "memory");
    else              asm volatile("s_waitcnt vmcnt(0)" ::: "memory");
    __builtin_amdgcn_sched_barrier(0);
    __builtin_amdgcn_s_barrier();
    if ((t % 3) == 0)      CMP_UP(As0, Bs0);
    else if ((t % 3) == 1) CMP_UP(As1, Bs1);
    else                   CMP_UP(As2, Bs2);
    __builtin_amdgcn_s_barrier();
    if (t + 3 < 8) {
      if ((t % 3) == 0)      STG_UP(As0, Bs0, (t + 3) * 64);
      else if ((t % 3) == 1) STG_UP(As1, Bs1, (t + 3) * 64);
      else                   STG_UP(As2, Bs2, (t + 3) * 64);
    }
  }
#undef STG_UP
#undef CMP_UP

  const bool toC1 = (col0 >= split_col);
#pragma unroll
  for (int i = 0; i < 4; i++) {
#pragma unroll
    for (int j = 0; j < 4; j++) {
      int col = col0 - (toC1 ? split_col : 0) + wc * 64 + j * 16 + lm;
#pragma unroll
      for (int r = 0; r < 4; r++) {
        int row = row0 + wr * 64 + i * 16 + lq * 4 + r;
        if (toC1) C1[(size_t)row * ldc + col] = f2bf(acc[i][j][r]);
        else C0[(size_t)row * ldc + col] = acc[i][j][r];
      }
    }
  }
}

// ---------------- bf16 MFMA GEMM 64x64 (down-proj, +=), BK=128, 3-deep pipeline -------------
// K must be 1024 (NT=8).
__global__ __launch_bounds__(256) void gemm_bf16_32(
    const u16* __restrict__ A, const u16* __restrict__ Bt,
    float* __restrict__ C, int M, int N, int K, int ldc)
{
  __shared__ u16 As0[64 * 128], As1[64 * 128], As2[64 * 128];
  __shared__ u16 Bs0[64 * 128], Bs1[64 * 128], Bs2[64 * 128];
  const int tid = threadIdx.x;
  const int row0 = blockIdx.y * 64, col0 = blockIdx.x * 64;
  const int wave = tid >> 6, lane = tid & 63;
  const int wr = wave >> 1, wc = wave & 1;   // wave tile: 32 rows x 32 cols
  const int lm = lane & 15, lq = lane >> 4;
  const int lr16 = lane >> 4;                // 0..3 row within 4-row group (256B rows)
  const int ls16 = lane & 15;                // 16B slot within row (16 slots)
  f32x4 acc[2][2] = {};

#define STAGE_DN(AS, BS, K0) do { \
  _Pragma("unroll") for (int i = 0; i < 4; i++) { \
    int rA = (wave * 4 + i) * 4 + lr16; \
    int cgk = ls16 ^ (rA & 15); \
    gload16(A + (size_t)(row0 + rA) * K + (K0) + cgk * 8, &AS[(wave * 4 + i) * 512]); \
  } \
  _Pragma("unroll") for (int i = 0; i < 4; i++) { \
    int rB = (wave * 4 + i) * 4 + lr16; \
    int cgk = ls16 ^ (rB & 15); \
    gload16(Bt + (size_t)(col0 + rB) * K + (K0) + cgk * 8, &BS[(wave * 4 + i) * 512]); \
  } \
} while (0)

#define COMPUTE_DN(AS, BS) do { \
  _Pragma("unroll") for (int kc = 0; kc < 4; kc++) { \
    short8 af[2], bfv[2]; \
    _Pragma("unroll") for (int i = 0; i < 2; i++) \
      af[i] = *(const short8*)&AS[(wr * 32 + i * 16 + lm) * 128 + (((kc * 4 + lq) ^ lm) * 8)]; \
    _Pragma("unroll") for (int j = 0; j < 2; j++) \
      bfv[j] = *(const short8*)&BS[(wc * 32 + j * 16 + lm) * 128 + (((kc * 4 + lq) ^ lm) * 8)]; \
    _Pragma("unroll") for (int i = 0; i < 2; i++) \
      _Pragma("unroll") for (int j = 0; j < 2; j++) \
        acc[i][j] = __builtin_amdgcn_mfma_f32_16x16x32_bf16(af[i], bfv[j], acc[i][j], 0, 0, 0); \
  } \
} while (0)

  STAGE_DN(As0, Bs0, 0);
  asm volatile("" ::: "memory");
  STAGE_DN(As1, Bs1, 128);
  asm volatile("" ::: "memory");
  STAGE_DN(As2, Bs2, 256);
  // 24 DMA ops/wave in flight (8 per tile, 3 tiles)
#pragma unroll
  for (int t = 0; t < 8; t++) {
    if (t <= 5)       asm volatile("s_waitcnt vmcnt(16)" ::: "memory");
    else if (t == 6)  asm volatile("s_waitcnt vmcnt(8)" ::: "memory");
    else              asm volatile("s_waitcnt vmcnt(0)" ::: "memory");
    __builtin_amdgcn_sched_barrier(0);
    __builtin_amdgcn_s_barrier();
    if ((t % 3) == 0)      COMPUTE_DN(As0, Bs0);
    else if ((t % 3) == 1) COMPUTE_DN(As1, Bs1);
    else                   COMPUTE_DN(As2, Bs2);
    __builtin_amdgcn_s_barrier();
    if (t + 3 < 8) {
      if ((t % 3) == 0)      STAGE_DN(As0, Bs0, (t + 3) * 128);
      else if ((t % 3) == 1) STAGE_DN(As1, Bs1, (t + 3) * 128);
      else                   STAGE_DN(As2, Bs2, (t + 3) * 128);
    }
  }
#undef STAGE_DN
#undef COMPUTE_DN

#pragma unroll
  for (int i = 0; i < 2; i++) {
#pragma unroll
    for (int j = 0; j < 2; j++) {
      int col = col0 + wc * 32 + j * 16 + lm;
#pragma unroll
      for (int r = 0; r < 4; r++) {
        int row = row0 + wr * 32 + i * 16 + lq * 4 + r;
        C[(size_t)row * ldc + col] += acc[i][j][r];
      }
    }
  }
}

// ---------------- fused causal conv+SiLU+headwise qkv; 8 rows/block; writes V and V^T -------
__global__ __launch_bounds__(256) void convqkv_kernel(
    const float* __restrict__ xm,
    const float* __restrict__ cw, const float* __restrict__ cb,
    const float* __restrict__ qw, const float* __restrict__ kw, const float* __restrict__ vw,
    float* __restrict__ xc, u16* __restrict__ q, u16* __restrict__ k, u16* __restrict__ v,
    u16* __restrict__ vt)
{
  int r0 = blockIdx.x * 8;         // rows r0..r0+7, same batch (S_LEN % 8 == 0)
  int s0 = r0 & (S_LEN - 1);
  int g = threadIdx.x;             // channel group of 4
  int c0 = g * 4;
  const float* base = xm + (size_t)r0 * INNER_D + c0;

  float4 xv[11];
#pragma unroll
  for (int j = 0; j < 11; j++) {
    int ts = s0 - 3 + j;
    float4 t = {0.f, 0.f, 0.f, 0.f};
    if (ts >= 0) t = *(const float4*)(base + (ptrdiff_t)(j - 3) * INNER_D);
    xv[j] = t;
  }
  float cwv[4][4];
#pragma unroll
  for (int c = 0; c < 4; c++)
#pragma unroll
    for (int kk = 0; kk < 4; kk++) cwv[c][kk] = cw[(c0 + c) * 4 + kk];
  float cbv[4] = {cb[c0], cb[c0 + 1], cb[c0 + 2], cb[c0 + 3]};
  const float* qg = qw + g * 16;
  const float* kg = kw + g * 16;
  const float* vg = vw + g * 16;
  float qwv[16], kwv[16], vwv[16];
#pragma unroll
  for (int i = 0; i < 16; i++) { qwv[i] = qg[i]; kwv[i] = kg[i]; vwv[i] = vg[i]; }

  u32 vt_pack[4][4];   // [channel][s-pair] fully static indexing

#pragma unroll
  for (int i = 0; i < 8; i++) {
    float a0 = cbv[0], a1 = cbv[1], a2 = cbv[2], a3 = cbv[3];
#pragma unroll
    for (int kk = 0; kk < 4; kk++) {
      float4 xvv = xv[i + kk];
      a0 += xvv.x * cwv[0][kk];
      a1 += xvv.y * cwv[1][kk];
      a2 += xvv.z * cwv[2][kk];
      a3 += xvv.w * cwv[3][kk];
    }
    a0 = a0 / (1.f + __expf(-a0));
    a1 = a1 / (1.f + __expf(-a1));
    a2 = a2 / (1.f + __expf(-a2));
    a3 = a3 / (1.f + __expf(-a3));
    float4 accv = {a0, a1, a2, a3};
    *(float4*)(xc + (size_t)(r0 + i) * INNER_D + c0) = accv;

    float xcv[4] = {a0, a1, a2, a3};
    float xmv[4] = {xv[i + 3].x, xv[i + 3].y, xv[i + 3].z, xv[i + 3].w};
    ushort4 qs, ks, vs;
    u16* qp = (u16*)&qs; u16* kp = (u16*)&ks; u16* vp = (u16*)&vs;
#pragma unroll
    for (int o = 0; o < 4; o++) {
      float aq = 0.f, ak = 0.f, av = 0.f;
#pragma unroll
      for (int d = 0; d < 4; d++) {
        aq += xcv[d] * qwv[o * 4 + d];
        ak += xcv[d] * kwv[o * 4 + d];
        av += xmv[d] * vwv[o * 4 + d];
      }
      qp[o] = f2bf(aq); kp[o] = f2bf(ak);
      u16 vv = f2bf(av);
      vp[o] = vv;
      if ((i & 1) == 0) vt_pack[o][i >> 1] = (u32)vv;
      else              vt_pack[o][i >> 1] |= ((u32)vv) << 16;
    }
    size_t off = (size_t)(r0 + i) * INNER_D + c0;
    *(ushort4*)(q + off) = qs;
    *(ushort4*)(k + off) = ks;
    *(ushort4*)(v + off) = vs;
  }
  // V^T: vt[b][d][s], 16B (8 s-values) per channel
  u16* vtb = vt + ((size_t)((r0 >> 10) * INNER_D + c0)) * S_LEN + s0;
#pragma unroll
  for (int c = 0; c < 4; c++) {
    uint4 wv4 = {vt_pack[c][0], vt_pack[c][1], vt_pack[c][2], vt_pack[c][3]};
    *(uint4*)(vtb + (size_t)c * S_LEN) = wv4;
  }
}

// ---------------- gates as skinny MFMA GEMM, K-split x2: 256 blocks ----------------
// block 2i+h: rows [16i,16i+16), K half h (1536 each); outputs to half-offset buffers.
__global__ __launch_bounds__(256) void gates_mfma_kernel(
    const u16* __restrict__ q, const u16* __restrict__ k, const u16* __restrict__ v,
    const u16* __restrict__ whi, const u16* __restrict__ wlo,
    const float* __restrict__ igb, const float* __restrict__ fgb,
    float* __restrict__ ig, float* __restrict__ fg)
{
  const int blk2 = blockIdx.x;     // 0..255
  const int blk = blk2 >> 1, half = blk2 & 1;
  const int tid = threadIdx.x;
  const int wave = tid >> 6, lane = tid & 63;
  const int lm = lane & 15, lq = lane >> 4;
  const int grow = blk * 16 + lm;
  const u16* parts[3] = {q, k, v};
  f32x4 acc = {};
#pragma unroll 4
  for (int kc = 0; kc < 12; kc++) {
    int k0 = half * 1536 + wave * 384 + kc * 32;
    int part = k0 >> 10;
    int idx = (k0 & 1023) + lq * 8;
    S8 a, bh_, bl_;
    a.q = *(const uint4*)(parts[part] + (size_t)grow * INNER_D + idx);
    bh_.q = *(const uint4*)(whi + (size_t)lm * 3072 + k0 + lq * 8);
    bl_.q = *(const uint4*)(wlo + (size_t)lm * 3072 + k0 + lq * 8);
    __builtin_amdgcn_s_setprio(1);
    acc = __builtin_amdgcn_mfma_f32_16x16x32_bf16(a.v, bh_.v, acc, 0, 0, 0);
    acc = __builtin_amdgcn_mfma_f32_16x16x32_bf16(a.v, bl_.v, acc, 0, 0, 0);
    __builtin_amdgcn_s_setprio(0);
  }
  __shared__ float red[4][16][17];
#pragma unroll
  for (int r = 0; r < 4; r++) red[wave][lq * 4 + r][lm] = acc[r];
  __syncthreads();
  if (wave == 0) {
#pragma unroll
    for (int r = 0; r < 4; r++) {
      int row = lq * 4 + r;
      float sum = red[0][row][lm] + red[1][row][lm] + red[2][row][lm] + red[3][row][lm];
      int growr = blk * 16 + row;
      int b = growr >> 10, s = growr & (S_LEN - 1);
      if (lm < 8) {
        float bias = (half == 0) ? igb[lm] : 0.f;
        ig[half * 16384 + ((size_t)(b * NHEAD + lm) << 10) + s] = sum + bias;
      } else {
        float bias = (half == 0) ? fgb[lm - 8] : 0.f;
        fg[half * 16384 + ((size_t)(b * NHEAD + (lm - 8)) << 10) + s] = sum + bias;
      }
    }
  }
}

// ---------------- 128-q-row (8-wave) split-K MFMA attention + fused scan, 15 jobs/bh --------
// qp = q-tile-pair index (128 rows); k range in 64-t tiles.
__device__ __constant__ int c_qp[15] = {7, 7, 7, 6, 6, 6, 5, 5, 4, 4, 3, 3, 2, 1, 0};
__device__ __constant__ int c_k0[15] = {0, 6,11, 0, 5,10, 0, 6, 0, 5, 0, 4, 0, 0, 0};
__device__ __constant__ int c_k1[15] = {6,11,16, 5,10,14, 6,12, 5,10, 4, 8, 6, 4, 2};
__device__ __constant__ int c_md[15] = {1, 2, 3, 1, 2, 3, 1, 2, 1, 2, 1, 2, 0, 0, 0};

#define HP_SLOT 1310720   // 16 bh * 5 qr * 128 rows * 128
#define SC_SLOT 10240     // 16 bh * 5 qr * 128 rows

__global__ __launch_bounds__(512) void attn_mfma_kernel(
    const u16* __restrict__ qhg, const u16* __restrict__ khg, const u16* __restrict__ vtg,
    const float* __restrict__ ig_arr, const float* __restrict__ fg_arr,
    const float* __restrict__ xc, const u16* __restrict__ zh,
    const float* __restrict__ skip, const float* __restrict__ onw,
    u16* __restrict__ hs, float* __restrict__ hpart, float* __restrict__ scpart,
    float* __restrict__ enmp)
{
  const int bh = blockIdx.x;
  const int job = blockIdx.y;
  const int qp = c_qp[job], k0t = c_k0[job], k1t = c_k1[job], mode = c_md[job];
  const int b = bh >> 3, h = bh & 7;
  const int s0 = qp * 128;
  const int tid = threadIdx.x;
  const int wave = tid >> 6, lane = tid & 63;
  const int lm = lane & 15, lq = lane >> 4;
  const size_t rowbase = (size_t)b * S_LEN;
  const int c0 = h * DHEAD;

  __shared__ u16 Ks0[64 * 128], Ks1[64 * 128];  // [t][128], 16B slots XOR-swizzled by (t&7)
  __shared__ u16 Vt0[128 * 64], Vt1[128 * 64];  // [d][64],  16B slots XOR-swizzled by (d&7)
  __shared__ u16 Ws[128 * 72];
  __shared__ float sa[1024];                    // exp(a)
  __shared__ float sws[16], swm[16];
  __shared__ float srm[128], senm[128];

  // Q fragment loads first (drained by scan's compiler waits before PREFs are issued)
  short8 aq[4];
  {
    const u16* qpp = qhg + (rowbase + s0 + wave * 16 + lm) * INNER_D + c0 + lq * 8;
#pragma unroll
    for (int kc = 0; kc < 4; kc++) {
      S8 tmp; tmp.q = *(const uint4*)(qpp + kc * 32);
      aq[kc] = tmp.v;
    }
  }

  // ---- fused per-bh scan (bitwise port of scan_kernel; 16 virtual waves over 512 threads) ----
  {
    float vsc[2], igv[2], css[2], msc[2];
#pragma unroll
    for (int c = 0; c < 2; c++) {
      int vt = c * 512 + tid;
      size_t o = ((size_t)bh << 10) + vt;
      float f = fg_arr[o] + fg_arr[16384 + o];
      igv[c] = ig_arr[o] + ig_arr[16384 + o];
      float lf = (f >= 0.f) ? -log1pf(__expf(-f)) : f - log1pf(__expf(f));
      float v = lf;
#pragma unroll
      for (int off = 1; off < 64; off <<= 1) {
        float u = __shfl_up(v, off);
        if (lane >= off) v += u;
      }
      if (lane == 63) sws[c * 8 + (tid >> 6)] = v;
      vsc[c] = v;
    }
    __syncthreads();
#pragma unroll
    for (int c = 0; c < 2; c++) {
      int vt = c * 512 + tid;
      int wvv = c * 8 + (tid >> 6);
      float pre = 0.f;
      for (int u = 0; u < wvv; u++) pre += sws[u];
      float cs = vsc[c] + pre;
      float av = igv[c] - cs;
      sa[vt] = __expf(av);
      float m = av;
#pragma unroll
      for (int off = 1; off < 64; off <<= 1) {
        float u = __shfl_up(m, off);
        if (lane >= off) m = fmaxf(m, u);
      }
      if (lane == 63) swm[wvv] = m;
      css[c] = cs; msc[c] = m;
    }
    __syncthreads();
#pragma unroll
    for (int c = 0; c < 2; c++) {
      int vt = c * 512 + tid;
      int wvv = c * 8 + (tid >> 6);
      float pm = -3.4e38f;
      for (int u = 0; u < wvv; u++) pm = fmaxf(pm, swm[u]);
      float rmx = fmaxf(msc[c], pm);
      if (vt >= s0 && vt < s0 + 128) {
        srm[vt - s0] = rmx;
        senm[vt - s0] = __expf(-(css[c] + rmx));
      }
    }
    __syncthreads();
  }

  const float scale = 0.08838834764831845f;  // 1/sqrt(128)
  float rmv[4], er[4];
#pragma unroll
  for (int r = 0; r < 4; r++) {
    rmv[r] = srm[wave * 16 + lq * 4 + r];
    er[r] = scale * __expf(-rmv[r]);   // hoisted: exp(a-rm) = exp(a)*exp(-rm)
  }

  // bf16 ones vector for MFMA row-sum (sc = P @ 1)
  S8 onesu;
#pragma unroll
  for (int j = 0; j < 8; j++) onesu.u[j] = 0x3F80;
  const short8 ones8 = onesu.v;

  f32x4 accH[8] = {};
  f32x4 accS = {};
  const int lr16 = lane >> 4;      // 0..3 (K rows: 256B each, 16 lanes/row)
  const int ls16 = lane & 15;      // 16B slot within 256B K row
  const int lr8 = lane >> 3;       // 0..7  (V rows: 128B each, 8 lanes/row)
  const int cgv = (lane & 7) ^ lr8;  // pre-swizzled V source slot
  const u16* vtbase = vtg + ((size_t)b * INNER_D + c0) * S_LEN;

// 8 waves: each stages 2 K block-rows + 2 V block-rows (4 vmcnt ops/wave)
#define PREF(KS, VS, T0) do { \
  _Pragma("unroll") for (int j = 0; j < 2; j++) { \
    int rK = (wave * 2 + j) * 4 + lr16; \
    int cgk = ls16 ^ (rK & 7); \
    gload16(khg + (rowbase + (T0) + rK) * INNER_D + c0 + cgk * 8, &KS[(wave * 2 + j) * 512]); \
  } \
  _Pragma("unroll") for (int j = 0; j < 2; j++) { \
    int rV = (wave * 2 + j) * 8 + lr8; \
    gload16(vtbase + (size_t)rV * S_LEN + (T0) + cgv * 8, &VS[(wave * 2 + j) * 512]); \
  } \
} while (0)

#define QK_STEP(KS, PACC) do { \
  __builtin_amdgcn_s_setprio(1); \
  _Pragma("unroll") for (int kc = 0; kc < 4; kc++) \
    _Pragma("unroll") for (int cb = 0; cb < 4; cb++) { \
      short8 bk = *(const short8*)&KS[(cb * 16 + lm) * 128 + (((kc * 4 + lq) ^ (lm & 7)) * 8)]; \
      PACC[cb] = __builtin_amdgcn_mfma_f32_16x16x32_bf16(aq[kc], bk, PACC[cb], 0, 0, 0); \
    } \
  __builtin_amdgcn_s_setprio(0); \
} while (0)

// msk: block-uniform — causal cndmask only on tiles with T0 >= s0; exp(a) from LDS
#define W_PV(VT, T0, PACC, MSK) do { \
  _Pragma("unroll") for (int cb = 0; cb < 4; cb++) { \
    float ec = sa[(T0) + cb * 16 + lm]; \
    _Pragma("unroll") for (int r = 0; r < 4; r++) { \
      float wv = PACC[cb][r] * ec * er[r]; \
      if (MSK) { \
        int colg = (T0) + cb * 16 + lm; \
        int rowg = s0 + wave * 16 + lq * 4 + r; \
        if (colg > rowg) wv = 0.f; \
      } \
      Ws[(wave * 16 + lq * 4 + r) * 72 + cb * 16 + lm] = f2bf(wv); \
    } \
  } \
  __builtin_amdgcn_s_setprio(1); \
  _Pragma("unroll") for (int kc = 0; kc < 2; kc++) { \
    short8 aw = *(const short8*)&Ws[(wave * 16 + lm) * 72 + kc * 32 + lq * 8]; \
    accS = __builtin_amdgcn_mfma_f32_16x16x32_bf16(aw, ones8, accS, 0, 0, 0); \
    _Pragma("unroll") for (int nb = 0; nb < 8; nb++) { \
      short8 bv = *(const short8*)&VT[(nb * 16 + lm) * 64 + (((kc * 4 + lq) ^ (lm & 7)) * 8)]; \
      accH[nb] = __builtin_amdgcn_mfma_f32_16x16x32_bf16(aw, bv, accH[nb], 0, 0, 0); \
    } \
  } \
  __builtin_amdgcn_s_setprio(0); \
} while (0)

  int kt = k0t;
  PREF(Ks0, Vt0, kt * 64);
  asm volatile("" ::: "memory");
  if (kt + 1 < k1t) PREF(Ks1, Vt1, (kt + 1) * 64);

  while (true) {
    {
      if (kt + 1 < k1t) asm volatile("s_waitcnt vmcnt(4)" ::: "memory");
      else              asm volatile("s_waitcnt vmcnt(0)" ::: "memory");
      __builtin_amdgcn_sched_barrier(0);
      __builtin_amdgcn_s_barrier();
      f32x4 pacc[4] = {};
      QK_STEP(Ks0, pacc);
      bool msk = (kt * 64 >= s0);
      W_PV(Vt0, kt * 64, pacc, msk);
      __builtin_amdgcn_s_barrier();
      if (kt + 2 < k1t) PREF(Ks0, Vt0, (kt + 2) * 64);
      kt++;
      if (kt >= k1t) break;
    }
    {
      if (kt + 1 < k1t) asm volatile("s_waitcnt vmcnt(4)" ::: "memory");
      else              asm volatile("s_waitcnt vmcnt(0)" ::: "memory");
      __builtin_amdgcn_sched_barrier(0);
      __builtin_amdgcn_s_barrier();
      f32x4 pacc[4] = {};
      QK_STEP(Ks1, pacc);
      bool msk = (kt * 64 >= s0);
      W_PV(Vt1, kt * 64, pacc, msk);
      __builtin_amdgcn_s_barrier();
      if (kt + 2 < k1t) PREF(Ks1, Vt1, (kt + 2) * 64);
      kt++;
      if (kt >= k1t) break;
    }
  }
#undef PREF
#undef QK_STEP
#undef W_PV

  if (mode != 0) {
    int slot = mode - 1;
    int qr = qp - 3;
    float* Hp = hpart + (size_t)slot * HP_SLOT + ((size_t)(bh * 5 + qr)) * 16384;
    float* sp = scpart + slot * SC_SLOT + (bh * 5 + qr) * 128;
    float* ep = enmp + (bh * 5 + qr) * 128;
#pragma unroll
    for (int r = 0; r < 4; r++) {
      int row = wave * 16 + lq * 4 + r;
      if (lm == 0) {
        sp[row] = accS[r];
        if (slot == 0) ep[row] = senm[row];
      }
#pragma unroll
      for (int nb = 0; nb < 8; nb++)
        Hp[row * 128 + nb * 16 + lm] = accH[nb][r];
    }
    return;
  }

  float inv[4], muv[4], rsv[4];
#pragma unroll
  for (int r = 0; r < 4; r++) {
    int row = wave * 16 + lq * 4 + r;
    float nrm = fmaxf(fabsf(accS[r]), senm[row]);
    inv[r] = 1.f / (nrm + 1e-6f);
  }
#pragma unroll
  for (int r = 0; r < 4; r++) {
    float s = 0.f, qq = 0.f;
#pragma unroll
    for (int nb = 0; nb < 8; nb++) {
      float hv = accH[nb][r] * inv[r];
      accH[nb][r] = hv;
      s += hv; qq += hv * hv;
    }
    s += __shfl_xor(s, 1); s += __shfl_xor(s, 2); s += __shfl_xor(s, 4); s += __shfl_xor(s, 8);
    qq += __shfl_xor(qq, 1); qq += __shfl_xor(qq, 2); qq += __shfl_xor(qq, 4); qq += __shfl_xor(qq, 8);
    float mu = s * (1.f / DHEAD);
    float var = qq * (1.f / DHEAD) - mu * mu;
    muv[r] = mu;
    rsv[r] = rsqrtf(var + 1e-5f);
  }
  float ow[8], sk[8];
#pragma unroll
  for (int nb = 0; nb < 8; nb++) {
    ow[nb] = onw[c0 + nb * 16 + lm];
    sk[nb] = skip[c0 + nb * 16 + lm];
  }
#pragma unroll
  for (int r = 0; r < 4; r++) {
    int rowg = s0 + wave * 16 + lq * 4 + r;
    size_t base = (rowbase + rowg) * INNER_D + c0;
#pragma unroll
    for (int nb = 0; nb < 8; nb++) {
      int d = nb * 16 + lm;
      float xcv = xc[base + d];
      float zv = bf2f(zh[base + d]);
      float hn = (accH[nb][r] - muv[r]) * rsv[r] * ow[nb] + sk[nb] * xcv;
      float o = hn * (zv / (1.f + __expf(-zv)));
      hs[base + d] = f2bf(o);
    }
  }
}

// combine 2..3 partial slots for rows s >= 384; one wave per row (10240 rows).
__global__ __launch_bounds__(256) void attn_combine_kernel(
    const float* __restrict__ hpart, const float* __restrict__ scpart,
    const float* __restrict__ enmp,
    const float* __restrict__ xc, const u16* __restrict__ zh,
    const float* __restrict__ skip, const float* __restrict__ onw,
    u16* __restrict__ hs)
{
  int wave = threadIdx.x >> 6, lane = threadIdx.x & 63;
  int gid = blockIdx.x * 4 + wave;   // 0..10239
  int bh = gid / 640;
  int rr = gid % 640;
  int qr = rr >> 7, row = rr & 127;
  int b = bh >> 3, hh = bh & 7;
  int s = (qr + 3) * 128 + row;
  int nsl = (qr >= 3) ? 3 : 2;       // qp3-5: 2 slots, qp6-7: 3 slots
  size_t off = (((size_t)(bh * 5 + qr)) * 128 + row) * 128 + lane * 2;
  int sidx = (bh * 5 + qr) * 128 + row;
  float hx = 0.f, hy = 0.f, sc = 0.f;
  for (int sl = 0; sl < nsl; sl++) {
    float2 hp = *(const float2*)(hpart + (size_t)sl * HP_SLOT + off);
    hx += hp.x; hy += hp.y;
    sc += scpart[sl * SC_SLOT + sidx];
  }
  float nrm = fmaxf(fabsf(sc), enmp[sidx]);
  float inv = 1.f / (nrm + 1e-6f);
  hx *= inv; hy *= inv;
  float sm = hx + hy, sq = hx * hx + hy * hy;
#pragma unroll
  for (int off2 = 32; off2; off2 >>= 1) { sm += __shfl_xor(sm, off2); sq += __shfl_xor(sq, off2); }
  float mu = sm * (1.f / DHEAD);
  float var = sq * (1.f / DHEAD) - mu * mu;
  float rs = rsqrtf(var + 1e-5f);
  int c0 = hh * DHEAD + lane * 2;
  size_t base = ((size_t)(b * S_LEN + s)) * INNER_D + c0;
  float2 xc2 = *(const float2*)(xc + base);
  ushort2 z2u = *(const ushort2*)(zh + base);
  float z2x = bf2f(z2u.x), z2y = bf2f(z2u.y);
  float skx = skip[c0], sky = skip[c0 + 1];
  float owx = onw[c0],  owy = onw[c0 + 1];
  ushort2 o;
  o.x = f2bf(((hx - mu) * rs * owx + skx * xc2.x) * (z2x / (1.f + __expf(-z2x))));
  o.y = f2bf(((hy - mu) * rs * owy + sky * xc2.y) * (z2y / (1.f + __expf(-z2y))));
  *(ushort2*)(hs + base) = o;
}

extern "C" void kernel_launch(void* const* d_in, const int* in_sizes, int n_in,
                              void* d_out, int out_size, void* d_ws, size_t ws_size,
                              hipStream_t stream)
{
  const float* x_enc   = (const float*)d_in[0];
  const float* x_mark  = (const float*)d_in[1];
  const float* emb_W   = (const float*)d_in[4];
  const float* emb_b   = (const float*)d_in[5];
  const float* ln_w    = (const float*)d_in[6];
  const float* up_W    = (const float*)d_in[7];
  const float* conv_W  = (const float*)d_in[8];
  const float* conv_b  = (const float*)d_in[9];
  const float* q_W     = (const float*)d_in[10];
  const float* k_W     = (const float*)d_in[11];
  const float* v_W     = (const float*)d_in[12];
  const float* ig_W    = (const float*)d_in[13];
  const float* ig_b    = (const float*)d_in[14];
  const float* fg_W    = (const float*)d_in[15];
  const float* fg_b    = (const float*)d_in[16];
  const float* skip_w  = (const float*)d_in[17];
  const float* onorm_w = (const float*)d_in[18];
  const float* down_W  = (const float*)d_in[19];
  const float* post_ln = (const float*)d_in[20];
  const float* head_W  = (const float*)d_in[21];
  const float* head_b  = (const float*)d_in[22];

  float* p = (float*)d_ws;
  float* x    = p; p += 1048576;   // 2048*512 f32
  float* xm   = p; p += 2097152;   // 2048*1024 f32; reused as hsbh bf16 after convqkv
  float* xc   = p; p += 2097152;
  float* igb_ = p; p += 32768;     // 2 K-halves x 16384
  float* fgb_ = p; p += 32768;
  float* enmp = p; p += 16384;     // 16 bh x 5 qr x 128 (padded)
  u16* qhb = (u16*)p; p += 1048576;  // 2048*1024 u16
  u16* khb = (u16*)p; p += 1048576;
  u16* vhb = (u16*)p; p += 1048576;
  u16* zh  = (u16*)p; p += 1048576;  // 2048*1024 u16 (full size)
  u16* xnh = (u16*)p; p += 524288;   // 2048*512 u16
  u16* upWtA = (u16*)p; p += 2097152; // 4 x 2048x512 u16
  u16* dnWtA = (u16*)p; p += 1048576; // 4 x 512x1024 u16
  u16* gtwH = (u16*)p; p += 98304;    // 4 x 16 x 3072 u16
  u16* gtwL = (u16*)p; p += 98304;
  float* hpart = p; p += 3932160;     // 3 slots x 16 bh x 5 qr x 128 x 128 f32
  float* scpart = p; p += 32768;      // 3 slots x 10240 (padded)
  u16* vtg = (u16*)p; p += 1048576;   // 2 x 1024 x 1024 u16 (V^T per layer)
  u16* hsbh = (u16*)xm;

  // one merged prep launch: up/down weight transposes + gates weights + embedding
  prep_kernel<<<4352, 256, 0, stream>>>(
      up_W, upWtA, down_W, dnWtA, ig_W, fg_W, gtwH, gtwL,
      x_enc, x_mark, emb_W, emb_b, x);

  for (int L = 0; L < 4; L++) {
    ln_kernel<<<512, 256, 0, stream>>>(x, ln_w + L * 512, xnh);
    gemm_bf16_split64<<<dim3(16, 16), 256, 0, stream>>>(
        xnh, upWtA + (size_t)L * 1048576, xm, zh, 2048, 2048, 512, 1024, 1024);
    convqkv_kernel<<<256, 256, 0, stream>>>(
        xm, conv_W + L * 4096, conv_b + L * 1024,
        q_W + L * 4096, k_W + L * 4096, v_W + L * 4096,
        xc, qhb, khb, vhb, vtg);
    gates_mfma_kernel<<<256, 256, 0, stream>>>(
        qhb, khb, vhb, gtwH + (size_t)L * 49152, gtwL + (size_t)L * 49152,
        ig_b + L * 8, fg_b + L * 8, igb_, fgb_);
    attn_mfma_kernel<<<dim3(16, 15), 512, 0, stream>>>(
        qhb, khb, vtg, igb_, fgb_, xc, zh,
        skip_w + L * 1024, onorm_w + L * 1024, hsbh, hpart, scpart, enmp);
    attn_combine_kernel<<<2560, 256, 0, stream>>>(
        hpart, scpart, enmp, xc, zh, skip_w + L * 1024, onorm_w + L * 1024, hsbh);
    gemm_bf16_32<<<dim3(8, 32), 256, 0, stream>>>(
        hsbh, dnWtA + (size_t)L * 524288, x, 2048, 512, 1024, 512);
  }

  lnhead_kernel<<<192, 256, 0, stream>>>(x, post_ln, head_W, head_b, (float*)d_out);
}

// Round 14
// 409.233 us; speedup vs baseline: 1.1253x; 1.0140x over previous
//
#include <hip/hip_runtime.h>
#include <hip/hip_bf16.h>

#define S_LEN 1024
#define E_DIM 512
#define INNER_D 1024
#define NHEAD 8
#define DHEAD 128

typedef unsigned short u16;
typedef unsigned int u32;
typedef __attribute__((ext_vector_type(8))) short short8;
typedef __attribute__((ext_vector_type(4))) float f32x4;

union S8 { short8 v; u16 u[8]; uint4 q; };

__device__ __forceinline__ u16 f2bf(float f) {
  u32 u = __float_as_uint(f);
  u32 r = u + 0x7FFFu + ((u >> 16) & 1u);
  return (u16)(r >> 16);
}
__device__ __forceinline__ float bf2f(u16 u) { return __uint_as_float(((u32)u) << 16); }

// direct global -> LDS (16B per lane). LDS dest = wave-uniform base + lane*16B (linear).
__device__ __forceinline__ void gload16(const u16* g, u16* l) {
  __builtin_amdgcn_global_load_lds((const __attribute__((address_space(1))) void*)g,
                                   (__attribute__((address_space(3))) void*)l, 16, 0, 0);
}

// ---------------- merged one-time prep: transposes + gates weights + embedding ----------------
__device__ __forceinline__ void prep_transpose(
    const float* __restrict__ in, u16* __restrict__ out, int K, int N,
    int k0, int n0, int t, u16 (*T)[72])
{
  int kr = t >> 2, nseg = (t & 3) * 16;
  const float* src = in + (size_t)(k0 + kr) * N + n0 + nseg;
#pragma unroll
  for (int j = 0; j < 16; j++) T[kr][nseg + j] = f2bf(src[j]);
  __syncthreads();
  int nr = t >> 2, kseg = (t & 3) * 16;
  u32 u[8];
#pragma unroll
  for (int rr = 0; rr < 8; rr++) {
    u32 lo = T[kseg + 2 * rr][nr];
    u32 hi = T[kseg + 2 * rr + 1][nr];
    u[rr] = lo | (hi << 16);
  }
  u16* dst = out + (size_t)(n0 + nr) * K + k0 + kseg;
  uint4 w0 = {u[0], u[1], u[2], u[3]};
  uint4 w1 = {u[4], u[5], u[6], u[7]};
  *(uint4*)dst = w0;
  *(uint4*)(dst + 8) = w1;
}

__global__ __launch_bounds__(256) void prep_kernel(
    const float* __restrict__ up_W, u16* __restrict__ upWt,
    const float* __restrict__ down_W, u16* __restrict__ dnWt,
    const float* __restrict__ igW, const float* __restrict__ fgW,
    u16* __restrict__ ghi, u16* __restrict__ glo,
    const float* __restrict__ xe, const float* __restrict__ xmk,
    const float* __restrict__ eW, const float* __restrict__ eb,
    float* __restrict__ x)
{
  __shared__ u16 T[64][72];
  __shared__ float in_s[25];
  int id = blockIdx.x;
  int t = threadIdx.x;
  if (id < 1024) {                     // up_W transpose: [L][512][2048] -> [L][2048][512]
    int bx = id & 7, rest = id >> 3;
    int by = rest & 31, L = rest >> 5;
    prep_transpose(up_W + (size_t)L * 512 * 2048, upWt + (size_t)L * 1048576,
                   512, 2048, bx * 64, by * 64, t, T);
  } else if (id < 1536) {              // down_W transpose: [L][1024][512] -> [L][512][1024]
    int id2 = id - 1024;
    int bx = id2 & 15, rest = id2 >> 4;
    int by = rest & 7, L = rest >> 3;
    prep_transpose(down_W + (size_t)L * 1024 * 512, dnWt + (size_t)L * 524288,
                   1024, 512, bx * 64, by * 64, t, T);
  } else if (id < 2304) {              // gates weights: hi/lo split transpose
    int id3 = id - 1536;
    int bx = id3 % 12, rest = id3 / 12;
    int n = rest & 15, L = rest >> 4;
    int k = bx * 256 + t;
    const float* W = ((n < 8) ? igW : fgW) + (size_t)L * 24576;
    float v = W[(size_t)k * 8 + (n & 7)];
    u16 h = f2bf(v);
    u16 l = f2bf(v - bf2f(h));
    size_t o = ((size_t)L * 16 + n) * 3072 + k;
    ghi[o] = h;
    glo[o] = l;
  } else {                             // embedding, one row per block
    int row = id - 2304;
    if (t < 21) in_s[t] = xe[row * 21 + t];
    else if (t < 25) in_s[t] = xmk[row * 4 + t - 21];
    __syncthreads();
#pragma unroll
    for (int rep = 0; rep < 2; rep++) {
      int e = t + rep * 256;
      float acc = eb[e];
#pragma unroll
      for (int i = 0; i < 25; i++) acc += in_s[i] * eW[i * E_DIM + e];
      x[(size_t)row * E_DIM + e] = acc;
    }
  }
}

// ---------------- layernorm -> bf16; one wave per row, 4 rows/block ----------------
__global__ __launch_bounds__(256) void ln_kernel(
    const float* __restrict__ x, const float* __restrict__ w, u16* __restrict__ out)
{
  int row = blockIdx.x * 4 + (threadIdx.x >> 6);
  int lane = threadIdx.x & 63;
  const float* xr = x + (size_t)row * E_DIM + lane * 8;
  float4 a = *(const float4*)xr;
  float4 b = *(const float4*)(xr + 4);
  float s = a.x + a.y + a.z + a.w + b.x + b.y + b.z + b.w;
  float q = a.x * a.x + a.y * a.y + a.z * a.z + a.w * a.w
          + b.x * b.x + b.y * b.y + b.z * b.z + b.w * b.w;
#pragma unroll
  for (int off = 1; off < 64; off <<= 1) { s += __shfl_xor(s, off); q += __shfl_xor(q, off); }
  float mu = s * (1.f / E_DIM);
  float var = q * (1.f / E_DIM) - mu * mu;
  float rs = rsqrtf(var + 1e-5f);
  const float* wr = w + lane * 8;
  S8 o;
  o.u[0] = f2bf((a.x - mu) * rs * wr[0]);
  o.u[1] = f2bf((a.y - mu) * rs * wr[1]);
  o.u[2] = f2bf((a.z - mu) * rs * wr[2]);
  o.u[3] = f2bf((a.w - mu) * rs * wr[3]);
  o.u[4] = f2bf((b.x - mu) * rs * wr[4]);
  o.u[5] = f2bf((b.y - mu) * rs * wr[5]);
  o.u[6] = f2bf((b.z - mu) * rs * wr[6]);
  o.u[7] = f2bf((b.w - mu) * rs * wr[7]);
  *(uint4*)(out + (size_t)row * E_DIM + lane * 8) = o.q;
}

// ---------------- fused final layernorm + head (one block per output row) ----------------
__global__ __launch_bounds__(256) void lnhead_kernel(
    const float* __restrict__ x, const float* __restrict__ w,
    const float* __restrict__ hW, const float* __restrict__ hb,
    float* __restrict__ out)
{
  int ridx = blockIdx.x;
  int b = ridx / 96, r = ridx % 96;
  int row = b * S_LEN + (S_LEN - 96) + r;
  int tid = threadIdx.x;
  const float* xr = x + (size_t)row * E_DIM;
  float2 v = *(const float2*)(xr + tid * 2);
  float s = v.x + v.y, q = v.x * v.x + v.y * v.y;
#pragma unroll
  for (int off = 32; off; off >>= 1) { s += __shfl_xor(s, off); q += __shfl_xor(q, off); }
  __shared__ float ssum[4], ssq[4];
  __shared__ float lnv[512];
  __shared__ float part[8][32];
  int wv = tid >> 6;
  if ((tid & 63) == 0) { ssum[wv] = s; ssq[wv] = q; }
  __syncthreads();
  s = ssum[0] + ssum[1] + ssum[2] + ssum[3];
  q = ssq[0] + ssq[1] + ssq[2] + ssq[3];
  float mu = s * (1.f / E_DIM);
  float var = q * (1.f / E_DIM) - mu * mu;
  float rs = rsqrtf(var + 1e-5f);
  int e = tid * 2;
  lnv[e]     = (v.x - mu) * rs * w[e];
  lnv[e + 1] = (v.y - mu) * rs * w[e + 1];
  __syncthreads();
  int n = tid & 31, sl = tid >> 5;
  float p = 0.f;
  if (n < 21) {
#pragma unroll 8
    for (int kk = 0; kk < 64; kk++)
      p += lnv[sl * 64 + kk] * hW[(sl * 64 + kk) * 21 + n];
  }
  part[sl][n] = p;
  __syncthreads();
  if (tid < 21) {
    float acc = hb[tid];
#pragma unroll
    for (int j = 0; j < 8; j++) acc += part[j][tid];
    out[ridx * 21 + tid] = acc;
  }
}

// ---------------- bf16 MFMA GEMM 128x128, BK=64, 3-buf distance-2, 1 barrier/stage ---------
// split C: C0 f32, C1 bf16; grid (N/128, M/128). K must be 512 (NT=8).
__global__ __launch_bounds__(256) void gemm_bf16_split64(
    const u16* __restrict__ A, const u16* __restrict__ Bt,
    float* __restrict__ C0, u16* __restrict__ C1,
    int M, int N, int K, int split_col, int ldc)
{
  __shared__ u16 As0[128 * 64], As1[128 * 64], As2[128 * 64];
  __shared__ u16 Bs0[128 * 64], Bs1[128 * 64], Bs2[128 * 64];
  const int tid = threadIdx.x;
  const int row0 = blockIdx.y * 128, col0 = blockIdx.x * 128;
  const int wave = tid >> 6, lane = tid & 63;
  const int wr = wave >> 1, wc = wave & 1;   // wave tile: 64 rows x 64 cols
  const int lm = lane & 15, lq = lane >> 4;
  const int lr8 = lane >> 3;                 // 0..7 row within 8-row group
  const int cg8 = (lane & 7) ^ lr8;          // pre-swizzled source 16B slot (8 slots/row)
  f32x4 acc[4][4] = {};
  const u16* Abase = A + (size_t)(row0 + lr8) * K + cg8 * 8;
  const u16* Bbase = Bt + (size_t)(col0 + lr8) * K + cg8 * 8;
  const int key = lm & 7;

#define STG_UP(AS, BS, K0) do { \
  _Pragma("unroll") for (int i = 0; i < 4; i++) \
    gload16(Abase + (size_t)((wave * 4 + i) * 8) * K + (K0), &AS[(wave * 4 + i) * 512]); \
  _Pragma("unroll") for (int i = 0; i < 4; i++) \
    gload16(Bbase + (size_t)((wave * 4 + i) * 8) * K + (K0), &BS[(wave * 4 + i) * 512]); \
} while (0)

#define CMP_UP(AS, BS) do { \
  _Pragma("unroll") for (int kc = 0; kc < 2; kc++) { \
    short8 af[4], bfv[4]; \
    _Pragma("unroll") for (int i = 0; i < 4; i++) \
      af[i] = *(const short8*)&AS[(wr * 64 + i * 16 + lm) * 64 + (((kc * 4 + lq) ^ key) * 8)]; \
    _Pragma("unroll") for (int j = 0; j < 4; j++) \
      bfv[j] = *(const short8*)&BS[(wc * 64 + j * 16 + lm) * 64 + (((kc * 4 + lq) ^ key) * 8)]; \
    _Pragma("unroll") for (int i = 0; i < 4; i++) \
      _Pragma("unroll") for (int j = 0; j < 4; j++) \
        acc[i][j] = __builtin_amdgcn_mfma_f32_16x16x32_bf16(af[i], bfv[j], acc[i][j], 0, 0, 0); \
  } \
} while (0)

  STG_UP(As0, Bs0, 0);
  asm volatile("" ::: "memory");
  STG_UP(As1, Bs1, 64);
  // distance-2 prefetch: write target = buffer read 2 stages ago; 1 barrier/stage
#pragma unroll
  for (int t = 0; t < 8; t++) {
    if (t < 7) asm volatile("s_waitcnt vmcnt(8)" ::: "memory");
    else       asm volatile("s_waitcnt vmcnt(0)" ::: "memory");
    __builtin_amdgcn_sched_barrier(0);
    __builtin_amdgcn_s_barrier();
    if ((t % 3) == 0)      CMP_UP(As0, Bs0);
    else if ((t % 3) == 1) CMP_UP(As1, Bs1);
    else                   CMP_UP(As2, Bs2);
    if (t + 2 < 8) {
      if (((t + 2) % 3) == 0)      STG_UP(As0, Bs0, (t + 2) * 64);
      else if (((t + 2) % 3) == 1) STG_UP(As1, Bs1, (t + 2) * 64);
      else                         STG_UP(As2, Bs2, (t + 2) * 64);
    }
  }
#undef STG_UP
#undef CMP_UP

  const bool toC1 = (col0 >= split_col);
#pragma unroll
  for (int i = 0; i < 4; i++) {
#pragma unroll
    for (int j = 0; j < 4; j++) {
      int col = col0 - (toC1 ? split_col : 0) + wc * 64 + j * 16 + lm;
#pragma unroll
      for (int r = 0; r < 4; r++) {
        int row = row0 + wr * 64 + i * 16 + lq * 4 + r;
        if (toC1) C1[(size_t)row * ldc + col] = f2bf(acc[i][j][r]);
        else C0[(size_t)row * ldc + col] = acc[i][j][r];
      }
    }
  }
}

// ---------------- bf16 MFMA GEMM 64x64 (down-proj, +=), BK=128, 3-buf distance-2 ------------
// K must be 1024 (NT=8).
__global__ __launch_bounds__(256) void gemm_bf16_32(
    const u16* __restrict__ A, const u16* __restrict__ Bt,
    float* __restrict__ C, int M, int N, int K, int ldc)
{
  __shared__ u16 As0[64 * 128], As1[64 * 128], As2[64 * 128];
  __shared__ u16 Bs0[64 * 128], Bs1[64 * 128], Bs2[64 * 128];
  const int tid = threadIdx.x;
  const int row0 = blockIdx.y * 64, col0 = blockIdx.x * 64;
  const int wave = tid >> 6, lane = tid & 63;
  const int wr = wave >> 1, wc = wave & 1;   // wave tile: 32 rows x 32 cols
  const int lm = lane & 15, lq = lane >> 4;
  const int lr16 = lane >> 4;                // 0..3 row within 4-row group (256B rows)
  const int ls16 = lane & 15;                // 16B slot within row (16 slots)
  f32x4 acc[2][2] = {};

#define STAGE_DN(AS, BS, K0) do { \
  _Pragma("unroll") for (int i = 0; i < 4; i++) { \
    int rA = (wave * 4 + i) * 4 + lr16; \
    int cgk = ls16 ^ (rA & 15); \
    gload16(A + (size_t)(row0 + rA) * K + (K0) + cgk * 8, &AS[(wave * 4 + i) * 512]); \
  } \
  _Pragma("unroll") for (int i = 0; i < 4; i++) { \
    int rB = (wave * 4 + i) * 4 + lr16; \
    int cgk = ls16 ^ (rB & 15); \
    gload16(Bt + (size_t)(col0 + rB) * K + (K0) + cgk * 8, &BS[(wave * 4 + i) * 512]); \
  } \
} while (0)

#define COMPUTE_DN(AS, BS) do { \
  _Pragma("unroll") for (int kc = 0; kc < 4; kc++) { \
    short8 af[2], bfv[2]; \
    _Pragma("unroll") for (int i = 0; i < 2; i++) \
      af[i] = *(const short8*)&AS[(wr * 32 + i * 16 + lm) * 128 + (((kc * 4 + lq) ^ lm) * 8)]; \
    _Pragma("unroll") for (int j = 0; j < 2; j++) \
      bfv[j] = *(const short8*)&BS[(wc * 32 + j * 16 + lm) * 128 + (((kc * 4 + lq) ^ lm) * 8)]; \
    _Pragma("unroll") for (int i = 0; i < 2; i++) \
      _Pragma("unroll") for (int j = 0; j < 2; j++) \
        acc[i][j] = __builtin_amdgcn_mfma_f32_16x16x32_bf16(af[i], bfv[j], acc[i][j], 0, 0, 0); \
  } \
} while (0)

  STAGE_DN(As0, Bs0, 0);
  asm volatile("" ::: "memory");
  STAGE_DN(As1, Bs1, 128);
  // distance-2 prefetch, 1 barrier/stage
#pragma unroll
  for (int t = 0; t < 8; t++) {
    if (t < 7) asm volatile("s_waitcnt vmcnt(8)" ::: "memory");
    else       asm volatile("s_waitcnt vmcnt(0)" ::: "memory");
    __builtin_amdgcn_sched_barrier(0);
    __builtin_amdgcn_s_barrier();
    if ((t % 3) == 0)      COMPUTE_DN(As0, Bs0);
    else if ((t % 3) == 1) COMPUTE_DN(As1, Bs1);
    else                   COMPUTE_DN(As2, Bs2);
    if (t + 2 < 8) {
      if (((t + 2) % 3) == 0)      STAGE_DN(As0, Bs0, (t + 2) * 128);
      else if (((t + 2) % 3) == 1) STAGE_DN(As1, Bs1, (t + 2) * 128);
      else                         STAGE_DN(As2, Bs2, (t + 2) * 128);
    }
  }
#undef STAGE_DN
#undef COMPUTE_DN

#pragma unroll
  for (int i = 0; i < 2; i++) {
#pragma unroll
    for (int j = 0; j < 2; j++) {
      int col = col0 + wc * 32 + j * 16 + lm;
#pragma unroll
      for (int r = 0; r < 4; r++) {
        int row = row0 + wr * 32 + i * 16 + lq * 4 + r;
        C[(size_t)row * ldc + col] += acc[i][j][r];
      }
    }
  }
}

// ---------------- fused causal conv+SiLU+headwise qkv; 8 rows/block; writes V and V^T -------
__global__ __launch_bounds__(256) void convqkv_kernel(
    const float* __restrict__ xm,
    const float* __restrict__ cw, const float* __restrict__ cb,
    const float* __restrict__ qw, const float* __restrict__ kw, const float* __restrict__ vw,
    float* __restrict__ xc, u16* __restrict__ q, u16* __restrict__ k, u16* __restrict__ v,
    u16* __restrict__ vt)
{
  int r0 = blockIdx.x * 8;         // rows r0..r0+7, same batch (S_LEN % 8 == 0)
  int s0 = r0 & (S_LEN - 1);
  int g = threadIdx.x;             // channel group of 4
  int c0 = g * 4;
  const float* base = xm + (size_t)r0 * INNER_D + c0;

  float4 xv[11];
#pragma unroll
  for (int j = 0; j < 11; j++) {
    int ts = s0 - 3 + j;
    float4 t = {0.f, 0.f, 0.f, 0.f};
    if (ts >= 0) t = *(const float4*)(base + (ptrdiff_t)(j - 3) * INNER_D);
    xv[j] = t;
  }
  float cwv[4][4];
#pragma unroll
  for (int c = 0; c < 4; c++)
#pragma unroll
    for (int kk = 0; kk < 4; kk++) cwv[c][kk] = cw[(c0 + c) * 4 + kk];
  float cbv[4] = {cb[c0], cb[c0 + 1], cb[c0 + 2], cb[c0 + 3]};
  const float* qg = qw + g * 16;
  const float* kg = kw + g * 16;
  const float* vg = vw + g * 16;
  float qwv[16], kwv[16], vwv[16];
#pragma unroll
  for (int i = 0; i < 16; i++) { qwv[i] = qg[i]; kwv[i] = kg[i]; vwv[i] = vg[i]; }

  u32 vt_pack[4][4];   // [channel][s-pair] fully static indexing

#pragma unroll
  for (int i = 0; i < 8; i++) {
    float a0 = cbv[0], a1 = cbv[1], a2 = cbv[2], a3 = cbv[3];
#pragma unroll
    for (int kk = 0; kk < 4; kk++) {
      float4 xvv = xv[i + kk];
      a0 += xvv.x * cwv[0][kk];
      a1 += xvv.y * cwv[1][kk];
      a2 += xvv.z * cwv[2][kk];
      a3 += xvv.w * cwv[3][kk];
    }
    a0 = a0 / (1.f + __expf(-a0));
    a1 = a1 / (1.f + __expf(-a1));
    a2 = a2 / (1.f + __expf(-a2));
    a3 = a3 / (1.f + __expf(-a3));
    float4 accv = {a0, a1, a2, a3};
    *(float4*)(xc + (size_t)(r0 + i) * INNER_D + c0) = accv;

    float xcv[4] = {a0, a1, a2, a3};
    float xmv[4] = {xv[i + 3].x, xv[i + 3].y, xv[i + 3].z, xv[i + 3].w};
    ushort4 qs, ks, vs;
    u16* qp = (u16*)&qs; u16* kp = (u16*)&ks; u16* vp = (u16*)&vs;
#pragma unroll
    for (int o = 0; o < 4; o++) {
      float aq = 0.f, ak = 0.f, av = 0.f;
#pragma unroll
      for (int d = 0; d < 4; d++) {
        aq += xcv[d] * qwv[o * 4 + d];
        ak += xcv[d] * kwv[o * 4 + d];
        av += xmv[d] * vwv[o * 4 + d];
      }
      qp[o] = f2bf(aq); kp[o] = f2bf(ak);
      u16 vv = f2bf(av);
      vp[o] = vv;
      if ((i & 1) == 0) vt_pack[o][i >> 1] = (u32)vv;
      else              vt_pack[o][i >> 1] |= ((u32)vv) << 16;
    }
    size_t off = (size_t)(r0 + i) * INNER_D + c0;
    *(ushort4*)(q + off) = qs;
    *(ushort4*)(k + off) = ks;
    *(ushort4*)(v + off) = vs;
  }
  // V^T: vt[b][d][s], 16B (8 s-values) per channel
  u16* vtb = vt + ((size_t)((r0 >> 10) * INNER_D + c0)) * S_LEN + s0;
#pragma unroll
  for (int c = 0; c < 4; c++) {
    uint4 wv4 = {vt_pack[c][0], vt_pack[c][1], vt_pack[c][2], vt_pack[c][3]};
    *(uint4*)(vtb + (size_t)c * S_LEN) = wv4;
  }
}

// ---------------- gates as skinny MFMA GEMM, K-split x2: 256 blocks ----------------
// block 2i+h: rows [16i,16i+16), K half h (1536 each); outputs to half-offset buffers.
__global__ __launch_bounds__(256) void gates_mfma_kernel(
    const u16* __restrict__ q, const u16* __restrict__ k, const u16* __restrict__ v,
    const u16* __restrict__ whi, const u16* __restrict__ wlo,
    const float* __restrict__ igb, const float* __restrict__ fgb,
    float* __restrict__ ig, float* __restrict__ fg)
{
  const int blk2 = blockIdx.x;     // 0..255
  const int blk = blk2 >> 1, half = blk2 & 1;
  const int tid = threadIdx.x;
  const int wave = tid >> 6, lane = tid & 63;
  const int lm = lane & 15, lq = lane >> 4;
  const int grow = blk * 16 + lm;
  const u16* parts[3] = {q, k, v};
  f32x4 acc = {};
#pragma unroll 4
  for (int kc = 0; kc < 12; kc++) {
    int k0 = half * 1536 + wave * 384 + kc * 32;
    int part = k0 >> 10;
    int idx = (k0 & 1023) + lq * 8;
    S8 a, bh_, bl_;
    a.q = *(const uint4*)(parts[part] + (size_t)grow * INNER_D + idx);
    bh_.q = *(const uint4*)(whi + (size_t)lm * 3072 + k0 + lq * 8);
    bl_.q = *(const uint4*)(wlo + (size_t)lm * 3072 + k0 + lq * 8);
    __builtin_amdgcn_s_setprio(1);
    acc = __builtin_amdgcn_mfma_f32_16x16x32_bf16(a.v, bh_.v, acc, 0, 0, 0);
    acc = __builtin_amdgcn_mfma_f32_16x16x32_bf16(a.v, bl_.v, acc, 0, 0, 0);
    __builtin_amdgcn_s_setprio(0);
  }
  __shared__ float red[4][16][17];
#pragma unroll
  for (int r = 0; r < 4; r++) red[wave][lq * 4 + r][lm] = acc[r];
  __syncthreads();
  if (wave == 0) {
#pragma unroll
    for (int r = 0; r < 4; r++) {
      int row = lq * 4 + r;
      float sum = red[0][row][lm] + red[1][row][lm] + red[2][row][lm] + red[3][row][lm];
      int growr = blk * 16 + row;
      int b = growr >> 10, s = growr & (S_LEN - 1);
      if (lm < 8) {
        float bias = (half == 0) ? igb[lm] : 0.f;
        ig[half * 16384 + ((size_t)(b * NHEAD + lm) << 10) + s] = sum + bias;
      } else {
        float bias = (half == 0) ? fgb[lm - 8] : 0.f;
        fg[half * 16384 + ((size_t)(b * NHEAD + (lm - 8)) << 10) + s] = sum + bias;
      }
    }
  }
}

// ---------------- 128-q-row (8-wave) split-K MFMA attention + fused scan, 15 jobs/bh --------
// qp = q-tile-pair index (128 rows); k range in 64-t tiles.
__device__ __constant__ int c_qp[15] = {7, 7, 7, 6, 6, 6, 5, 5, 4, 4, 3, 3, 2, 1, 0};
__device__ __constant__ int c_k0[15] = {0, 6,11, 0, 5,10, 0, 6, 0, 5, 0, 4, 0, 0, 0};
__device__ __constant__ int c_k1[15] = {6,11,16, 5,10,14, 6,12, 5,10, 4, 8, 6, 4, 2};
__device__ __constant__ int c_md[15] = {1, 2, 3, 1, 2, 3, 1, 2, 1, 2, 1, 2, 0, 0, 0};

#define HP_SLOT 1310720   // 16 bh * 5 qr * 128 rows * 128
#define SC_SLOT 10240     // 16 bh * 5 qr * 128 rows

__global__ __launch_bounds__(512) void attn_mfma_kernel(
    const u16* __restrict__ qhg, const u16* __restrict__ khg, const u16* __restrict__ vtg,
    const float* __restrict__ ig_arr, const float* __restrict__ fg_arr,
    const float* __restrict__ xc, const u16* __restrict__ zh,
    const float* __restrict__ skip, const float* __restrict__ onw,
    u16* __restrict__ hs, float* __restrict__ hpart, float* __restrict__ scpart,
    float* __restrict__ enmp)
{
  const int bh = blockIdx.x;
  const int job = blockIdx.y;
  const int qp = c_qp[job], k0t = c_k0[job], k1t = c_k1[job], mode = c_md[job];
  const int b = bh >> 3, h = bh & 7;
  const int s0 = qp * 128;
  const int tid = threadIdx.x;
  const int wave = tid >> 6, lane = tid & 63;
  const int lm = lane & 15, lq = lane >> 4;
  const size_t rowbase = (size_t)b * S_LEN;
  const int c0 = h * DHEAD;

  __shared__ u16 Ks0[64 * 128], Ks1[64 * 128], Ks2[64 * 128];  // [t][128], XOR-swizzled (t&7)
  __shared__ u16 Vt0[128 * 64], Vt1[128 * 64], Vt2[128 * 64];  // [d][64],  XOR-swizzled (d&7)
  __shared__ u16 Ws[128 * 72];
  __shared__ float sa[1024];                    // exp(a)
  __shared__ float sws[16], swm[16];
  __shared__ float srm[128], senm[128];

  // Q fragment loads first (drained by scan's compiler waits before PREFs are issued)
  short8 aq[4];
  {
    const u16* qpp = qhg + (rowbase + s0 + wave * 16 + lm) * INNER_D + c0 + lq * 8;
#pragma unroll
    for (int kc = 0; kc < 4; kc++) {
      S8 tmp; tmp.q = *(const uint4*)(qpp + kc * 32);
      aq[kc] = tmp.v;
    }
  }

  // ---- fused per-bh scan (bitwise port of scan_kernel; 16 virtual waves over 512 threads) ----
  {
    float vsc[2], igv[2], css[2], msc[2];
#pragma unroll
    for (int c = 0; c < 2; c++) {
      int vt = c * 512 + tid;
      size_t o = ((size_t)bh << 10) + vt;
      float f = fg_arr[o] + fg_arr[16384 + o];
      igv[c] = ig_arr[o] + ig_arr[16384 + o];
      float lf = (f >= 0.f) ? -log1pf(__expf(-f)) : f - log1pf(__expf(f));
      float v = lf;
#pragma unroll
      for (int off = 1; off < 64; off <<= 1) {
        float u = __shfl_up(v, off);
        if (lane >= off) v += u;
      }
      if (lane == 63) sws[c * 8 + (tid >> 6)] = v;
      vsc[c] = v;
    }
    __syncthreads();
#pragma unroll
    for (int c = 0; c < 2; c++) {
      int vt = c * 512 + tid;
      int wvv = c * 8 + (tid >> 6);
      float pre = 0.f;
      for (int u = 0; u < wvv; u++) pre += sws[u];
      float cs = vsc[c] + pre;
      float av = igv[c] - cs;
      sa[vt] = __expf(av);
      float m = av;
#pragma unroll
      for (int off = 1; off < 64; off <<= 1) {
        float u = __shfl_up(m, off);
        if (lane >= off) m = fmaxf(m, u);
      }
      if (lane == 63) swm[wvv] = m;
      css[c] = cs; msc[c] = m;
    }
    __syncthreads();
#pragma unroll
    for (int c = 0; c < 2; c++) {
      int vt = c * 512 + tid;
      int wvv = c * 8 + (tid >> 6);
      float pm = -3.4e38f;
      for (int u = 0; u < wvv; u++) pm = fmaxf(pm, swm[u]);
      float rmx = fmaxf(msc[c], pm);
      if (vt >= s0 && vt < s0 + 128) {
        srm[vt - s0] = rmx;
        senm[vt - s0] = __expf(-(css[c] + rmx));
      }
    }
    __syncthreads();
  }

  const float scale = 0.08838834764831845f;  // 1/sqrt(128)
  float rmv[4], er[4];
#pragma unroll
  for (int r = 0; r < 4; r++) {
    rmv[r] = srm[wave * 16 + lq * 4 + r];
    er[r] = scale * __expf(-rmv[r]);   // hoisted: exp(a-rm) = exp(a)*exp(-rm)
  }

  // bf16 ones vector for MFMA row-sum (sc = P @ 1)
  S8 onesu;
#pragma unroll
  for (int j = 0; j < 8; j++) onesu.u[j] = 0x3F80;
  const short8 ones8 = onesu.v;

  f32x4 accH[8] = {};
  f32x4 accS = {};
  const int lr16 = lane >> 4;      // 0..3 (K rows: 256B each, 16 lanes/row)
  const int ls16 = lane & 15;      // 16B slot within 256B K row
  const int lr8 = lane >> 3;       // 0..7  (V rows: 128B each, 8 lanes/row)
  const int cgv = (lane & 7) ^ lr8;  // pre-swizzled V source slot
  const u16* vtbase = vtg + ((size_t)b * INNER_D + c0) * S_LEN;

// 8 waves: each stages 2 K block-rows + 2 V block-rows (4 vmcnt ops/wave)
#define PREF(KS, VS, T0) do { \
  _Pragma("unroll") for (int j = 0; j < 2; j++) { \
    int rK = (wave * 2 + j) * 4 + lr16; \
    int cgk = ls16 ^ (rK & 7); \
    gload16(khg + (rowbase + (T0) + rK) * INNER_D + c0 + cgk * 8, &KS[(wave * 2 + j) * 512]); \
  } \
  _Pragma("unroll") for (int j = 0; j < 2; j++) { \
    int rV = (wave * 2 + j) * 8 + lr8; \
    gload16(vtbase + (size_t)rV * S_LEN + (T0) + cgv * 8, &VS[(wave * 2 + j) * 512]); \
  } \
} while (0)

#define QK_STEP(KS, PACC) do { \
  __builtin_amdgcn_s_setprio(1); \
  _Pragma("unroll") for (int kc = 0; kc < 4; kc++) \
    _Pragma("unroll") for (int cb = 0; cb < 4; cb++) { \
      short8 bk = *(const short8*)&KS[(cb * 16 + lm) * 128 + (((kc * 4 + lq) ^ (lm & 7)) * 8)]; \
      PACC[cb] = __builtin_amdgcn_mfma_f32_16x16x32_bf16(aq[kc], bk, PACC[cb], 0, 0, 0); \
    } \
  __builtin_amdgcn_s_setprio(0); \
} while (0)

// msk: block-uniform — causal cndmask only on tiles with T0 >= s0; exp(a) from LDS
#define W_PV(VT, T0, PACC, MSK) do { \
  _Pragma("unroll") for (int cb = 0; cb < 4; cb++) { \
    float ec = sa[(T0) + cb * 16 + lm]; \
    _Pragma("unroll") for (int r = 0; r < 4; r++) { \
      float wv = PACC[cb][r] * ec * er[r]; \
      if (MSK) { \
        int colg = (T0) + cb * 16 + lm; \
        int rowg = s0 + wave * 16 + lq * 4 + r; \
        if (colg > rowg) wv = 0.f; \
      } \
      Ws[(wave * 16 + lq * 4 + r) * 72 + cb * 16 + lm] = f2bf(wv); \
    } \
  } \
  __builtin_amdgcn_s_setprio(1); \
  _Pragma("unroll") for (int kc = 0; kc < 2; kc++) { \
    short8 aw = *(const short8*)&Ws[(wave * 16 + lm) * 72 + kc * 32 + lq * 8]; \
    accS = __builtin_amdgcn_mfma_f32_16x16x32_bf16(aw, ones8, accS, 0, 0, 0); \
    _Pragma("unroll") for (int nb = 0; nb < 8; nb++) { \
      short8 bv = *(const short8*)&VT[(nb * 16 + lm) * 64 + (((kc * 4 + lq) ^ (lm & 7)) * 8)]; \
      accH[nb] = __builtin_amdgcn_mfma_f32_16x16x32_bf16(aw, bv, accH[nb], 0, 0, 0); \
    } \
  } \
  __builtin_amdgcn_s_setprio(0); \
} while (0)

// one pipeline phase: buf CUR, prefetch into buf NXT2 (distance 2); 1 barrier
#define PHASE(KC, VC, KN, VN) do { \
  if (kt + 1 < k1t) asm volatile("s_waitcnt vmcnt(4)" ::: "memory"); \
  else              asm volatile("s_waitcnt vmcnt(0)" ::: "memory"); \
  __builtin_amdgcn_sched_barrier(0); \
  __builtin_amdgcn_s_barrier(); \
  f32x4 pacc[4] = {}; \
  QK_STEP(KC, pacc); \
  bool msk = (kt * 64 >= s0); \
  W_PV(VC, kt * 64, pacc, msk); \
  if (kt + 2 < k1t) PREF(KN, VN, (kt + 2) * 64); \
  kt++; \
} while (0)

  int kt = k0t;
  PREF(Ks0, Vt0, kt * 64);
  asm volatile("" ::: "memory");
  if (kt + 1 < k1t) PREF(Ks1, Vt1, (kt + 1) * 64);

  while (true) {
    { PHASE(Ks0, Vt0, Ks2, Vt2); if (kt >= k1t) break; }
    { PHASE(Ks1, Vt1, Ks0, Vt0); if (kt >= k1t) break; }
    { PHASE(Ks2, Vt2, Ks1, Vt1); if (kt >= k1t) break; }
  }
#undef PHASE
#undef PREF
#undef QK_STEP
#undef W_PV

  if (mode != 0) {
    int slot = mode - 1;
    int qr = qp - 3;
    float* Hp = hpart + (size_t)slot * HP_SLOT + ((size_t)(bh * 5 + qr)) * 16384;
    float* sp = scpart + slot * SC_SLOT + (bh * 5 + qr) * 128;
    float* ep = enmp + (bh * 5 + qr) * 128;
#pragma unroll
    for (int r = 0; r < 4; r++) {
      int row = wave * 16 + lq * 4 + r;
      if (lm == 0) {
        sp[row] = accS[r];
        if (slot == 0) ep[row] = senm[row];
      }
#pragma unroll
      for (int nb = 0; nb < 8; nb++)
        Hp[row * 128 + nb * 16 + lm] = accH[nb][r];
    }
    return;
  }

  float inv[4], muv[4], rsv[4];
#pragma unroll
  for (int r = 0; r < 4; r++) {
    int row = wave * 16 + lq * 4 + r;
    float nrm = fmaxf(fabsf(accS[r]), senm[row]);
    inv[r] = 1.f / (nrm + 1e-6f);
  }
#pragma unroll
  for (int r = 0; r < 4; r++) {
    float s = 0.f, qq = 0.f;
#pragma unroll
    for (int nb = 0; nb < 8; nb++) {
      float hv = accH[nb][r] * inv[r];
      accH[nb][r] = hv;
      s += hv; qq += hv * hv;
    }
    s += __shfl_xor(s, 1); s += __shfl_xor(s, 2); s += __shfl_xor(s, 4); s += __shfl_xor(s, 8);
    qq += __shfl_xor(qq, 1); qq += __shfl_xor(qq, 2); qq += __shfl_xor(qq, 4); qq += __shfl_xor(qq, 8);
    float mu = s * (1.f / DHEAD);
    float var = qq * (1.f / DHEAD) - mu * mu;
    muv[r] = mu;
    rsv[r] = rsqrtf(var + 1e-5f);
  }
  float ow[8], sk[8];
#pragma unroll
  for (int nb = 0; nb < 8; nb++) {
    ow[nb] = onw[c0 + nb * 16 + lm];
    sk[nb] = skip[c0 + nb * 16 + lm];
  }
#pragma unroll
  for (int r = 0; r < 4; r++) {
    int rowg = s0 + wave * 16 + lq * 4 + r;
    size_t base = (rowbase + rowg) * INNER_D + c0;
#pragma unroll
    for (int nb = 0; nb < 8; nb++) {
      int d = nb * 16 + lm;
      float xcv = xc[base + d];
      float zv = bf2f(zh[base + d]);
      float hn = (accH[nb][r] - muv[r]) * rsv[r] * ow[nb] + sk[nb] * xcv;
      float o = hn * (zv / (1.f + __expf(-zv)));
      hs[base + d] = f2bf(o);
    }
  }
}

// combine 2..3 partial slots for rows s >= 384; one wave per row (10240 rows).
__global__ __launch_bounds__(256) void attn_combine_kernel(
    const float* __restrict__ hpart, const float* __restrict__ scpart,
    const float* __restrict__ enmp,
    const float* __restrict__ xc, const u16* __restrict__ zh,
    const float* __restrict__ skip, const float* __restrict__ onw,
    u16* __restrict__ hs)
{
  int wave = threadIdx.x >> 6, lane = threadIdx.x & 63;
  int gid = blockIdx.x * 4 + wave;   // 0..10239
  int bh = gid / 640;
  int rr = gid % 640;
  int qr = rr >> 7, row = rr & 127;
  int b = bh >> 3, hh = bh & 7;
  int s = (qr + 3) * 128 + row;
  int nsl = (qr >= 3) ? 3 : 2;       // qp3-5: 2 slots, qp6-7: 3 slots
  size_t off = (((size_t)(bh * 5 + qr)) * 128 + row) * 128 + lane * 2;
  int sidx = (bh * 5 + qr) * 128 + row;
  float hx = 0.f, hy = 0.f, sc = 0.f;
  for (int sl = 0; sl < nsl; sl++) {
    float2 hp = *(const float2*)(hpart + (size_t)sl * HP_SLOT + off);
    hx += hp.x; hy += hp.y;
    sc += scpart[sl * SC_SLOT + sidx];
  }
  float nrm = fmaxf(fabsf(sc), enmp[sidx]);
  float inv = 1.f / (nrm + 1e-6f);
  hx *= inv; hy *= inv;
  float sm = hx + hy, sq = hx * hx + hy * hy;
#pragma unroll
  for (int off2 = 32; off2; off2 >>= 1) { sm += __shfl_xor(sm, off2); sq += __shfl_xor(sq, off2); }
  float mu = sm * (1.f / DHEAD);
  float var = sq * (1.f / DHEAD) - mu * mu;
  float rs = rsqrtf(var + 1e-5f);
  int c0 = hh * DHEAD + lane * 2;
  size_t base = ((size_t)(b * S_LEN + s)) * INNER_D + c0;
  float2 xc2 = *(const float2*)(xc + base);
  ushort2 z2u = *(const ushort2*)(zh + base);
  float z2x = bf2f(z2u.x), z2y = bf2f(z2u.y);
  float skx = skip[c0], sky = skip[c0 + 1];
  float owx = onw[c0],  owy = onw[c0 + 1];
  ushort2 o;
  o.x = f2bf(((hx - mu) * rs * owx + skx * xc2.x) * (z2x / (1.f + __expf(-z2x))));
  o.y = f2bf(((hy - mu) * rs * owy + sky * xc2.y) * (z2y / (1.f + __expf(-z2y))));
  *(ushort2*)(hs + base) = o;
}

extern "C" void kernel_launch(void* const* d_in, const int* in_sizes, int n_in,
                              void* d_out, int out_size, void* d_ws, size_t ws_size,
                              hipStream_t stream)
{
  const float* x_enc   = (const float*)d_in[0];
  const float* x_mark  = (const float*)d_in[1];
  const float* emb_W   = (const float*)d_in[4];
  const float* emb_b   = (const float*)d_in[5];
  const float* ln_w    = (const float*)d_in[6];
  const float* up_W    = (const float*)d_in[7];
  const float* conv_W  = (const float*)d_in[8];
  const float* conv_b  = (const float*)d_in[9];
  const float* q_W     = (const float*)d_in[10];
  const float* k_W     = (const float*)d_in[11];
  const float* v_W     = (const float*)d_in[12];
  const float* ig_W    = (const float*)d_in[13];
  const float* ig_b    = (const float*)d_in[14];
  const float* fg_W    = (const float*)d_in[15];
  const float* fg_b    = (const float*)d_in[16];
  const float* skip_w  = (const float*)d_in[17];
  const float* onorm_w = (const float*)d_in[18];
  const float* down_W  = (const float*)d_in[19];
  const float* post_ln = (const float*)d_in[20];
  const float* head_W  = (const float*)d_in[21];
  const float* head_b  = (const float*)d_in[22];

  float* p = (float*)d_ws;
  float* x    = p; p += 1048576;   // 2048*512 f32
  float* xm   = p; p += 2097152;   // 2048*1024 f32; reused as hsbh bf16 after convqkv
  float* xc   = p; p += 2097152;
  float* igb_ = p; p += 32768;     // 2 K-halves x 16384
  float* fgb_ = p; p += 32768;
  float* enmp = p; p += 16384;     // 16 bh x 5 qr x 128 (padded)
  u16* qhb = (u16*)p; p += 1048576;  // 2048*1024 u16
  u16* khb = (u16*)p; p += 1048576;
  u16* vhb = (u16*)p; p += 1048576;
  u16* zh  = (u16*)p; p += 1048576;  // 2048*1024 u16 (full size)
  u16* xnh = (u16*)p; p += 524288;   // 2048*512 u16
  u16* upWtA = (u16*)p; p += 2097152; // 4 x 2048x512 u16
  u16* dnWtA = (u16*)p; p += 1048576; // 4 x 512x1024 u16
  u16* gtwH = (u16*)p; p += 98304;    // 4 x 16 x 3072 u16
  u16* gtwL = (u16*)p; p += 98304;
  float* hpart = p; p += 3932160;     // 3 slots x 16 bh x 5 qr x 128 x 128 f32
  float* scpart = p; p += 32768;      // 3 slots x 10240 (padded)
  u16* vtg = (u16*)p; p += 1048576;   // 2 x 1024 x 1024 u16 (V^T per layer)
  u16* hsbh = (u16*)xm;

  // one merged prep launch: up/down weight transposes + gates weights + embedding
  prep_kernel<<<4352, 256, 0, stream>>>(
      up_W, upWtA, down_W, dnWtA, ig_W, fg_W, gtwH, gtwL,
      x_enc, x_mark, emb_W, emb_b, x);

  for (int L = 0; L < 4; L++) {
    ln_kernel<<<512, 256, 0, stream>>>(x, ln_w + L * 512, xnh);
    gemm_bf16_split64<<<dim3(16, 16), 256, 0, stream>>>(
        xnh, upWtA + (size_t)L * 1048576, xm, zh, 2048, 2048, 512, 1024, 1024);
    convqkv_kernel<<<256, 256, 0, stream>>>(
        xm, conv_W + L * 4096, conv_b + L * 1024,
        q_W + L * 4096, k_W + L * 4096, v_W + L * 4096,
        xc, qhb, khb, vhb, vtg);
    gates_mfma_kernel<<<256, 256, 0, stream>>>(
        qhb, khb, vhb, gtwH + (size_t)L * 49152, gtwL + (size_t)L * 49152,
        ig_b + L * 8, fg_b + L * 8, igb_, fgb_);
    attn_mfma_kernel<<<dim3(16, 15), 512, 0, stream>>>(
        qhb, khb, vtg, igb_, fgb_, xc, zh,
        skip_w + L * 1024, onorm_w + L * 1024, hsbh, hpart, scpart, enmp);
    attn_combine_kernel<<<2560, 256, 0, stream>>>(
        hpart, scpart, enmp, xc, zh, skip_w + L * 1024, onorm_w + L * 1024, hsbh);
    gemm_bf16_32<<<dim3(8, 32), 256, 0, stream>>>(
        hsbh, dnWtA + (size_t)L * 524288, x, 2048, 512, 1024, 512);
  }

  lnhead_kernel<<<192, 256, 0, stream>>>(x, post_ln, head_W, head_b, (float*)d_out);
}

// Round 15
// 400.108 us; speedup vs baseline: 1.1510x; 1.0228x over previous
//
#include <hip/hip_runtime.h>
#include <hip/hip_bf16.h>

#define S_LEN 1024
#define E_DIM 512
#define INNER_D 1024
#define NHEAD 8
#define DHEAD 128

typedef unsigned short u16;
typedef unsigned int u32;
typedef __attribute__((ext_vector_type(8))) short short8;
typedef __attribute__((ext_vector_type(4))) float f32x4;

union S8 { short8 v; u16 u[8]; uint4 q; };

__device__ __forceinline__ u16 f2bf(float f) {
  u32 u = __float_as_uint(f);
  u32 r = u + 0x7FFFu + ((u >> 16) & 1u);
  return (u16)(r >> 16);
}
__device__ __forceinline__ float bf2f(u16 u) { return __uint_as_float(((u32)u) << 16); }

// direct global -> LDS (16B per lane). LDS dest = wave-uniform base + lane*16B (linear).
__device__ __forceinline__ void gload16(const u16* g, u16* l) {
  __builtin_amdgcn_global_load_lds((const __attribute__((address_space(1))) void*)g,
                                   (__attribute__((address_space(3))) void*)l, 16, 0, 0);
}

// ---------------- merged one-time prep: transposes + gates weights + embedding ----------------
__device__ __forceinline__ void prep_transpose(
    const float* __restrict__ in, u16* __restrict__ out, int K, int N,
    int k0, int n0, int t, u16 (*T)[72])
{
  int kr = t >> 2, nseg = (t & 3) * 16;
  const float* src = in + (size_t)(k0 + kr) * N + n0 + nseg;
#pragma unroll
  for (int j = 0; j < 16; j++) T[kr][nseg + j] = f2bf(src[j]);
  __syncthreads();
  int nr = t >> 2, kseg = (t & 3) * 16;
  u32 u[8];
#pragma unroll
  for (int rr = 0; rr < 8; rr++) {
    u32 lo = T[kseg + 2 * rr][nr];
    u32 hi = T[kseg + 2 * rr + 1][nr];
    u[rr] = lo | (hi << 16);
  }
  u16* dst = out + (size_t)(n0 + nr) * K + k0 + kseg;
  uint4 w0 = {u[0], u[1], u[2], u[3]};
  uint4 w1 = {u[4], u[5], u[6], u[7]};
  *(uint4*)dst = w0;
  *(uint4*)(dst + 8) = w1;
}

__global__ __launch_bounds__(256) void prep_kernel(
    const float* __restrict__ up_W, u16* __restrict__ upWt,
    const float* __restrict__ down_W, u16* __restrict__ dnWt,
    const float* __restrict__ igW, const float* __restrict__ fgW,
    u16* __restrict__ ghi, u16* __restrict__ glo,
    const float* __restrict__ xe, const float* __restrict__ xmk,
    const float* __restrict__ eW, const float* __restrict__ eb,
    float* __restrict__ x)
{
  __shared__ u16 T[64][72];
  __shared__ float in_s[25];
  int id = blockIdx.x;
  int t = threadIdx.x;
  if (id < 1024) {                     // up_W transpose: [L][512][2048] -> [L][2048][512]
    int bx = id & 7, rest = id >> 3;
    int by = rest & 31, L = rest >> 5;
    prep_transpose(up_W + (size_t)L * 512 * 2048, upWt + (size_t)L * 1048576,
                   512, 2048, bx * 64, by * 64, t, T);
  } else if (id < 1536) {              // down_W transpose: [L][1024][512] -> [L][512][1024]
    int id2 = id - 1024;
    int bx = id2 & 15, rest = id2 >> 4;
    int by = rest & 7, L = rest >> 3;
    prep_transpose(down_W + (size_t)L * 1024 * 512, dnWt + (size_t)L * 524288,
                   1024, 512, bx * 64, by * 64, t, T);
  } else if (id < 2304) {              // gates weights: hi/lo split transpose
    int id3 = id - 1536;
    int bx = id3 % 12, rest = id3 / 12;
    int n = rest & 15, L = rest >> 4;
    int k = bx * 256 + t;
    const float* W = ((n < 8) ? igW : fgW) + (size_t)L * 24576;
    float v = W[(size_t)k * 8 + (n & 7)];
    u16 h = f2bf(v);
    u16 l = f2bf(v - bf2f(h));
    size_t o = ((size_t)L * 16 + n) * 3072 + k;
    ghi[o] = h;
    glo[o] = l;
  } else {                             // embedding, one row per block
    int row = id - 2304;
    if (t < 21) in_s[t] = xe[row * 21 + t];
    else if (t < 25) in_s[t] = xmk[row * 4 + t - 21];
    __syncthreads();
#pragma unroll
    for (int rep = 0; rep < 2; rep++) {
      int e = t + rep * 256;
      float acc = eb[e];
#pragma unroll
      for (int i = 0; i < 25; i++) acc += in_s[i] * eW[i * E_DIM + e];
      x[(size_t)row * E_DIM + e] = acc;
    }
  }
}

// ---------------- layernorm -> bf16; one wave per row, 4 rows/block ----------------
__global__ __launch_bounds__(256) void ln_kernel(
    const float* __restrict__ x, const float* __restrict__ w, u16* __restrict__ out)
{
  int row = blockIdx.x * 4 + (threadIdx.x >> 6);
  int lane = threadIdx.x & 63;
  const float* xr = x + (size_t)row * E_DIM + lane * 8;
  float4 a = *(const float4*)xr;
  float4 b = *(const float4*)(xr + 4);
  float s = a.x + a.y + a.z + a.w + b.x + b.y + b.z + b.w;
  float q = a.x * a.x + a.y * a.y + a.z * a.z + a.w * a.w
          + b.x * b.x + b.y * b.y + b.z * b.z + b.w * b.w;
#pragma unroll
  for (int off = 1; off < 64; off <<= 1) { s += __shfl_xor(s, off); q += __shfl_xor(q, off); }
  float mu = s * (1.f / E_DIM);
  float var = q * (1.f / E_DIM) - mu * mu;
  float rs = rsqrtf(var + 1e-5f);
  const float* wr = w + lane * 8;
  S8 o;
  o.u[0] = f2bf((a.x - mu) * rs * wr[0]);
  o.u[1] = f2bf((a.y - mu) * rs * wr[1]);
  o.u[2] = f2bf((a.z - mu) * rs * wr[2]);
  o.u[3] = f2bf((a.w - mu) * rs * wr[3]);
  o.u[4] = f2bf((b.x - mu) * rs * wr[4]);
  o.u[5] = f2bf((b.y - mu) * rs * wr[5]);
  o.u[6] = f2bf((b.z - mu) * rs * wr[6]);
  o.u[7] = f2bf((b.w - mu) * rs * wr[7]);
  *(uint4*)(out + (size_t)row * E_DIM + lane * 8) = o.q;
}

// ---------------- fused final layernorm + head (one block per output row) ----------------
__global__ __launch_bounds__(256) void lnhead_kernel(
    const float* __restrict__ x, const float* __restrict__ w,
    const float* __restrict__ hW, const float* __restrict__ hb,
    float* __restrict__ out)
{
  int ridx = blockIdx.x;
  int b = ridx / 96, r = ridx % 96;
  int row = b * S_LEN + (S_LEN - 96) + r;
  int tid = threadIdx.x;
  const float* xr = x + (size_t)row * E_DIM;
  float2 v = *(const float2*)(xr + tid * 2);
  float s = v.x + v.y, q = v.x * v.x + v.y * v.y;
#pragma unroll
  for (int off = 32; off; off >>= 1) { s += __shfl_xor(s, off); q += __shfl_xor(q, off); }
  __shared__ float ssum[4], ssq[4];
  __shared__ float lnv[512];
  __shared__ float part[8][32];
  int wv = tid >> 6;
  if ((tid & 63) == 0) { ssum[wv] = s; ssq[wv] = q; }
  __syncthreads();
  s = ssum[0] + ssum[1] + ssum[2] + ssum[3];
  q = ssq[0] + ssq[1] + ssq[2] + ssq[3];
  float mu = s * (1.f / E_DIM);
  float var = q * (1.f / E_DIM) - mu * mu;
  float rs = rsqrtf(var + 1e-5f);
  int e = tid * 2;
  lnv[e]     = (v.x - mu) * rs * w[e];
  lnv[e + 1] = (v.y - mu) * rs * w[e + 1];
  __syncthreads();
  int n = tid & 31, sl = tid >> 5;
  float p = 0.f;
  if (n < 21) {
#pragma unroll 8
    for (int kk = 0; kk < 64; kk++)
      p += lnv[sl * 64 + kk] * hW[(sl * 64 + kk) * 21 + n];
  }
  part[sl][n] = p;
  __syncthreads();
  if (tid < 21) {
    float acc = hb[tid];
#pragma unroll
    for (int j = 0; j < 8; j++) acc += part[j][tid];
    out[ridx * 21 + tid] = acc;
  }
}

// ---------------- bf16 MFMA GEMM 128x64, BK=64, 3-buf distance-2, 2 blocks/CU ---------------
// split C: C0 f32, C1 bf16; grid (N/64=32, M/128=16) = 512 blocks. K must be 512 (NT=8).
__global__ __launch_bounds__(256) void gemm_bf16_split64(
    const u16* __restrict__ A, const u16* __restrict__ Bt,
    float* __restrict__ C0, u16* __restrict__ C1,
    int M, int N, int K, int split_col, int ldc)
{
  __shared__ u16 As0[128 * 64], As1[128 * 64], As2[128 * 64];
  __shared__ u16 Bs0[64 * 64], Bs1[64 * 64], Bs2[64 * 64];
  const int tid = threadIdx.x;
  const int row0 = blockIdx.y * 128, col0 = blockIdx.x * 64;
  const int wave = tid >> 6, lane = tid & 63;
  const int wr = wave >> 1, wc = wave & 1;   // wave tile: 64 rows x 32 cols
  const int lm = lane & 15, lq = lane >> 4;
  const int lr8 = lane >> 3;                 // 0..7 row within 8-row group
  const int cg8 = (lane & 7) ^ lr8;          // pre-swizzled source 16B slot (8 slots/row)
  f32x4 acc[4][2] = {};
  const u16* Abase = A + (size_t)(row0 + lr8) * K + cg8 * 8;
  const u16* Bbase = Bt + (size_t)(col0 + lr8) * K + cg8 * 8;
  const int key = lm & 7;

#define STG_UP(AS, BS, K0) do { \
  _Pragma("unroll") for (int i = 0; i < 4; i++) \
    gload16(Abase + (size_t)((wave * 4 + i) * 8) * K + (K0), &AS[(wave * 4 + i) * 512]); \
  _Pragma("unroll") for (int i = 0; i < 2; i++) \
    gload16(Bbase + (size_t)((wave * 2 + i) * 8) * K + (K0), &BS[(wave * 2 + i) * 512]); \
} while (0)

#define CMP_UP(AS, BS) do { \
  _Pragma("unroll") for (int kc = 0; kc < 2; kc++) { \
    short8 af[4], bfv[2]; \
    _Pragma("unroll") for (int i = 0; i < 4; i++) \
      af[i] = *(const short8*)&AS[(wr * 64 + i * 16 + lm) * 64 + (((kc * 4 + lq) ^ key) * 8)]; \
    _Pragma("unroll") for (int j = 0; j < 2; j++) \
      bfv[j] = *(const short8*)&BS[(wc * 32 + j * 16 + lm) * 64 + (((kc * 4 + lq) ^ key) * 8)]; \
    _Pragma("unroll") for (int i = 0; i < 4; i++) \
      _Pragma("unroll") for (int j = 0; j < 2; j++) \
        acc[i][j] = __builtin_amdgcn_mfma_f32_16x16x32_bf16(af[i], bfv[j], acc[i][j], 0, 0, 0); \
  } \
} while (0)

  STG_UP(As0, Bs0, 0);
  asm volatile("" ::: "memory");
  STG_UP(As1, Bs1, 64);
  // distance-2 prefetch: write target = buffer read 2 stages ago; 1 barrier/stage
#pragma unroll
  for (int t = 0; t < 8; t++) {
    if (t < 7) asm volatile("s_waitcnt vmcnt(6)" ::: "memory");
    else       asm volatile("s_waitcnt vmcnt(0)" ::: "memory");
    __builtin_amdgcn_sched_barrier(0);
    __builtin_amdgcn_s_barrier();
    if ((t % 3) == 0)      CMP_UP(As0, Bs0);
    else if ((t % 3) == 1) CMP_UP(As1, Bs1);
    else                   CMP_UP(As2, Bs2);
    if (t + 2 < 8) {
      if (((t + 2) % 3) == 0)      STG_UP(As0, Bs0, (t + 2) * 64);
      else if (((t + 2) % 3) == 1) STG_UP(As1, Bs1, (t + 2) * 64);
      else                         STG_UP(As2, Bs2, (t + 2) * 64);
    }
  }
#undef STG_UP
#undef CMP_UP

  const bool toC1 = (col0 >= split_col);
#pragma unroll
  for (int i = 0; i < 4; i++) {
#pragma unroll
    for (int j = 0; j < 2; j++) {
      int col = col0 - (toC1 ? split_col : 0) + wc * 32 + j * 16 + lm;
#pragma unroll
      for (int r = 0; r < 4; r++) {
        int row = row0 + wr * 64 + i * 16 + lq * 4 + r;
        if (toC1) C1[(size_t)row * ldc + col] = f2bf(acc[i][j][r]);
        else C0[(size_t)row * ldc + col] = acc[i][j][r];
      }
    }
  }
}

// ---------------- bf16 MFMA GEMM 64x32 (down-proj, +=), BK=128, 3-buf dist-2, 2 blocks/CU ----
// grid (N/32=16, M/64=32) = 512 blocks. K must be 1024 (NT=8).
__global__ __launch_bounds__(256) void gemm_bf16_32(
    const u16* __restrict__ A, const u16* __restrict__ Bt,
    float* __restrict__ C, int M, int N, int K, int ldc)
{
  __shared__ u16 As0[64 * 128], As1[64 * 128], As2[64 * 128];
  __shared__ u16 Bs0[32 * 128], Bs1[32 * 128], Bs2[32 * 128];
  const int tid = threadIdx.x;
  const int row0 = blockIdx.y * 64, col0 = blockIdx.x * 32;
  const int wave = tid >> 6, lane = tid & 63;
  const int wr = wave >> 1, wc = wave & 1;   // wave tile: 32 rows x 16 cols
  const int lm = lane & 15, lq = lane >> 4;
  const int lr16 = lane >> 4;                // 0..3 row within 4-row group (256B rows)
  const int ls16 = lane & 15;                // 16B slot within row (16 slots)
  f32x4 acc[2] = {};

#define STAGE_DN(AS, BS, K0) do { \
  _Pragma("unroll") for (int i = 0; i < 4; i++) { \
    int rA = (wave * 4 + i) * 4 + lr16; \
    int cgk = ls16 ^ (rA & 15); \
    gload16(A + (size_t)(row0 + rA) * K + (K0) + cgk * 8, &AS[(wave * 4 + i) * 512]); \
  } \
  _Pragma("unroll") for (int i = 0; i < 2; i++) { \
    int rB = (wave * 2 + i) * 4 + lr16; \
    int cgk = ls16 ^ (rB & 15); \
    gload16(Bt + (size_t)(col0 + rB) * K + (K0) + cgk * 8, &BS[(wave * 2 + i) * 512]); \
  } \
} while (0)

#define COMPUTE_DN(AS, BS) do { \
  _Pragma("unroll") for (int kc = 0; kc < 4; kc++) { \
    short8 af[2], bfv; \
    _Pragma("unroll") for (int i = 0; i < 2; i++) \
      af[i] = *(const short8*)&AS[(wr * 32 + i * 16 + lm) * 128 + (((kc * 4 + lq) ^ lm) * 8)]; \
    bfv = *(const short8*)&BS[(wc * 16 + lm) * 128 + (((kc * 4 + lq) ^ lm) * 8)]; \
    _Pragma("unroll") for (int i = 0; i < 2; i++) \
      acc[i] = __builtin_amdgcn_mfma_f32_16x16x32_bf16(af[i], bfv, acc[i], 0, 0, 0); \
  } \
} while (0)

  STAGE_DN(As0, Bs0, 0);
  asm volatile("" ::: "memory");
  STAGE_DN(As1, Bs1, 128);
  // distance-2 prefetch, 1 barrier/stage
#pragma unroll
  for (int t = 0; t < 8; t++) {
    if (t < 7) asm volatile("s_waitcnt vmcnt(6)" ::: "memory");
    else       asm volatile("s_waitcnt vmcnt(0)" ::: "memory");
    __builtin_amdgcn_sched_barrier(0);
    __builtin_amdgcn_s_barrier();
    if ((t % 3) == 0)      COMPUTE_DN(As0, Bs0);
    else if ((t % 3) == 1) COMPUTE_DN(As1, Bs1);
    else                   COMPUTE_DN(As2, Bs2);
    if (t + 2 < 8) {
      if (((t + 2) % 3) == 0)      STAGE_DN(As0, Bs0, (t + 2) * 128);
      else if (((t + 2) % 3) == 1) STAGE_DN(As1, Bs1, (t + 2) * 128);
      else                         STAGE_DN(As2, Bs2, (t + 2) * 128);
    }
  }
#undef STAGE_DN
#undef COMPUTE_DN

#pragma unroll
  for (int i = 0; i < 2; i++) {
    int col = col0 + wc * 16 + lm;
#pragma unroll
    for (int r = 0; r < 4; r++) {
      int row = row0 + wr * 32 + i * 16 + lq * 4 + r;
      C[(size_t)row * ldc + col] += acc[i][r];
    }
  }
}

// ---------------- fused causal conv+SiLU+headwise qkv; 8 rows/block; writes V and V^T -------
__global__ __launch_bounds__(256) void convqkv_kernel(
    const float* __restrict__ xm,
    const float* __restrict__ cw, const float* __restrict__ cb,
    const float* __restrict__ qw, const float* __restrict__ kw, const float* __restrict__ vw,
    float* __restrict__ xc, u16* __restrict__ q, u16* __restrict__ k, u16* __restrict__ v,
    u16* __restrict__ vt)
{
  int r0 = blockIdx.x * 8;         // rows r0..r0+7, same batch (S_LEN % 8 == 0)
  int s0 = r0 & (S_LEN - 1);
  int g = threadIdx.x;             // channel group of 4
  int c0 = g * 4;
  const float* base = xm + (size_t)r0 * INNER_D + c0;

  float4 xv[11];
#pragma unroll
  for (int j = 0; j < 11; j++) {
    int ts = s0 - 3 + j;
    float4 t = {0.f, 0.f, 0.f, 0.f};
    if (ts >= 0) t = *(const float4*)(base + (ptrdiff_t)(j - 3) * INNER_D);
    xv[j] = t;
  }
  float cwv[4][4];
#pragma unroll
  for (int c = 0; c < 4; c++)
#pragma unroll
    for (int kk = 0; kk < 4; kk++) cwv[c][kk] = cw[(c0 + c) * 4 + kk];
  float cbv[4] = {cb[c0], cb[c0 + 1], cb[c0 + 2], cb[c0 + 3]};
  const float* qg = qw + g * 16;
  const float* kg = kw + g * 16;
  const float* vg = vw + g * 16;
  float qwv[16], kwv[16], vwv[16];
#pragma unroll
  for (int i = 0; i < 16; i++) { qwv[i] = qg[i]; kwv[i] = kg[i]; vwv[i] = vg[i]; }

  u32 vt_pack[4][4];   // [channel][s-pair] fully static indexing

#pragma unroll
  for (int i = 0; i < 8; i++) {
    float a0 = cbv[0], a1 = cbv[1], a2 = cbv[2], a3 = cbv[3];
#pragma unroll
    for (int kk = 0; kk < 4; kk++) {
      float4 xvv = xv[i + kk];
      a0 += xvv.x * cwv[0][kk];
      a1 += xvv.y * cwv[1][kk];
      a2 += xvv.z * cwv[2][kk];
      a3 += xvv.w * cwv[3][kk];
    }
    a0 = a0 / (1.f + __expf(-a0));
    a1 = a1 / (1.f + __expf(-a1));
    a2 = a2 / (1.f + __expf(-a2));
    a3 = a3 / (1.f + __expf(-a3));
    float4 accv = {a0, a1, a2, a3};
    *(float4*)(xc + (size_t)(r0 + i) * INNER_D + c0) = accv;

    float xcv[4] = {a0, a1, a2, a3};
    float xmv[4] = {xv[i + 3].x, xv[i + 3].y, xv[i + 3].z, xv[i + 3].w};
    ushort4 qs, ks, vs;
    u16* qp = (u16*)&qs; u16* kp = (u16*)&ks; u16* vp = (u16*)&vs;
#pragma unroll
    for (int o = 0; o < 4; o++) {
      float aq = 0.f, ak = 0.f, av = 0.f;
#pragma unroll
      for (int d = 0; d < 4; d++) {
        aq += xcv[d] * qwv[o * 4 + d];
        ak += xcv[d] * kwv[o * 4 + d];
        av += xmv[d] * vwv[o * 4 + d];
      }
      qp[o] = f2bf(aq); kp[o] = f2bf(ak);
      u16 vv = f2bf(av);
      vp[o] = vv;
      if ((i & 1) == 0) vt_pack[o][i >> 1] = (u32)vv;
      else              vt_pack[o][i >> 1] |= ((u32)vv) << 16;
    }
    size_t off = (size_t)(r0 + i) * INNER_D + c0;
    *(ushort4*)(q + off) = qs;
    *(ushort4*)(k + off) = ks;
    *(ushort4*)(v + off) = vs;
  }
  // V^T: vt[b][d][s], 16B (8 s-values) per channel
  u16* vtb = vt + ((size_t)((r0 >> 10) * INNER_D + c0)) * S_LEN + s0;
#pragma unroll
  for (int c = 0; c < 4; c++) {
    uint4 wv4 = {vt_pack[c][0], vt_pack[c][1], vt_pack[c][2], vt_pack[c][3]};
    *(uint4*)(vtb + (size_t)c * S_LEN) = wv4;
  }
}

// ---------------- gates as skinny MFMA GEMM, K-split x2: 256 blocks ----------------
// block 2i+h: rows [16i,16i+16), K half h (1536 each); outputs to half-offset buffers.
__global__ __launch_bounds__(256) void gates_mfma_kernel(
    const u16* __restrict__ q, const u16* __restrict__ k, const u16* __restrict__ v,
    const u16* __restrict__ whi, const u16* __restrict__ wlo,
    const float* __restrict__ igb, const float* __restrict__ fgb,
    float* __restrict__ ig, float* __restrict__ fg)
{
  const int blk2 = blockIdx.x;     // 0..255
  const int blk = blk2 >> 1, half = blk2 & 1;
  const int tid = threadIdx.x;
  const int wave = tid >> 6, lane = tid & 63;
  const int lm = lane & 15, lq = lane >> 4;
  const int grow = blk * 16 + lm;
  const u16* parts[3] = {q, k, v};
  f32x4 acc = {};
#pragma unroll 4
  for (int kc = 0; kc < 12; kc++) {
    int k0 = half * 1536 + wave * 384 + kc * 32;
    int part = k0 >> 10;
    int idx = (k0 & 1023) + lq * 8;
    S8 a, bh_, bl_;
    a.q = *(const uint4*)(parts[part] + (size_t)grow * INNER_D + idx);
    bh_.q = *(const uint4*)(whi + (size_t)lm * 3072 + k0 + lq * 8);
    bl_.q = *(const uint4*)(wlo + (size_t)lm * 3072 + k0 + lq * 8);
    __builtin_amdgcn_s_setprio(1);
    acc = __builtin_amdgcn_mfma_f32_16x16x32_bf16(a.v, bh_.v, acc, 0, 0, 0);
    acc = __builtin_amdgcn_mfma_f32_16x16x32_bf16(a.v, bl_.v, acc, 0, 0, 0);
    __builtin_amdgcn_s_setprio(0);
  }
  __shared__ float red[4][16][17];
#pragma unroll
  for (int r = 0; r < 4; r++) red[wave][lq * 4 + r][lm] = acc[r];
  __syncthreads();
  if (wave == 0) {
#pragma unroll
    for (int r = 0; r < 4; r++) {
      int row = lq * 4 + r;
      float sum = red[0][row][lm] + red[1][row][lm] + red[2][row][lm] + red[3][row][lm];
      int growr = blk * 16 + row;
      int b = growr >> 10, s = growr & (S_LEN - 1);
      if (lm < 8) {
        float bias = (half == 0) ? igb[lm] : 0.f;
        ig[half * 16384 + ((size_t)(b * NHEAD + lm) << 10) + s] = sum + bias;
      } else {
        float bias = (half == 0) ? fgb[lm - 8] : 0.f;
        fg[half * 16384 + ((size_t)(b * NHEAD + (lm - 8)) << 10) + s] = sum + bias;
      }
    }
  }
}

// ---------------- 128-q-row (8-wave) split-K MFMA attention + fused scan, 15 jobs/bh --------
// qp = q-tile-pair index (128 rows); k range in 64-t tiles.
__device__ __constant__ int c_qp[15] = {7, 7, 7, 6, 6, 6, 5, 5, 4, 4, 3, 3, 2, 1, 0};
__device__ __constant__ int c_k0[15] = {0, 6,11, 0, 5,10, 0, 6, 0, 5, 0, 4, 0, 0, 0};
__device__ __constant__ int c_k1[15] = {6,11,16, 5,10,14, 6,12, 5,10, 4, 8, 6, 4, 2};
__device__ __constant__ int c_md[15] = {1, 2, 3, 1, 2, 3, 1, 2, 1, 2, 1, 2, 0, 0, 0};

#define HP_SLOT 1310720   // 16 bh * 5 qr * 128 rows * 128
#define SC_SLOT 10240     // 16 bh * 5 qr * 128 rows

__global__ __launch_bounds__(512) void attn_mfma_kernel(
    const u16* __restrict__ qhg, const u16* __restrict__ khg, const u16* __restrict__ vtg,
    const float* __restrict__ ig_arr, const float* __restrict__ fg_arr,
    const float* __restrict__ xc, const u16* __restrict__ zh,
    const float* __restrict__ skip, const float* __restrict__ onw,
    u16* __restrict__ hs, float* __restrict__ hpart, float* __restrict__ scpart,
    float* __restrict__ enmp)
{
  const int bh = blockIdx.x;
  const int job = blockIdx.y;
  const int qp = c_qp[job], k0t = c_k0[job], k1t = c_k1[job], mode = c_md[job];
  const int b = bh >> 3, h = bh & 7;
  const int s0 = qp * 128;
  const int tid = threadIdx.x;
  const int wave = tid >> 6, lane = tid & 63;
  const int lm = lane & 15, lq = lane >> 4;
  const size_t rowbase = (size_t)b * S_LEN;
  const int c0 = h * DHEAD;

  __shared__ u16 Ks0[64 * 128], Ks1[64 * 128], Ks2[64 * 128];  // [t][128], XOR-swizzled (t&7)
  __shared__ u16 Vt0[128 * 64], Vt1[128 * 64], Vt2[128 * 64];  // [d][64],  XOR-swizzled (d&7)
  __shared__ u16 Ws[128 * 72];
  __shared__ float sa[1024];                    // exp(a)
  __shared__ float sws[16], swm[16];
  __shared__ float srm[128], senm[128];

  // Q fragment loads first (drained by scan's compiler waits before PREFs are issued)
  short8 aq[4];
  {
    const u16* qpp = qhg + (rowbase + s0 + wave * 16 + lm) * INNER_D + c0 + lq * 8;
#pragma unroll
    for (int kc = 0; kc < 4; kc++) {
      S8 tmp; tmp.q = *(const uint4*)(qpp + kc * 32);
      aq[kc] = tmp.v;
    }
  }

  // ---- fused per-bh scan (bitwise port of scan_kernel; 16 virtual waves over 512 threads) ----
  {
    float vsc[2], igv[2], css[2], msc[2];
#pragma unroll
    for (int c = 0; c < 2; c++) {
      int vt = c * 512 + tid;
      size_t o = ((size_t)bh << 10) + vt;
      float f = fg_arr[o] + fg_arr[16384 + o];
      igv[c] = ig_arr[o] + ig_arr[16384 + o];
      float lf = (f >= 0.f) ? -log1pf(__expf(-f)) : f - log1pf(__expf(f));
      float v = lf;
#pragma unroll
      for (int off = 1; off < 64; off <<= 1) {
        float u = __shfl_up(v, off);
        if (lane >= off) v += u;
      }
      if (lane == 63) sws[c * 8 + (tid >> 6)] = v;
      vsc[c] = v;
    }
    __syncthreads();
#pragma unroll
    for (int c = 0; c < 2; c++) {
      int vt = c * 512 + tid;
      int wvv = c * 8 + (tid >> 6);
      float pre = 0.f;
      for (int u = 0; u < wvv; u++) pre += sws[u];
      float cs = vsc[c] + pre;
      float av = igv[c] - cs;
      sa[vt] = __expf(av);
      float m = av;
#pragma unroll
      for (int off = 1; off < 64; off <<= 1) {
        float u = __shfl_up(m, off);
        if (lane >= off) m = fmaxf(m, u);
      }
      if (lane == 63) swm[wvv] = m;
      css[c] = cs; msc[c] = m;
    }
    __syncthreads();
#pragma unroll
    for (int c = 0; c < 2; c++) {
      int vt = c * 512 + tid;
      int wvv = c * 8 + (tid >> 6);
      float pm = -3.4e38f;
      for (int u = 0; u < wvv; u++) pm = fmaxf(pm, swm[u]);
      float rmx = fmaxf(msc[c], pm);
      if (vt >= s0 && vt < s0 + 128) {
        srm[vt - s0] = rmx;
        senm[vt - s0] = __expf(-(css[c] + rmx));
      }
    }
    __syncthreads();
  }

  const float scale = 0.08838834764831845f;  // 1/sqrt(128)
  float rmv[4], er[4];
#pragma unroll
  for (int r = 0; r < 4; r++) {
    rmv[r] = srm[wave * 16 + lq * 4 + r];
    er[r] = scale * __expf(-rmv[r]);   // hoisted: exp(a-rm) = exp(a)*exp(-rm)
  }

  // bf16 ones vector for MFMA row-sum (sc = P @ 1)
  S8 onesu;
#pragma unroll
  for (int j = 0; j < 8; j++) onesu.u[j] = 0x3F80;
  const short8 ones8 = onesu.v;

  f32x4 accH[8] = {};
  f32x4 accS = {};
  const int lr16 = lane >> 4;      // 0..3 (K rows: 256B each, 16 lanes/row)
  const int ls16 = lane & 15;      // 16B slot within 256B K row
  const int lr8 = lane >> 3;       // 0..7  (V rows: 128B each, 8 lanes/row)
  const int cgv = (lane & 7) ^ lr8;  // pre-swizzled V source slot
  const u16* vtbase = vtg + ((size_t)b * INNER_D + c0) * S_LEN;

// 8 waves: each stages 2 K block-rows + 2 V block-rows (4 vmcnt ops/wave)
#define PREF(KS, VS, T0) do { \
  _Pragma("unroll") for (int j = 0; j < 2; j++) { \
    int rK = (wave * 2 + j) * 4 + lr16; \
    int cgk = ls16 ^ (rK & 7); \
    gload16(khg + (rowbase + (T0) + rK) * INNER_D + c0 + cgk * 8, &KS[(wave * 2 + j) * 512]); \
  } \
  _Pragma("unroll") for (int j = 0; j < 2; j++) { \
    int rV = (wave * 2 + j) * 8 + lr8; \
    gload16(vtbase + (size_t)rV * S_LEN + (T0) + cgv * 8, &VS[(wave * 2 + j) * 512]); \
  } \
} while (0)

#define QK_STEP(KS, PACC) do { \
  __builtin_amdgcn_s_setprio(1); \
  _Pragma("unroll") for (int kc = 0; kc < 4; kc++) \
    _Pragma("unroll") for (int cb = 0; cb < 4; cb++) { \
      short8 bk = *(const short8*)&KS[(cb * 16 + lm) * 128 + (((kc * 4 + lq) ^ (lm & 7)) * 8)]; \
      PACC[cb] = __builtin_amdgcn_mfma_f32_16x16x32_bf16(aq[kc], bk, PACC[cb], 0, 0, 0); \
    } \
  __builtin_amdgcn_s_setprio(0); \
} while (0)

// msk: block-uniform — causal cndmask only on tiles with T0 >= s0; exp(a) from LDS
#define W_PV(VT, T0, PACC, MSK) do { \
  _Pragma("unroll") for (int cb = 0; cb < 4; cb++) { \
    float ec = sa[(T0) + cb * 16 + lm]; \
    _Pragma("unroll") for (int r = 0; r < 4; r++) { \
      float wv = PACC[cb][r] * ec * er[r]; \
      if (MSK) { \
        int colg = (T0) + cb * 16 + lm; \
        int rowg = s0 + wave * 16 + lq * 4 + r; \
        if (colg > rowg) wv = 0.f; \
      } \
      Ws[(wave * 16 + lq * 4 + r) * 72 + cb * 16 + lm] = f2bf(wv); \
    } \
  } \
  __builtin_amdgcn_s_setprio(1); \
  _Pragma("unroll") for (int kc = 0; kc < 2; kc++) { \
    short8 aw = *(const short8*)&Ws[(wave * 16 + lm) * 72 + kc * 32 + lq * 8]; \
    accS = __builtin_amdgcn_mfma_f32_16x16x32_bf16(aw, ones8, accS, 0, 0, 0); \
    _Pragma("unroll") for (int nb = 0; nb < 8; nb++) { \
      short8 bv = *(const short8*)&VT[(nb * 16 + lm) * 64 + (((kc * 4 + lq) ^ (lm & 7)) * 8)]; \
      accH[nb] = __builtin_amdgcn_mfma_f32_16x16x32_bf16(aw, bv, accH[nb], 0, 0, 0); \
    } \
  } \
  __builtin_amdgcn_s_setprio(0); \
} while (0)

// one pipeline phase: buf CUR, prefetch into buf NXT2 (distance 2); 1 barrier
#define PHASE(KC, VC, KN, VN) do { \
  if (kt + 1 < k1t) asm volatile("s_waitcnt vmcnt(4)" ::: "memory"); \
  else              asm volatile("s_waitcnt vmcnt(0)" ::: "memory"); \
  __builtin_amdgcn_sched_barrier(0); \
  __builtin_amdgcn_s_barrier(); \
  f32x4 pacc[4] = {}; \
  QK_STEP(KC, pacc); \
  bool msk = (kt * 64 >= s0); \
  W_PV(VC, kt * 64, pacc, msk); \
  if (kt + 2 < k1t) PREF(KN, VN, (kt + 2) * 64); \
  kt++; \
} while (0)

  int kt = k0t;
  PREF(Ks0, Vt0, kt * 64);
  asm volatile("" ::: "memory");
  if (kt + 1 < k1t) PREF(Ks1, Vt1, (kt + 1) * 64);

  while (true) {
    { PHASE(Ks0, Vt0, Ks2, Vt2); if (kt >= k1t) break; }
    { PHASE(Ks1, Vt1, Ks0, Vt0); if (kt >= k1t) break; }
    { PHASE(Ks2, Vt2, Ks1, Vt1); if (kt >= k1t) break; }
  }
#undef PHASE
#undef PREF
#undef QK_STEP
#undef W_PV

  if (mode != 0) {
    int slot = mode - 1;
    int qr = qp - 3;
    float* Hp = hpart + (size_t)slot * HP_SLOT + ((size_t)(bh * 5 + qr)) * 16384;
    float* sp = scpart + slot * SC_SLOT + (bh * 5 + qr) * 128;
    float* ep = enmp + (bh * 5 + qr) * 128;
#pragma unroll
    for (int r = 0; r < 4; r++) {
      int row = wave * 16 + lq * 4 + r;
      if (lm == 0) {
        sp[row] = accS[r];
        if (slot == 0) ep[row] = senm[row];
      }
#pragma unroll
      for (int nb = 0; nb < 8; nb++)
        Hp[row * 128 + nb * 16 + lm] = accH[nb][r];
    }
    return;
  }

  float inv[4], muv[4], rsv[4];
#pragma unroll
  for (int r = 0; r < 4; r++) {
    int row = wave * 16 + lq * 4 + r;
    float nrm = fmaxf(fabsf(accS[r]), senm[row]);
    inv[r] = 1.f / (nrm + 1e-6f);
  }
#pragma unroll
  for (int r = 0; r < 4; r++) {
    float s = 0.f, qq = 0.f;
#pragma unroll
    for (int nb = 0; nb < 8; nb++) {
      float hv = accH[nb][r] * inv[r];
      accH[nb][r] = hv;
      s += hv; qq += hv * hv;
    }
    s += __shfl_xor(s, 1); s += __shfl_xor(s, 2); s += __shfl_xor(s, 4); s += __shfl_xor(s, 8);
    qq += __shfl_xor(qq, 1); qq += __shfl_xor(qq, 2); qq += __shfl_xor(qq, 4); qq += __shfl_xor(qq, 8);
    float mu = s * (1.f / DHEAD);
    float var = qq * (1.f / DHEAD) - mu * mu;
    muv[r] = mu;
    rsv[r] = rsqrtf(var + 1e-5f);
  }
  float ow[8], sk[8];
#pragma unroll
  for (int nb = 0; nb < 8; nb++) {
    ow[nb] = onw[c0 + nb * 16 + lm];
    sk[nb] = skip[c0 + nb * 16 + lm];
  }
#pragma unroll
  for (int r = 0; r < 4; r++) {
    int rowg = s0 + wave * 16 + lq * 4 + r;
    size_t base = (rowbase + rowg) * INNER_D + c0;
#pragma unroll
    for (int nb = 0; nb < 8; nb++) {
      int d = nb * 16 + lm;
      float xcv = xc[base + d];
      float zv = bf2f(zh[base + d]);
      float hn = (accH[nb][r] - muv[r]) * rsv[r] * ow[nb] + sk[nb] * xcv;
      float o = hn * (zv / (1.f + __expf(-zv)));
      hs[base + d] = f2bf(o);
    }
  }
}

// combine 2..3 partial slots for rows s >= 384; one wave per row (10240 rows).
__global__ __launch_bounds__(256) void attn_combine_kernel(
    const float* __restrict__ hpart, const float* __restrict__ scpart,
    const float* __restrict__ enmp,
    const float* __restrict__ xc, const u16* __restrict__ zh,
    const float* __restrict__ skip, const float* __restrict__ onw,
    u16* __restrict__ hs)
{
  int wave = threadIdx.x >> 6, lane = threadIdx.x & 63;
  int gid = blockIdx.x * 4 + wave;   // 0..10239
  int bh = gid / 640;
  int rr = gid % 640;
  int qr = rr >> 7, row = rr & 127;
  int b = bh >> 3, hh = bh & 7;
  int s = (qr + 3) * 128 + row;
  int nsl = (qr >= 3) ? 3 : 2;       // qp3-5: 2 slots, qp6-7: 3 slots
  size_t off = (((size_t)(bh * 5 + qr)) * 128 + row) * 128 + lane * 2;
  int sidx = (bh * 5 + qr) * 128 + row;
  float hx = 0.f, hy = 0.f, sc = 0.f;
  for (int sl = 0; sl < nsl; sl++) {
    float2 hp = *(const float2*)(hpart + (size_t)sl * HP_SLOT + off);
    hx += hp.x; hy += hp.y;
    sc += scpart[sl * SC_SLOT + sidx];
  }
  float nrm = fmaxf(fabsf(sc), enmp[sidx]);
  float inv = 1.f / (nrm + 1e-6f);
  hx *= inv; hy *= inv;
  float sm = hx + hy, sq = hx * hx + hy * hy;
#pragma unroll
  for (int off2 = 32; off2; off2 >>= 1) { sm += __shfl_xor(sm, off2); sq += __shfl_xor(sq, off2); }
  float mu = sm * (1.f / DHEAD);
  float var = sq * (1.f / DHEAD) - mu * mu;
  float rs = rsqrtf(var + 1e-5f);
  int c0 = hh * DHEAD + lane * 2;
  size_t base = ((size_t)(b * S_LEN + s)) * INNER_D + c0;
  float2 xc2 = *(const float2*)(xc + base);
  ushort2 z2u = *(const ushort2*)(zh + base);
  float z2x = bf2f(z2u.x), z2y = bf2f(z2u.y);
  float skx = skip[c0], sky = skip[c0 + 1];
  float owx = onw[c0],  owy = onw[c0 + 1];
  ushort2 o;
  o.x = f2bf(((hx - mu) * rs * owx + skx * xc2.x) * (z2x / (1.f + __expf(-z2x))));
  o.y = f2bf(((hy - mu) * rs * owy + sky * xc2.y) * (z2y / (1.f + __expf(-z2y))));
  *(ushort2*)(hs + base) = o;
}

extern "C" void kernel_launch(void* const* d_in, const int* in_sizes, int n_in,
                              void* d_out, int out_size, void* d_ws, size_t ws_size,
                              hipStream_t stream)
{
  const float* x_enc   = (const float*)d_in[0];
  const float* x_mark  = (const float*)d_in[1];
  const float* emb_W   = (const float*)d_in[4];
  const float* emb_b   = (const float*)d_in[5];
  const float* ln_w    = (const float*)d_in[6];
  const float* up_W    = (const float*)d_in[7];
  const float* conv_W  = (const float*)d_in[8];
  const float* conv_b  = (const float*)d_in[9];
  const float* q_W     = (const float*)d_in[10];
  const float* k_W     = (const float*)d_in[11];
  const float* v_W     = (const float*)d_in[12];
  const float* ig_W    = (const float*)d_in[13];
  const float* ig_b    = (const float*)d_in[14];
  const float* fg_W    = (const float*)d_in[15];
  const float* fg_b    = (const float*)d_in[16];
  const float* skip_w  = (const float*)d_in[17];
  const float* onorm_w = (const float*)d_in[18];
  const float* down_W  = (const float*)d_in[19];
  const float* post_ln = (const float*)d_in[20];
  const float* head_W  = (const float*)d_in[21];
  const float* head_b  = (const float*)d_in[22];

  float* p = (float*)d_ws;
  float* x    = p; p += 1048576;   // 2048*512 f32
  float* xm   = p; p += 2097152;   // 2048*1024 f32; reused as hsbh bf16 after convqkv
  float* xc   = p; p += 2097152;
  float* igb_ = p; p += 32768;     // 2 K-halves x 16384
  float* fgb_ = p; p += 32768;
  float* enmp = p; p += 16384;     // 16 bh x 5 qr x 128 (padded)
  u16* qhb = (u16*)p; p += 1048576;  // 2048*1024 u16
  u16* khb = (u16*)p; p += 1048576;
  u16* vhb = (u16*)p; p += 1048576;
  u16* zh  = (u16*)p; p += 1048576;  // 2048*1024 u16 (full size)
  u16* xnh = (u16*)p; p += 524288;   // 2048*512 u16
  u16* upWtA = (u16*)p; p += 2097152; // 4 x 2048x512 u16
  u16* dnWtA = (u16*)p; p += 1048576; // 4 x 512x1024 u16
  u16* gtwH = (u16*)p; p += 98304;    // 4 x 16 x 3072 u16
  u16* gtwL = (u16*)p; p += 98304;
  float* hpart = p; p += 3932160;     // 3 slots x 16 bh x 5 qr x 128 x 128 f32
  float* scpart = p; p += 32768;      // 3 slots x 10240 (padded)
  u16* vtg = (u16*)p; p += 1048576;   // 2 x 1024 x 1024 u16 (V^T per layer)
  u16* hsbh = (u16*)xm;

  // one merged prep launch: up/down weight transposes + gates weights + embedding
  prep_kernel<<<4352, 256, 0, stream>>>(
      up_W, upWtA, down_W, dnWtA, ig_W, fg_W, gtwH, gtwL,
      x_enc, x_mark, emb_W, emb_b, x);

  for (int L = 0; L < 4; L++) {
    ln_kernel<<<512, 256, 0, stream>>>(x, ln_w + L * 512, xnh);
    gemm_bf16_split64<<<dim3(32, 16), 256, 0, stream>>>(
        xnh, upWtA + (size_t)L * 1048576, xm, zh, 2048, 2048, 512, 1024, 1024);
    convqkv_kernel<<<256, 256, 0, stream>>>(
        xm, conv_W + L * 4096, conv_b + L * 1024,
        q_W + L * 4096, k_W + L * 4096, v_W + L * 4096,
        xc, qhb, khb, vhb, vtg);
    gates_mfma_kernel<<<256, 256, 0, stream>>>(
        qhb, khb, vhb, gtwH + (size_t)L * 49152, gtwL + (size_t)L * 49152,
        ig_b + L * 8, fg_b + L * 8, igb_, fgb_);
    attn_mfma_kernel<<<dim3(16, 15), 512, 0, stream>>>(
        qhb, khb, vtg, igb_, fgb_, xc, zh,
        skip_w + L * 1024, onorm_w + L * 1024, hsbh, hpart, scpart, enmp);
    attn_combine_kernel<<<2560, 256, 0, stream>>>(
        hpart, scpart, enmp, xc, zh, skip_w + L * 1024, onorm_w + L * 1024, hsbh);
    gemm_bf16_32<<<dim3(16, 32), 256, 0, stream>>>(
        hsbh, dnWtA + (size_t)L * 524288, x, 2048, 512, 1024, 512);
  }

  lnhead_kernel<<<192, 256, 0, stream>>>(x, post_ln, head_W, head_b, (float*)d_out);
}